// Round 6
// baseline (6293.299 us; speedup 1.0000x reference)
//
#include <hip/hip_runtime.h>
#include <stdint.h>

typedef __bf16 bf16_t;
typedef bf16_t bf16x8 __attribute__((ext_vector_type(8)));
typedef float f32x4 __attribute__((ext_vector_type(4)));

__device__ __forceinline__ float bf2f(unsigned short u) {
  union { unsigned int i; float f; } x; x.i = ((unsigned int)u) << 16; return x.f;
}
__device__ __forceinline__ unsigned short f2bf(float f) {
  union { float f; unsigned int i; } x; x.f = f;
  unsigned int r = x.i + 0x7FFFu + ((x.i >> 16) & 1u);
  return (unsigned short)(r >> 16);
}
__device__ __forceinline__ unsigned pack2(float a, float b) {
  return (unsigned)f2bf(a) | ((unsigned)f2bf(b) << 16);
}

__global__ void fill_ident(float2* __restrict__ p) {
  int i = blockIdx.x * 256 + threadIdx.x;
  if (i < 768) p[i] = make_float2(1.f, 0.f);
}

// pre-split fp32 weights into hi/lo bf16 planes
__global__ __launch_bounds__(256) void wsplit(
    const float* __restrict__ in, unsigned short* __restrict__ hi,
    unsigned short* __restrict__ lo, int n) {
  int i = (blockIdx.x * 256 + threadIdx.x) * 8;
  if (i >= n) return;
  float4 a = *(const float4*)(in + i);
  float4 b = *(const float4*)(in + i + 4);
  float f[8] = {a.x, a.y, a.z, a.w, b.x, b.y, b.z, b.w};
  unsigned short sh[8], sl[8];
#pragma unroll
  for (int j = 0; j < 8; ++j) {
    sh[j] = f2bf(f[j]);
    sl[j] = f2bf(f[j] - bf2f(sh[j]));
  }
  *(uint4*)(hi + i) = *(uint4*)sh;
  *(uint4*)(lo + i) = *(uint4*)sl;
}

struct f8 { float4 a, b; };

__device__ __forceinline__ f8 ld_c8(const float* __restrict__ X,
                                    const float* __restrict__ TE,
                                    const float* __restrict__ SE,
                                    size_t row, int cc) {
  const float* src = (cc < 256) ? X : ((cc < 512) ? TE : SE);
  const float* p = src + row * 256 + (cc & 255);
  f8 r; r.a = *(const float4*)p; r.b = *(const float4*)(p + 4);
  return r;
}
__device__ __forceinline__ void split_pack(const float4 a, const float4 b,
                                           uint4& hi, uint4& lo) {
  float f[8] = {a.x, a.y, a.z, a.w, b.x, b.y, b.z, b.w};
  unsigned sh[8], sl[8];
#pragma unroll
  for (int j = 0; j < 8; ++j) {
    unsigned short h = f2bf(f[j]);
    sh[j] = h;
    sl[j] = f2bf(f[j] - bf2f(h));
  }
  hi = make_uint4(sh[0] | (sh[1] << 16), sh[2] | (sh[3] << 16),
                  sh[4] | (sh[5] << 16), sh[6] | (sh[7] << 16));
  lo = make_uint4(sl[0] | (sl[1] << 16), sl[2] | (sl[3] << 16),
                  sl[4] | (sl[5] << 16), sl[6] | (sl[7] << 16));
}
__device__ __forceinline__ uint4 pack_hi(const float4 a, const float4 b) {
  return make_uint4(pack2(a.x, a.y), pack2(a.z, a.w), pack2(b.x, b.y), pack2(b.z, b.w));
}

// ---------- GEMM: C[M,Cout] = A[M,K]*W[Cout,K]^T + bias ----------
// AMODE 0: A fp32. 1: A concat(X,TE,SE) fp32. 2: A bf16 raw.
// PREC 1: ah*bh only (stats). 2: ah*(bh+bl). 3: + al*bh.
// SMODE 0: none, 1: raw bf16, 2: relu(BN) bf16, 3: relu(BN) fp32, 4: raw fp32.
// PART: per-block column partials; cstr = C row stride.
template<int AMODE, int SMODE, int PART, int PREC>
__global__ __launch_bounds__(256) void gemm2(
    const void* __restrict__ Ap, const float* __restrict__ AX,
    const float* __restrict__ ATE, const float* __restrict__ ASE,
    const unsigned short* __restrict__ Wh, const unsigned short* __restrict__ Wl,
    const float* __restrict__ bias, const float2* __restrict__ ssO,
    unsigned short* __restrict__ Cb, float* __restrict__ Cf,
    float* __restrict__ psum, float* __restrict__ psq,
    int K, int Cout, int cstr, int pOff) {
  constexpr int PLANES = (PREC == 3) ? 4 : (PREC == 2 ? 3 : 2);
  __shared__ unsigned short lds[PLANES * 8192];
  unsigned short* lAh = lds;
  unsigned short* lBh = lds + 8192;
  unsigned short* lBl = lds + (PREC >= 2 ? 16384 : 0);
  unsigned short* lAl = lds + (PREC == 3 ? 24576 : 0);
  __shared__ float red[4][64][2];

  const int tid = threadIdx.x;
  const int lane = tid & 63, wid = tid >> 6;
  const int wr = wid >> 1, wc = wid & 1;
  const int l15 = lane & 15, l4 = lane >> 4;
  const int brow = blockIdx.x * 128, bcol = blockIdx.y * 128;

  f32x4 acc[4][4] = {};

  const int sr = tid >> 3;
  const int sc = (tid & 7) * 8;
  const int sdst = sc ^ ((sr & 7) << 3);

  f8 vaf[4]; uint4 vah[4]; uint4 vbh[4], vbl[4];
  auto loadA = [&](int ci, int cc) {
    size_t ar = (size_t)(brow + ci * 32 + sr);
    if constexpr (AMODE == 2) {
      vah[ci] = *(const uint4*)((const unsigned short*)Ap + ar * K + cc);
    } else if constexpr (AMODE == 0) {
      const float* p = (const float*)Ap + ar * K + cc;
      vaf[ci].a = *(const float4*)p; vaf[ci].b = *(const float4*)(p + 4);
    } else {
      vaf[ci] = ld_c8(AX, ATE, ASE, ar, cc);
    }
  };
  auto loadB = [&](int ci, int cc) {
    size_t wrw = (size_t)(bcol + ci * 32 + sr);
    vbh[ci] = *(const uint4*)(Wh + wrw * K + cc);
    if constexpr (PREC >= 2) vbl[ci] = *(const uint4*)(Wl + wrw * K + cc);
  };
#pragma unroll
  for (int ci = 0; ci < 4; ++ci) { loadA(ci, sc); loadB(ci, sc); }

  const int axor = (l15 & 7) << 3;

  for (int kt = 0; kt < K; kt += 64) {
    __syncthreads();
#pragma unroll
    for (int ci = 0; ci < 4; ++ci) {
      int dst = ((ci * 32 + sr) << 6) + sdst;
      if constexpr (AMODE == 2) {
        *(uint4*)(lAh + dst) = vah[ci];
      } else if constexpr (PREC == 3) {
        uint4 hi, lo;
        split_pack(vaf[ci].a, vaf[ci].b, hi, lo);
        *(uint4*)(lAh + dst) = hi; *(uint4*)(lAl + dst) = lo;
      } else {
        *(uint4*)(lAh + dst) = pack_hi(vaf[ci].a, vaf[ci].b);
      }
      *(uint4*)(lBh + dst) = vbh[ci];
      if constexpr (PREC >= 2) *(uint4*)(lBl + dst) = vbl[ci];
    }
    if (kt + 64 < K) {
      int cc = kt + 64 + sc;
#pragma unroll
      for (int ci = 0; ci < 4; ++ci) { loadA(ci, cc); loadB(ci, cc); }
    }
    __syncthreads();
#pragma unroll
    for (int ks = 0; ks < 2; ++ks) {
      const int cofs = (ks * 32 + l4 * 8) ^ axor;
      bf16x8 afh[4], afl[4], bfh[4], bfl[4];
#pragma unroll
      for (int m = 0; m < 4; ++m) {
        int o = ((wr * 64 + m * 16 + l15) << 6) + cofs;
        afh[m] = *(const bf16x8*)(lAh + o);
        if constexpr (PREC == 3) afl[m] = *(const bf16x8*)(lAl + o);
      }
#pragma unroll
      for (int nn = 0; nn < 4; ++nn) {
        int o = ((wc * 64 + nn * 16 + l15) << 6) + cofs;
        bfh[nn] = *(const bf16x8*)(lBh + o);
        if constexpr (PREC >= 2) bfl[nn] = *(const bf16x8*)(lBl + o);
      }
#pragma unroll
      for (int m = 0; m < 4; ++m)
#pragma unroll
        for (int nn = 0; nn < 4; ++nn) {
          acc[m][nn] = __builtin_amdgcn_mfma_f32_16x16x32_bf16(afh[m], bfh[nn], acc[m][nn], 0, 0, 0);
          if constexpr (PREC >= 2)
            acc[m][nn] = __builtin_amdgcn_mfma_f32_16x16x32_bf16(afh[m], bfl[nn], acc[m][nn], 0, 0, 0);
          if constexpr (PREC == 3)
            acc[m][nn] = __builtin_amdgcn_mfma_f32_16x16x32_bf16(afl[m], bfh[nn], acc[m][nn], 0, 0, 0);
        }
    }
  }

  float cs[4] = {0.f, 0.f, 0.f, 0.f}, cq[4] = {0.f, 0.f, 0.f, 0.f};
#pragma unroll
  for (int nn = 0; nn < 4; ++nn) {
    int col = bcol + wc * 64 + nn * 16 + l15;
    float bv = bias[col];
    float2 s2 = make_float2(1.f, 0.f);
    if constexpr (SMODE == 2 || SMODE == 3) s2 = ssO[col];
#pragma unroll
    for (int m = 0; m < 4; ++m) {
      int row0 = brow + wr * 64 + m * 16 + l4 * 4;
#pragma unroll
      for (int r = 0; r < 4; ++r) {
        float v = acc[m][nn][r] + bv;
        size_t idx = (size_t)(row0 + r) * cstr + col;
        if constexpr (SMODE == 1) Cb[idx] = f2bf(v);
        if constexpr (SMODE == 2) Cb[idx] = f2bf(fmaxf(v * s2.x + s2.y, 0.f));
        if constexpr (SMODE == 3) Cf[idx] = fmaxf(v * s2.x + s2.y, 0.f);
        if constexpr (SMODE == 4) Cf[idx] = v;
        if constexpr (PART) { cs[nn] += v; cq[nn] += v * v; }
      }
    }
  }
  if constexpr (PART) {
#pragma unroll
    for (int nn = 0; nn < 4; ++nn) {
      cs[nn] += __shfl_xor(cs[nn], 16); cs[nn] += __shfl_xor(cs[nn], 32);
      cq[nn] += __shfl_xor(cq[nn], 16); cq[nn] += __shfl_xor(cq[nn], 32);
    }
    __syncthreads();
    if (lane < 16) {
#pragma unroll
      for (int nn = 0; nn < 4; ++nn) {
        red[wid][nn * 16 + lane][0] = cs[nn];
        red[wid][nn * 16 + lane][1] = cq[nn];
      }
    }
    __syncthreads();
    if (tid < 128) {
      int w0 = tid >> 6, cl = tid & 63;
      float s = red[w0][cl][0] + red[w0 + 2][cl][0];
      float q = red[w0][cl][1] + red[w0 + 2][cl][1];
      psum[(size_t)(pOff + blockIdx.x) * Cout + bcol + tid] = s;
      psq[(size_t)(pOff + blockIdx.x) * Cout + bcol + tid] = q;
    }
  }
}

// ---------- BN stats: row-parallel partial + finalize ----------
__global__ __launch_bounds__(512) void bn_part(
    const float* __restrict__ psum, const float* __restrict__ psq,
    float* __restrict__ pp, int gridM, int Cout) {
  const int lane = threadIdx.x & 63, wv = threadIdx.x >> 6;
  const int c = blockIdx.y * 64 + lane;
  float s = 0.f, q = 0.f;
  for (int r = blockIdx.x + 64 * wv; r < gridM; r += 512) {
    s += psum[(size_t)r * Cout + c];
    q += psq[(size_t)r * Cout + c];
  }
  __shared__ float rs[8][64], rq[8][64];
  rs[wv][lane] = s; rq[wv][lane] = q;
  __syncthreads();
  if (threadIdx.x < 64) {
    float S = 0.f, Q = 0.f;
#pragma unroll
    for (int w2 = 0; w2 < 8; ++w2) { S += rs[w2][threadIdx.x]; Q += rq[w2][threadIdx.x]; }
    pp[(size_t)blockIdx.x * Cout + blockIdx.y * 64 + threadIdx.x] = S;
    pp[(size_t)(64 + blockIdx.x) * Cout + blockIdx.y * 64 + threadIdx.x] = Q;
  }
}
__global__ __launch_bounds__(64) void bn_fin(
    const float* __restrict__ pp, const float* __restrict__ g,
    const float* __restrict__ be, float2* __restrict__ ss, int Cout, float invR) {
  int c = blockIdx.x * 64 + threadIdx.x;
  float S = 0.f, Q = 0.f;
  for (int r = 0; r < 64; ++r) {
    S += pp[(size_t)r * Cout + c];
    Q += pp[(size_t)(64 + r) * Cout + c];
  }
  float mu = S * invR, var = Q * invR - mu * mu;
  float sc = g[c] * rsqrtf(var + 1e-5f);
  ss[c] = make_float2(sc, be[c] - mu * sc);
}

// ---------- attention ----------
template<int NK, int NQ, int VBF, int OBF>
__global__ void attn_sm(const unsigned short* __restrict__ qy,
                        const unsigned short* __restrict__ ky,
                        const void* __restrict__ vyv,
                        const float2* __restrict__ ssq, const float2* __restrict__ ssk,
                        const float2* __restrict__ ssv, void* __restrict__ outv,
                        size_t qStride, size_t kvStride, size_t oStride, int RS) {
  __shared__ float kl[NK][16][17];
  __shared__ float vl[NK][16][17];
  const int n = blockIdx.x, b = blockIdx.y;
  const int tid = threadIdx.x;
  const unsigned short* kyb = ky + (size_t)b * kvStride;
  for (int ch = tid; ch < NK * 32; ch += NQ * 16) {
    int t = ch >> 5, c8 = (ch & 31) * 8;
    size_t src = ((size_t)t * 500 + n) * RS + c8;
    uint4 kv = *(const uint4*)(kyb + src);
    const unsigned short* kp = (const unsigned short*)&kv;
    float fv[8];
    if constexpr (VBF) {
      const unsigned short* vb = (const unsigned short*)vyv + (size_t)b * kvStride;
      uint4 vv = *(const uint4*)(vb + src);
      const unsigned short* vp = (const unsigned short*)&vv;
#pragma unroll
      for (int j = 0; j < 8; ++j) fv[j] = bf2f(vp[j]);
    } else {
      const float* vf = (const float*)vyv + (size_t)b * kvStride;
      float4 a = *(const float4*)(vf + src);
      float4 bb = *(const float4*)(vf + src + 4);
      fv[0]=a.x; fv[1]=a.y; fv[2]=a.z; fv[3]=a.w;
      fv[4]=bb.x; fv[5]=bb.y; fv[6]=bb.z; fv[7]=bb.w;
    }
#pragma unroll
    for (int j = 0; j < 8; ++j) {
      int c = c8 + j;
      float2 sk = ssk[c], sv = ssv[c];
      kl[t][c >> 4][c & 15] = fmaxf(bf2f(kp[j]) * sk.x + sk.y, 0.f);
      vl[t][c >> 4][c & 15] = fmaxf(fv[j] * sv.x + sv.y, 0.f);
    }
  }
  __syncthreads();
  const int s = tid >> 4, h = tid & 15;
  unsigned short qraw[16];
  size_t qb = (size_t)b * qStride + ((size_t)s * 500 + n) * 256 + h * 16;
  *(uint4*)qraw = *(const uint4*)(qy + qb);
  *(uint4*)(qraw + 8) = *(const uint4*)(qy + qb + 8);
  float qv[16];
#pragma unroll
  for (int c = 0; c < 16; ++c) {
    float2 sq = ssq[h * 16 + c];
    qv[c] = fmaxf(bf2f(qraw[c]) * sq.x + sq.y, 0.f);
  }
  float lg[NK], mx = -1e30f;
#pragma unroll
  for (int t = 0; t < NK; ++t) {
    float d = 0.f;
#pragma unroll
    for (int c = 0; c < 16; ++c) d += qv[c] * kl[t][h][c];
    lg[t] = d * 0.25f;
    mx = fmaxf(mx, lg[t]);
  }
  float sum = 0.f;
#pragma unroll
  for (int t = 0; t < NK; ++t) { lg[t] = __expf(lg[t] - mx); sum += lg[t]; }
  float inv = 1.f / sum;
  float o[16];
#pragma unroll
  for (int c = 0; c < 16; ++c) o[c] = 0.f;
#pragma unroll
  for (int t = 0; t < NK; ++t) {
    float p = lg[t] * inv;
#pragma unroll
    for (int c = 0; c < 16; ++c) o[c] += p * vl[t][h][c];
  }
  size_t ob = (size_t)b * oStride + ((size_t)s * 500 + n) * 256 + h * 16;
  if constexpr (OBF) {
    unsigned short* out = (unsigned short*)outv;
    uint4 w0;
    w0.x = pack2(o[0], o[1]); w0.y = pack2(o[2], o[3]);
    w0.z = pack2(o[4], o[5]); w0.w = pack2(o[6], o[7]);
    *(uint4*)(out + ob) = w0;
    w0.x = pack2(o[8], o[9]); w0.y = pack2(o[10], o[11]);
    w0.z = pack2(o[12], o[13]); w0.w = pack2(o[14], o[15]);
    *(uint4*)(out + ob + 8) = w0;
  } else {
    float* out = (float*)outv;
    *(float4*)(out + ob)      = make_float4(o[0], o[1], o[2], o[3]);
    *(float4*)(out + ob + 4)  = make_float4(o[4], o[5], o[6], o[7]);
    *(float4*)(out + ob + 8)  = make_float4(o[8], o[9], o[10], o[11]);
    *(float4*)(out + ob + 12) = make_float4(o[12], o[13], o[14], o[15]);
  }
}

// ---------- final: out = X + relu(BN(y)), y fp32 ----------
__global__ __launch_bounds__(256) void bn_relu_addx(
    const float* __restrict__ y, const float2* __restrict__ ss,
    const float* __restrict__ X, float* __restrict__ out) {
  int r = blockIdx.x * 8 + (threadIdx.x >> 5);
  int c8 = (threadIdx.x & 31) * 8;
  size_t idx = (size_t)r * 256 + c8;
  float4 y0 = *(const float4*)(y + idx);
  float4 y1 = *(const float4*)(y + idx + 4);
  float4 x0 = *(const float4*)(X + idx);
  float4 x1 = *(const float4*)(X + idx + 4);
  float yv[8] = {y0.x, y0.y, y0.z, y0.w, y1.x, y1.y, y1.z, y1.w};
  float ov[8];
#pragma unroll
  for (int j = 0; j < 8; ++j) {
    float2 sc = ss[c8 + j];
    ov[j] = fmaxf(yv[j] * sc.x + sc.y, 0.f);
  }
  *(float4*)(out + idx)     = make_float4(x0.x + ov[0], x0.y + ov[1], x0.z + ov[2], x0.w + ov[3]);
  *(float4*)(out + idx + 4) = make_float4(x1.x + ov[4], x1.y + ov[5], x1.z + ov[6], x1.w + ov[7]);
}

// ---------- launcher ----------
extern "C" void kernel_launch(void* const* d_in, const int* in_sizes, int n_in,
                              void* d_out, int out_size, void* d_ws, size_t ws_size,
                              hipStream_t stream) {
  (void)in_sizes; (void)n_in; (void)out_size;
  const float* X  = (const float*)d_in[0];
  const float* TE = (const float*)d_in[1];
  const float* SE = (const float*)d_in[2];
  const float* I  = (const float*)d_in[3];
  const float *Wf[8], *Bf[8], *Gf[8], *Zf[8];
  for (int l = 0; l < 8; ++l) {
    Wf[l] = (const float*)d_in[4 + l * 4 + 0];
    Bf[l] = (const float*)d_in[4 + l * 4 + 1];
    Gf[l] = (const float*)d_in[4 + l * 4 + 2];
    Zf[l] = (const float*)d_in[4 + l * 4 + 3];
  }
  // tier P (330 MB) if workspace allows; else tier Q (256 MB, proven)
  const bool tP = ws_size >= 345000000ULL;

  char* w = (char*)d_ws;
  size_t off = 0;
  auto alloc = [&](size_t bytes) -> void* {
    void* p = w + off;
    off += (bytes + 255) & ~(size_t)255;
    return p;
  };

  float* psum0 = (float*)alloc((size_t)2000 * 768 * 4);
  float* psq0  = (float*)alloc((size_t)2000 * 768 * 4);
  float* psumK = (float*)alloc((size_t)2000 * 256 * 4);
  float* psqK  = (float*)alloc((size_t)2000 * 256 * 4);
  float* psumV = (float*)alloc((size_t)2000 * 256 * 4);
  float* psqV  = (float*)alloc((size_t)2000 * 256 * 4);
  float* pp    = (float*)alloc((size_t)128 * 768 * 4);
  float2* ss   = (float2*)alloc((size_t)(8 * 768 + 768) * sizeof(float2));
  float2* ident = ss + 8 * 768;
  unsigned short *Wh[8], *Wl[8];
  const int wn[8] = {196608, 196608, 196608, 196608, 196608, 196608, 196608, 65536};
  for (int l = 0; l < 8; ++l) {
    Wh[l] = (unsigned short*)alloc((size_t)wn[l] * 2);
    Wl[l] = (unsigned short*)alloc((size_t)wn[l] * 2);
  }
  unsigned short* q0 = (unsigned short*)alloc((size_t)16000 * 256 * 2);

  unsigned short *o0b = nullptr, *q1 = nullptr, *o0c = nullptr;
  if (tP) o0b = (unsigned short*)alloc((size_t)256000 * 256 * 2);
  else    q1  = (unsigned short*)alloc((size_t)96000 * 256 * 2);
  float* Hc = (float*)alloc((size_t)16000 * 768 * 4);
  unsigned short* k0 = (unsigned short*)alloc((size_t)96000 * 256 * 2);
  unsigned short* v0 = (unsigned short*)alloc((size_t)96000 * 256 * 2);  // bf16, contiguous after k0
  if (!tP) o0c = (unsigned short*)alloc((size_t)16000 * 256 * 2);
  unsigned short* k1c = (unsigned short*)alloc((size_t)16000 * 256 * 2);
  unsigned short* v1c = (unsigned short*)alloc((size_t)16000 * 256 * 2);

  float* o1; float* y7;
  if (tP) {
    q1 = (unsigned short*)d_out;          // bf16 q1 in d_out (overwritten by final)
    o1 = (float*)k0;                      // overlays dead k0+v0 (exactly 96000*256*4)
    y7 = (float*)o0b;                     // overlays dead o0b
  } else {
    o1 = (float*)d_out;
    y7 = (float*)k0;                      // overlays dead k0+v0
  }

  // ---- prep ----
  fill_ident<<<dim3(3), 256, 0, stream>>>(ident);
  for (int l = 0; l < 8; ++l)
    wsplit<<<dim3(wn[l] / 2048), 256, 0, stream>>>(Wf[l], Wh[l], Wl[l], wn[l]);

  auto bn1 = [&](float* ps, float* pq, const float* g, const float* z, float2* dst,
                 int gridM, int Cout, float invR) {
    bn_part<<<dim3(64, Cout / 64), 512, 0, stream>>>(ps, pq, pp, gridM, Cout);
    bn_fin<<<dim3(Cout / 64), 64, 0, stream>>>(pp, g, z, dst, Cout, invR);
  };

  // ---- stage 1: q0, k0, v0 (bf16), q1 ----
  gemm2<0, 1, 1, 2><<<dim3(125, 2), 256, 0, stream>>>(
      I, nullptr, nullptr, nullptr, Wh[0], Wl[0], Bf[0], nullptr,
      q0, nullptr, psum0, psq0, 768, 256, 256, 0);
  bn1(psum0, psq0, Gf[0], Zf[0], ss + 0 * 768, 125, 256, 1.f / 16000.f);
  gemm2<1, 1, 1, 2><<<dim3(750, 2), 256, 0, stream>>>(
      nullptr, X, TE, SE, Wh[1], Wl[1], Bf[1], nullptr,
      k0, nullptr, psum0, psq0, 768, 256, 256, 0);
  bn1(psum0, psq0, Gf[1], Zf[1], ss + 1 * 768, 750, 256, 1.f / 96000.f);
  gemm2<1, 1, 1, 2><<<dim3(750, 2), 256, 0, stream>>>(
      nullptr, X, TE, SE, Wh[2], Wl[2], Bf[2], nullptr,
      v0, nullptr, psum0, psq0, 768, 256, 256, 0);
  bn1(psum0, psq0, Gf[2], Zf[2], ss + 2 * 768, 750, 256, 1.f / 96000.f);
  gemm2<1, 1, 1, 2><<<dim3(750, 2), 256, 0, stream>>>(
      nullptr, X, TE, SE, Wh[4], Wl[4], Bf[4], nullptr,
      q1, nullptr, psum0, psq0, 768, 256, 256, 0);
  bn1(psum0, psq0, Gf[4], Zf[4], ss + 4 * 768, 750, 256, 1.f / 96000.f);

  const size_t cOff  = (size_t)6000 * 256;   // per-b rows in k0/v0/q1/o1
  const size_t cOff1 = (size_t)16000 * 256;  // per-b rows in o0

  if (tP) {
    // single-launch attn0 -> o0b (bf16)
    attn_sm<12, 32, 1, 1><<<dim3(500, 16), 512, 0, stream>>>(
        q0, k0, v0, ss + 0 * 768, ss + 1 * 768, ss + 2 * 768, o0b,
        0, cOff, cOff1, 256);
    // m0o stats, one pass, PREC1
    gemm2<2, 0, 1, 1><<<dim3(2000, 6), 256, 0, stream>>>(
        o0b, nullptr, nullptr, nullptr, Wh[3], Wl[3], Bf[3], nullptr,
        nullptr, nullptr, psum0, psq0, 256, 768, 768, 0);
    bn1(psum0, psq0, Gf[3], Zf[3], ss + 3 * 768, 2000, 768, 1.f / 256000.f);
    // pass B: H chunk (from o0b) -> k/v stats (PREC1)
    for (int cb = 0; cb < 16; ++cb) {
      gemm2<2, 3, 0, 2><<<dim3(125, 6), 256, 0, stream>>>(
          o0b + cb * cOff1, nullptr, nullptr, nullptr, Wh[3], Wl[3], Bf[3],
          ss + 3 * 768, nullptr, Hc, nullptr, nullptr, 256, 768, 768, 0);
      gemm2<0, 0, 1, 1><<<dim3(125, 2), 256, 0, stream>>>(
          Hc, nullptr, nullptr, nullptr, Wh[5], Wl[5], Bf[5], nullptr,
          nullptr, nullptr, psumK, psqK, 768, 256, 256, cb * 125);
      gemm2<0, 0, 1, 1><<<dim3(125, 2), 256, 0, stream>>>(
          Hc, nullptr, nullptr, nullptr, Wh[6], Wl[6], Bf[6], nullptr,
          nullptr, nullptr, psumV, psqV, 768, 256, 256, cb * 125);
    }
    bn1(psumK, psqK, Gf[5], Zf[5], ss + 5 * 768, 2000, 256, 1.f / 256000.f);
    bn1(psumV, psqV, Gf[6], Zf[6], ss + 6 * 768, 2000, 256, 1.f / 256000.f);
    // pass C: H chunk -> BN'd k1c/v1c -> attn1 chunk -> o1 (over k0/v0)
    for (int cb = 0; cb < 16; ++cb) {
      gemm2<2, 3, 0, 2><<<dim3(125, 6), 256, 0, stream>>>(
          o0b + cb * cOff1, nullptr, nullptr, nullptr, Wh[3], Wl[3], Bf[3],
          ss + 3 * 768, nullptr, Hc, nullptr, nullptr, 256, 768, 768, 0);
      gemm2<0, 2, 0, 2><<<dim3(125, 2), 256, 0, stream>>>(
          Hc, nullptr, nullptr, nullptr, Wh[5], Wl[5], Bf[5],
          ss + 5 * 768, k1c, nullptr, nullptr, nullptr, 768, 256, 256, 0);
      gemm2<0, 2, 0, 2><<<dim3(125, 2), 256, 0, stream>>>(
          Hc, nullptr, nullptr, nullptr, Wh[6], Wl[6], Bf[6],
          ss + 6 * 768, v1c, nullptr, nullptr, nullptr, 768, 256, 256, 0);
      attn_sm<32, 12, 1, 0><<<dim3(500, 1), 192, 0, stream>>>(
          q1 + cb * cOff, k1c, v1c, ss + 4 * 768, ident, ident,
          o1 + cb * cOff, 0, 0, 0, 256);
    }
  } else {
    // pass A: attn0 chunks -> m0o stats (PREC1)
    for (int cb = 0; cb < 16; ++cb) {
      attn_sm<12, 32, 1, 1><<<dim3(500, 1), 512, 0, stream>>>(
          q0, k0 + cb * cOff, v0 + cb * cOff,
          ss + 0 * 768, ss + 1 * 768, ss + 2 * 768, o0c, 0, 0, 0, 256);
      gemm2<2, 0, 1, 1><<<dim3(125, 6), 256, 0, stream>>>(
          o0c, nullptr, nullptr, nullptr, Wh[3], Wl[3], Bf[3], nullptr,
          nullptr, nullptr, psum0, psq0, 256, 768, 768, cb * 125);
    }
    bn1(psum0, psq0, Gf[3], Zf[3], ss + 3 * 768, 2000, 768, 1.f / 256000.f);
    // pass B: attn0 + H -> k/v stats
    for (int cb = 0; cb < 16; ++cb) {
      attn_sm<12, 32, 1, 1><<<dim3(500, 1), 512, 0, stream>>>(
          q0, k0 + cb * cOff, v0 + cb * cOff,
          ss + 0 * 768, ss + 1 * 768, ss + 2 * 768, o0c, 0, 0, 0, 256);
      gemm2<2, 3, 0, 2><<<dim3(125, 6), 256, 0, stream>>>(
          o0c, nullptr, nullptr, nullptr, Wh[3], Wl[3], Bf[3],
          ss + 3 * 768, nullptr, Hc, nullptr, nullptr, 256, 768, 768, 0);
      gemm2<0, 0, 1, 1><<<dim3(125, 2), 256, 0, stream>>>(
          Hc, nullptr, nullptr, nullptr, Wh[5], Wl[5], Bf[5], nullptr,
          nullptr, nullptr, psumK, psqK, 768, 256, 256, cb * 125);
      gemm2<0, 0, 1, 1><<<dim3(125, 2), 256, 0, stream>>>(
          Hc, nullptr, nullptr, nullptr, Wh[6], Wl[6], Bf[6], nullptr,
          nullptr, nullptr, psumV, psqV, 768, 256, 256, cb * 125);
    }
    bn1(psumK, psqK, Gf[5], Zf[5], ss + 5 * 768, 2000, 256, 1.f / 256000.f);
    bn1(psumV, psqV, Gf[6], Zf[6], ss + 6 * 768, 2000, 256, 1.f / 256000.f);
    // pass C: attn0 + H + BN'd k1c/v1c + attn1 -> o1 (d_out)
    for (int cb = 0; cb < 16; ++cb) {
      attn_sm<12, 32, 1, 1><<<dim3(500, 1), 512, 0, stream>>>(
          q0, k0 + cb * cOff, v0 + cb * cOff,
          ss + 0 * 768, ss + 1 * 768, ss + 2 * 768, o0c, 0, 0, 0, 256);
      gemm2<2, 3, 0, 2><<<dim3(125, 6), 256, 0, stream>>>(
          o0c, nullptr, nullptr, nullptr, Wh[3], Wl[3], Bf[3],
          ss + 3 * 768, nullptr, Hc, nullptr, nullptr, 256, 768, 768, 0);
      gemm2<0, 2, 0, 2><<<dim3(125, 2), 256, 0, stream>>>(
          Hc, nullptr, nullptr, nullptr, Wh[5], Wl[5], Bf[5],
          ss + 5 * 768, k1c, nullptr, nullptr, nullptr, 768, 256, 256, 0);
      gemm2<0, 2, 0, 2><<<dim3(125, 2), 256, 0, stream>>>(
          Hc, nullptr, nullptr, nullptr, Wh[6], Wl[6], Bf[6],
          ss + 6 * 768, v1c, nullptr, nullptr, nullptr, 768, 256, 256, 0);
      attn_sm<32, 12, 1, 0><<<dim3(500, 1), 192, 0, stream>>>(
          q1 + cb * cOff, k1c, v1c, ss + 4 * 768, ident, ident,
          o1 + cb * cOff, 0, 0, 0, 256);
    }
  }

  // ---- m1o + final ----
  gemm2<0, 4, 1, 3><<<dim3(750, 2), 256, 0, stream>>>(
      o1, nullptr, nullptr, nullptr, Wh[7], Wl[7], Bf[7], nullptr,
      nullptr, y7, psum0, psq0, 256, 256, 256, 0);
  bn1(psum0, psq0, Gf[7], Zf[7], ss + 7 * 768, 750, 256, 1.f / 96000.f);
  bn_relu_addx<<<dim3(12000), 256, 0, stream>>>(y7, ss + 7 * 768, X, (float*)d_out);
}

// Round 7
// 4390.158 us; speedup vs baseline: 1.4335x; 1.4335x over previous
//
#include <hip/hip_runtime.h>
#include <stdint.h>

typedef __bf16 bf16_t;
typedef bf16_t bf16x8 __attribute__((ext_vector_type(8)));
typedef float f32x4 __attribute__((ext_vector_type(4)));

__device__ __forceinline__ float bf2f(unsigned short u) {
  union { unsigned int i; float f; } x; x.i = ((unsigned int)u) << 16; return x.f;
}
__device__ __forceinline__ unsigned short f2bf(float f) {
  union { float f; unsigned int i; } x; x.f = f;
  unsigned int r = x.i + 0x7FFFu + ((x.i >> 16) & 1u);
  return (unsigned short)(r >> 16);
}
__device__ __forceinline__ unsigned pack2(float a, float b) {
  return (unsigned)f2bf(a) | ((unsigned)f2bf(b) << 16);
}

// concat two 256-ch bias vectors
__global__ void cat2(const float* __restrict__ a, const float* __restrict__ b,
                     float* __restrict__ dst) {
  int i = threadIdx.x;
  dst[i] = a[i]; dst[256 + i] = b[i];
}

// pre-split fp32 weights into hi/lo bf16 planes
__global__ __launch_bounds__(256) void wsplit(
    const float* __restrict__ in, unsigned short* __restrict__ hi,
    unsigned short* __restrict__ lo, int n) {
  int i = (blockIdx.x * 256 + threadIdx.x) * 8;
  if (i >= n) return;
  float4 a = *(const float4*)(in + i);
  float4 b = *(const float4*)(in + i + 4);
  float f[8] = {a.x, a.y, a.z, a.w, b.x, b.y, b.z, b.w};
  unsigned short sh[8], sl[8];
#pragma unroll
  for (int j = 0; j < 8; ++j) {
    sh[j] = f2bf(f[j]);
    sl[j] = f2bf(f[j] - bf2f(sh[j]));
  }
  *(uint4*)(hi + i) = *(uint4*)sh;
  *(uint4*)(lo + i) = *(uint4*)sl;
}

struct f8 { float4 a, b; };

__device__ __forceinline__ f8 ld_c8(const float* __restrict__ X,
                                    const float* __restrict__ TE,
                                    const float* __restrict__ SE,
                                    size_t row, int cc) {
  const float* src = (cc < 256) ? X : ((cc < 512) ? TE : SE);
  const float* p = src + row * 256 + (cc & 255);
  f8 r; r.a = *(const float4*)p; r.b = *(const float4*)(p + 4);
  return r;
}
__device__ __forceinline__ uint4 pack_hi(const float4 a, const float4 b) {
  return make_uint4(pack2(a.x, a.y), pack2(a.z, a.w), pack2(b.x, b.y), pack2(b.z, b.w));
}

// ---------- GEMM: C[M,Cout] = A[M,K]*W[Cout,K]^T + bias ----------
// AMODE 0: A fp32. 1: A concat(X,TE,SE) fp32. 2: A bf16 raw.
// PREC 1: ah*bh (stats). 2: ah*(bh+bl).
// SMODE 0: none, 1: raw bf16, 2: relu(BN) bf16, 4: raw fp32,
//         5: dual raw bf16 (cols<256 -> Cb, >=256 -> Cb2; both stride 256).
// PART: per-block column partials (width Cout); cstr = C row stride.
template<int AMODE, int SMODE, int PART, int PREC>
__global__ __launch_bounds__(256) void gemm2(
    const void* __restrict__ Ap, const float* __restrict__ AX,
    const float* __restrict__ ATE, const float* __restrict__ ASE,
    const unsigned short* __restrict__ Wh, const unsigned short* __restrict__ Wl,
    const float* __restrict__ bias, const float2* __restrict__ ssO,
    unsigned short* __restrict__ Cb, unsigned short* __restrict__ Cb2,
    float* __restrict__ Cf, float* __restrict__ psum, float* __restrict__ psq,
    int K, int Cout, int cstr, int pOff) {
  constexpr int PLANES = (PREC == 2) ? 3 : 2;
  __shared__ unsigned short lds[PLANES * 8192];
  unsigned short* lAh = lds;
  unsigned short* lBh = lds + 8192;
  unsigned short* lBl = lds + (PREC == 2 ? 16384 : 0);
  __shared__ float red[4][64][2];

  const int tid = threadIdx.x;
  const int lane = tid & 63, wid = tid >> 6;
  const int wr = wid >> 1, wc = wid & 1;
  const int l15 = lane & 15, l4 = lane >> 4;
  const int brow = blockIdx.x * 128, bcol = blockIdx.y * 128;

  f32x4 acc[4][4] = {};

  const int sr = tid >> 3;
  const int sc = (tid & 7) * 8;
  const int sdst = sc ^ ((sr & 7) << 3);

  f8 vaf[4]; uint4 vah[4]; uint4 vbh[4], vbl[4];
  auto loadA = [&](int ci, int cc) {
    size_t ar = (size_t)(brow + ci * 32 + sr);
    if constexpr (AMODE == 2) {
      vah[ci] = *(const uint4*)((const unsigned short*)Ap + ar * K + cc);
    } else if constexpr (AMODE == 0) {
      const float* p = (const float*)Ap + ar * K + cc;
      vaf[ci].a = *(const float4*)p; vaf[ci].b = *(const float4*)(p + 4);
    } else {
      vaf[ci] = ld_c8(AX, ATE, ASE, ar, cc);
    }
  };
  auto loadB = [&](int ci, int cc) {
    size_t wrw = (size_t)(bcol + ci * 32 + sr);
    vbh[ci] = *(const uint4*)(Wh + wrw * K + cc);
    if constexpr (PREC == 2) vbl[ci] = *(const uint4*)(Wl + wrw * K + cc);
  };
#pragma unroll
  for (int ci = 0; ci < 4; ++ci) { loadA(ci, sc); loadB(ci, sc); }

  const int axor = (l15 & 7) << 3;

  for (int kt = 0; kt < K; kt += 64) {
    __syncthreads();
#pragma unroll
    for (int ci = 0; ci < 4; ++ci) {
      int dst = ((ci * 32 + sr) << 6) + sdst;
      if constexpr (AMODE == 2) *(uint4*)(lAh + dst) = vah[ci];
      else                      *(uint4*)(lAh + dst) = pack_hi(vaf[ci].a, vaf[ci].b);
      *(uint4*)(lBh + dst) = vbh[ci];
      if constexpr (PREC == 2) *(uint4*)(lBl + dst) = vbl[ci];
    }
    if (kt + 64 < K) {
      int cc = kt + 64 + sc;
#pragma unroll
      for (int ci = 0; ci < 4; ++ci) { loadA(ci, cc); loadB(ci, cc); }
    }
    __syncthreads();
#pragma unroll
    for (int ks = 0; ks < 2; ++ks) {
      const int cofs = (ks * 32 + l4 * 8) ^ axor;
      bf16x8 afh[4], bfh[4], bfl[4];
#pragma unroll
      for (int m = 0; m < 4; ++m) {
        int o = ((wr * 64 + m * 16 + l15) << 6) + cofs;
        afh[m] = *(const bf16x8*)(lAh + o);
      }
#pragma unroll
      for (int nn = 0; nn < 4; ++nn) {
        int o = ((wc * 64 + nn * 16 + l15) << 6) + cofs;
        bfh[nn] = *(const bf16x8*)(lBh + o);
        if constexpr (PREC == 2) bfl[nn] = *(const bf16x8*)(lBl + o);
      }
#pragma unroll
      for (int m = 0; m < 4; ++m)
#pragma unroll
        for (int nn = 0; nn < 4; ++nn) {
          acc[m][nn] = __builtin_amdgcn_mfma_f32_16x16x32_bf16(afh[m], bfh[nn], acc[m][nn], 0, 0, 0);
          if constexpr (PREC == 2)
            acc[m][nn] = __builtin_amdgcn_mfma_f32_16x16x32_bf16(afh[m], bfl[nn], acc[m][nn], 0, 0, 0);
        }
    }
  }

  float cs[4] = {0.f, 0.f, 0.f, 0.f}, cq[4] = {0.f, 0.f, 0.f, 0.f};
#pragma unroll
  for (int nn = 0; nn < 4; ++nn) {
    int col = bcol + wc * 64 + nn * 16 + l15;
    float bv = bias[col];
    float2 s2 = make_float2(1.f, 0.f);
    if constexpr (SMODE == 2) s2 = ssO[col];
#pragma unroll
    for (int m = 0; m < 4; ++m) {
      int row0 = brow + wr * 64 + m * 16 + l4 * 4;
#pragma unroll
      for (int r = 0; r < 4; ++r) {
        float v = acc[m][nn][r] + bv;
        if constexpr (SMODE == 1) Cb[(size_t)(row0 + r) * cstr + col] = f2bf(v);
        if constexpr (SMODE == 2) Cb[(size_t)(row0 + r) * cstr + col] = f2bf(fmaxf(v * s2.x + s2.y, 0.f));
        if constexpr (SMODE == 4) Cf[(size_t)(row0 + r) * cstr + col] = v;
        if constexpr (SMODE == 5) {
          unsigned short* dst = (col < 256) ? Cb : Cb2;
          dst[(size_t)(row0 + r) * 256 + (col & 255)] = f2bf(v);
        }
        if constexpr (PART) { cs[nn] += v; cq[nn] += v * v; }
      }
    }
  }
  if constexpr (PART) {
#pragma unroll
    for (int nn = 0; nn < 4; ++nn) {
      cs[nn] += __shfl_xor(cs[nn], 16); cs[nn] += __shfl_xor(cs[nn], 32);
      cq[nn] += __shfl_xor(cq[nn], 16); cq[nn] += __shfl_xor(cq[nn], 32);
    }
    __syncthreads();
    if (lane < 16) {
#pragma unroll
      for (int nn = 0; nn < 4; ++nn) {
        red[wid][nn * 16 + lane][0] = cs[nn];
        red[wid][nn * 16 + lane][1] = cq[nn];
      }
    }
    __syncthreads();
    if (tid < 128) {
      int w0 = tid >> 6, cl = tid & 63;
      float s = red[w0][cl][0] + red[w0 + 2][cl][0];
      float q = red[w0][cl][1] + red[w0 + 2][cl][1];
      psum[(size_t)(pOff + blockIdx.x) * Cout + bcol + tid] = s;
      psq[(size_t)(pOff + blockIdx.x) * Cout + bcol + tid] = q;
    }
  }
}

// ---------- column stats of a bf16 [rows][256] tensor; 2048 rows/block ----------
__global__ __launch_bounds__(256) void colstats(
    const unsigned short* __restrict__ A, float* __restrict__ psum,
    float* __restrict__ psq) {
  const int tid = threadIdx.x;
  const int r8 = tid >> 5, co = tid & 31;
  float s[8] = {0,0,0,0,0,0,0,0}, q[8] = {0,0,0,0,0,0,0,0};
  size_t base = (size_t)blockIdx.x * 2048;
  for (int it = 0; it < 256; ++it) {
    size_t row = base + it * 8 + r8;
    uint4 v = *(const uint4*)(A + row * 256 + co * 8);
    const unsigned short* pv = (const unsigned short*)&v;
#pragma unroll
    for (int j = 0; j < 8; ++j) {
      float f = bf2f(pv[j]);
      s[j] += f; q[j] += f * f;
    }
  }
  __shared__ float ls[8][32][8], lq[8][32][8];
#pragma unroll
  for (int j = 0; j < 8; ++j) { ls[r8][co][j] = s[j]; lq[r8][co][j] = q[j]; }
  __syncthreads();
  int co2 = tid >> 3, j2 = tid & 7;
  float S = 0.f, Q = 0.f;
#pragma unroll
  for (int r = 0; r < 8; ++r) { S += ls[r][co2][j2]; Q += lq[r][co2][j2]; }
  psum[(size_t)blockIdx.x * 256 + co2 * 8 + j2] = S;
  psq [(size_t)blockIdx.x * 256 + co2 * 8 + j2] = Q;
}

// ---------- BN stats: row-parallel partial + finalize ----------
__global__ __launch_bounds__(512) void bn_part(
    const float* __restrict__ psum, const float* __restrict__ psq,
    float* __restrict__ pp, int gridM, int Cout) {
  const int lane = threadIdx.x & 63, wv = threadIdx.x >> 6;
  const int c = blockIdx.y * 64 + lane;
  float s = 0.f, q = 0.f;
  for (int r = blockIdx.x + 64 * wv; r < gridM; r += 512) {
    s += psum[(size_t)r * Cout + c];
    q += psq[(size_t)r * Cout + c];
  }
  __shared__ float rs[8][64], rq[8][64];
  rs[wv][lane] = s; rq[wv][lane] = q;
  __syncthreads();
  if (threadIdx.x < 64) {
    float S = 0.f, Q = 0.f;
#pragma unroll
    for (int w2 = 0; w2 < 8; ++w2) { S += rs[w2][threadIdx.x]; Q += rq[w2][threadIdx.x]; }
    pp[(size_t)blockIdx.x * Cout + blockIdx.y * 64 + threadIdx.x] = S;
    pp[(size_t)(64 + blockIdx.x) * Cout + blockIdx.y * 64 + threadIdx.x] = Q;
  }
}
__global__ __launch_bounds__(64) void bn_fin(
    const float* __restrict__ pp, const float* __restrict__ g,
    const float* __restrict__ be, float2* __restrict__ ss, int Cout, float invR) {
  int c = blockIdx.x * 64 + threadIdx.x;
  float S = 0.f, Q = 0.f;
  for (int r = 0; r < 64; ++r) {
    S += pp[(size_t)r * Cout + c];
    Q += pp[(size_t)(64 + r) * Cout + c];
  }
  float mu = S * invR, var = Q * invR - mu * mu;
  float sc = g[c] * rsqrtf(var + 1e-5f);
  ss[c] = make_float2(sc, be[c] - mu * sc);
}
__global__ __launch_bounds__(64) void bn_fin2(
    const float* __restrict__ pp, const float* __restrict__ gA,
    const float* __restrict__ zA, const float* __restrict__ gB,
    const float* __restrict__ zB, float2* __restrict__ ssC, float invR) {
  int c = blockIdx.x * 64 + threadIdx.x;  // Cout = 512
  float S = 0.f, Q = 0.f;
  for (int r = 0; r < 64; ++r) {
    S += pp[(size_t)r * 512 + c];
    Q += pp[(size_t)(64 + r) * 512 + c];
  }
  float mu = S * invR, var = Q * invR - mu * mu;
  const float* g = (c < 256) ? gA : gB;
  const float* z = (c < 256) ? zA : zB;
  int ci = c & 255;
  float sc = g[ci] * rsqrtf(var + 1e-5f);
  ssC[c] = make_float2(sc, z[ci] - mu * sc);
}

// ---------- attention: q bf16 (+BN), k/v bf16 (+BN), bf16 out ----------
template<int NK, int NQ>
__global__ void attn_sm(const unsigned short* __restrict__ qy,
                        const unsigned short* __restrict__ ky,
                        const unsigned short* __restrict__ vy,
                        const float2* __restrict__ ssq, const float2* __restrict__ ssk,
                        const float2* __restrict__ ssv, unsigned short* __restrict__ out,
                        size_t qStride, size_t kvStride, size_t oStride, int RS) {
  __shared__ float kl[NK][16][17];
  __shared__ float vl[NK][16][17];
  const int n = blockIdx.x, b = blockIdx.y;
  const int tid = threadIdx.x;
  const unsigned short* kyb = ky + (size_t)b * kvStride;
  const unsigned short* vyb = vy + (size_t)b * kvStride;
  for (int ch = tid; ch < NK * 32; ch += NQ * 16) {
    int t = ch >> 5, c8 = (ch & 31) * 8;
    size_t src = ((size_t)t * 500 + n) * RS + c8;
    uint4 kv = *(const uint4*)(kyb + src);
    uint4 vv = *(const uint4*)(vyb + src);
    const unsigned short* kp = (const unsigned short*)&kv;
    const unsigned short* vp = (const unsigned short*)&vv;
#pragma unroll
    for (int j = 0; j < 8; ++j) {
      int c = c8 + j;
      float2 sk = ssk[c], sv = ssv[c];
      kl[t][c >> 4][c & 15] = fmaxf(bf2f(kp[j]) * sk.x + sk.y, 0.f);
      vl[t][c >> 4][c & 15] = fmaxf(bf2f(vp[j]) * sv.x + sv.y, 0.f);
    }
  }
  __syncthreads();
  const int s = tid >> 4, h = tid & 15;
  unsigned short qraw[16];
  size_t qb = (size_t)b * qStride + ((size_t)s * 500 + n) * 256 + h * 16;
  *(uint4*)qraw = *(const uint4*)(qy + qb);
  *(uint4*)(qraw + 8) = *(const uint4*)(qy + qb + 8);
  float qv[16];
#pragma unroll
  for (int c = 0; c < 16; ++c) {
    float2 sq = ssq[h * 16 + c];
    qv[c] = fmaxf(bf2f(qraw[c]) * sq.x + sq.y, 0.f);
  }
  float lg[NK], mx = -1e30f;
#pragma unroll
  for (int t = 0; t < NK; ++t) {
    float d = 0.f;
#pragma unroll
    for (int c = 0; c < 16; ++c) d += qv[c] * kl[t][h][c];
    lg[t] = d * 0.25f;
    mx = fmaxf(mx, lg[t]);
  }
  float sum = 0.f;
#pragma unroll
  for (int t = 0; t < NK; ++t) { lg[t] = __expf(lg[t] - mx); sum += lg[t]; }
  float inv = 1.f / sum;
  float o[16];
#pragma unroll
  for (int c = 0; c < 16; ++c) o[c] = 0.f;
#pragma unroll
  for (int t = 0; t < NK; ++t) {
    float p = lg[t] * inv;
#pragma unroll
    for (int c = 0; c < 16; ++c) o[c] += p * vl[t][h][c];
  }
  size_t ob = (size_t)b * oStride + ((size_t)s * 500 + n) * 256 + h * 16;
  uint4 w0;
  w0.x = pack2(o[0], o[1]); w0.y = pack2(o[2], o[3]);
  w0.z = pack2(o[4], o[5]); w0.w = pack2(o[6], o[7]);
  *(uint4*)(out + ob) = w0;
  w0.x = pack2(o[8], o[9]); w0.y = pack2(o[10], o[11]);
  w0.z = pack2(o[12], o[13]); w0.w = pack2(o[14], o[15]);
  *(uint4*)(out + ob + 8) = w0;
}

// ---------- final: out = X + relu(BN(y)), y fp32 ----------
__global__ __launch_bounds__(256) void bn_relu_addx(
    const float* __restrict__ y, const float2* __restrict__ ss,
    const float* __restrict__ X, float* __restrict__ out) {
  int r = blockIdx.x * 8 + (threadIdx.x >> 5);
  int c8 = (threadIdx.x & 31) * 8;
  size_t idx = (size_t)r * 256 + c8;
  float4 y0 = *(const float4*)(y + idx);
  float4 y1 = *(const float4*)(y + idx + 4);
  float4 x0 = *(const float4*)(X + idx);
  float4 x1 = *(const float4*)(X + idx + 4);
  float yv[8] = {y0.x, y0.y, y0.z, y0.w, y1.x, y1.y, y1.z, y1.w};
  float ov[8];
#pragma unroll
  for (int j = 0; j < 8; ++j) {
    float2 sc = ss[c8 + j];
    ov[j] = fmaxf(yv[j] * sc.x + sc.y, 0.f);
  }
  *(float4*)(out + idx)     = make_float4(x0.x + ov[0], x0.y + ov[1], x0.z + ov[2], x0.w + ov[3]);
  *(float4*)(out + idx + 4) = make_float4(x1.x + ov[4], x1.y + ov[5], x1.z + ov[6], x1.w + ov[7]);
}

// ---------- launcher ----------
extern "C" void kernel_launch(void* const* d_in, const int* in_sizes, int n_in,
                              void* d_out, int out_size, void* d_ws, size_t ws_size,
                              hipStream_t stream) {
  (void)in_sizes; (void)n_in; (void)out_size; (void)ws_size;
  const float* X  = (const float*)d_in[0];
  const float* TE = (const float*)d_in[1];
  const float* SE = (const float*)d_in[2];
  const float* I  = (const float*)d_in[3];
  const float *Wf[8], *Bf[8], *Gf[8], *Zf[8];
  for (int l = 0; l < 8; ++l) {
    Wf[l] = (const float*)d_in[4 + l * 4 + 0];
    Bf[l] = (const float*)d_in[4 + l * 4 + 1];
    Gf[l] = (const float*)d_in[4 + l * 4 + 2];
    Zf[l] = (const float*)d_in[4 + l * 4 + 3];
  }

  char* w = (char*)d_ws;
  size_t off = 0;
  auto alloc = [&](size_t bytes) -> void* {
    void* p = w + off;
    off += (bytes + 255) & ~(size_t)255;
    return p;
  };

  // ---- workspace (total ~330 MB; ws >= 345 MB proven in round 6) ----
  float* psum0 = (float*)alloc((size_t)2000 * 768 * 4);
  float* psq0  = (float*)alloc((size_t)2000 * 768 * 4);
  float* psumK = (float*)alloc((size_t)125 * 256 * 4);
  float* psqK  = (float*)alloc((size_t)125 * 256 * 4);
  float* pp    = (float*)alloc((size_t)128 * 768 * 4);
  float2* ss   = (float2*)alloc((size_t)(8 * 768 + 512) * sizeof(float2));
  float2* ssC  = ss + 8 * 768;   // fused k0|v0 BN (512)
  unsigned short *W0h, *W0l, *W3h, *W3l, *W4h, *W4l, *W7h, *W7l;
  unsigned short *KV0h, *KV0l, *KV1h, *KV1l;
  W0h = (unsigned short*)alloc(196608 * 2); W0l = (unsigned short*)alloc(196608 * 2);
  W3h = (unsigned short*)alloc(196608 * 2); W3l = (unsigned short*)alloc(196608 * 2);
  W4h = (unsigned short*)alloc(196608 * 2); W4l = (unsigned short*)alloc(196608 * 2);
  W7h = (unsigned short*)alloc(65536 * 2);  W7l = (unsigned short*)alloc(65536 * 2);
  KV0h = (unsigned short*)alloc(393216 * 2); KV0l = (unsigned short*)alloc(393216 * 2);
  KV1h = (unsigned short*)alloc(393216 * 2); KV1l = (unsigned short*)alloc(393216 * 2);
  float* b12 = (float*)alloc(512 * 4);
  float* b56 = (float*)alloc(512 * 4);
  // region R: q0 | kv0 | pad  == exactly k1 [256000][256] bf16 later
  char* R = (char*)alloc(131072000);
  unsigned short* q0  = (unsigned short*)R;                    // 16000*256
  unsigned short* kv0 = (unsigned short*)(R + 8192000);        // 96000*512
  unsigned short* k1  = (unsigned short*)R;                    // 256000*256
  unsigned short* o0b = (unsigned short*)alloc(131072000);     // 256000*256 -> v1 -> y7
  unsigned short* v1  = o0b;
  float* y7 = (float*)o0b;
  unsigned short* Hc  = (unsigned short*)alloc((size_t)32000 * 768 * 2);  // CB=2 chunk

  unsigned short* q1 = (unsigned short*)d_out;                 // 96000*256 bf16 (lower half)
  unsigned short* o1 = (unsigned short*)d_out + 24576000;      // 96000*256 bf16 (upper half)

  // ---- prep ----
  cat2<<<dim3(1), 256, 0, stream>>>(Bf[1], Bf[2], b12);
  cat2<<<dim3(1), 256, 0, stream>>>(Bf[5], Bf[6], b56);
  wsplit<<<dim3(96), 256, 0, stream>>>(Wf[0], W0h, W0l, 196608);
  wsplit<<<dim3(96), 256, 0, stream>>>(Wf[3], W3h, W3l, 196608);
  wsplit<<<dim3(96), 256, 0, stream>>>(Wf[4], W4h, W4l, 196608);
  wsplit<<<dim3(32), 256, 0, stream>>>(Wf[7], W7h, W7l, 65536);
  wsplit<<<dim3(96), 256, 0, stream>>>(Wf[1], KV0h, KV0l, 196608);
  wsplit<<<dim3(96), 256, 0, stream>>>(Wf[2], KV0h + 196608, KV0l + 196608, 196608);
  wsplit<<<dim3(96), 256, 0, stream>>>(Wf[5], KV1h, KV1l, 196608);
  wsplit<<<dim3(96), 256, 0, stream>>>(Wf[6], KV1h + 196608, KV1l + 196608, 196608);

  auto bn1 = [&](float* ps, float* pq, const float* g, const float* z, float2* dst,
                 int gridM, int Cout, float invR) {
    bn_part<<<dim3(64, Cout / 64), 512, 0, stream>>>(ps, pq, pp, gridM, Cout);
    bn_fin<<<dim3(Cout / 64), 64, 0, stream>>>(pp, g, z, dst, Cout, invR);
  };

  // ---- stage 1: q0, fused k0|v0, q1 ----
  gemm2<0, 1, 1, 2><<<dim3(125, 2), 256, 0, stream>>>(
      I, nullptr, nullptr, nullptr, W0h, W0l, Bf[0], nullptr,
      q0, nullptr, nullptr, psum0, psq0, 768, 256, 256, 0);
  bn1(psum0, psq0, Gf[0], Zf[0], ss + 0 * 768, 125, 256, 1.f / 16000.f);
  gemm2<1, 1, 1, 2><<<dim3(750, 4), 256, 0, stream>>>(
      nullptr, X, TE, SE, KV0h, KV0l, b12, nullptr,
      kv0, nullptr, nullptr, psum0, psq0, 768, 512, 512, 0);
  bn_part<<<dim3(64, 8), 512, 0, stream>>>(psum0, psq0, pp, 750, 512);
  bn_fin2<<<dim3(8), 64, 0, stream>>>(pp, Gf[1], Zf[1], Gf[2], Zf[2], ssC, 1.f / 96000.f);
  gemm2<1, 1, 1, 2><<<dim3(750, 2), 256, 0, stream>>>(
      nullptr, X, TE, SE, W4h, W4l, Bf[4], nullptr,
      q1, nullptr, nullptr, psum0, psq0, 768, 256, 256, 0);
  bn1(psum0, psq0, Gf[4], Zf[4], ss + 4 * 768, 750, 256, 1.f / 96000.f);

  // ---- attn0 (single launch) -> o0b bf16 ----
  attn_sm<12, 32><<<dim3(500, 16), 512, 0, stream>>>(
      q0, kv0, kv0 + 256, ss + 0 * 768, ssC, ssC + 256, o0b,
      0, (size_t)6000 * 512, (size_t)16000 * 256, 512);

  // ---- m0o stats (one pass, PREC1) ----
  gemm2<2, 0, 1, 1><<<dim3(2000, 6), 256, 0, stream>>>(
      o0b, nullptr, nullptr, nullptr, W3h, W3l, Bf[3], nullptr,
      nullptr, nullptr, nullptr, psum0, psq0, 256, 768, 768, 0);
  bn1(psum0, psq0, Gf[3], Zf[3], ss + 3 * 768, 2000, 768, 1.f / 256000.f);

  // ---- pass B: per 2-batch chunk: H -> fused k1|v1 raw bf16 ----
  for (int cb = 0; cb < 8; ++cb) {
    const size_t oCh = (size_t)cb * 32000 * 256;
    gemm2<2, 2, 0, 2><<<dim3(250, 6), 256, 0, stream>>>(
        o0b + oCh, nullptr, nullptr, nullptr, W3h, W3l, Bf[3], ss + 3 * 768,
        Hc, nullptr, nullptr, nullptr, nullptr, 256, 768, 768, 0);
    gemm2<2, 5, 0, 2><<<dim3(250, 4), 256, 0, stream>>>(
        Hc, nullptr, nullptr, nullptr, KV1h, KV1l, b56, nullptr,
        k1 + oCh, v1 + oCh, nullptr, nullptr, nullptr, 768, 512, 256, 0);
  }

  // ---- m1k / m1v stats from stored raw k1 / v1 ----
  colstats<<<dim3(125), 256, 0, stream>>>(k1, psumK, psqK);
  bn1(psumK, psqK, Gf[5], Zf[5], ss + 5 * 768, 125, 256, 1.f / 256000.f);
  colstats<<<dim3(125), 256, 0, stream>>>(v1, psumK, psqK);
  bn1(psumK, psqK, Gf[6], Zf[6], ss + 6 * 768, 125, 256, 1.f / 256000.f);

  // ---- attn1 (single launch) -> o1 bf16 in d_out upper half ----
  attn_sm<32, 12><<<dim3(500, 16), 192, 0, stream>>>(
      q1, k1, v1, ss + 4 * 768, ss + 5 * 768, ss + 6 * 768, o1,
      (size_t)6000 * 256, (size_t)16000 * 256, (size_t)6000 * 256, 256);

  // ---- m1o -> y7 fp32 (over o0b region) ----
  gemm2<2, 4, 1, 2><<<dim3(750, 2), 256, 0, stream>>>(
      o1, nullptr, nullptr, nullptr, W7h, W7l, Bf[7], nullptr,
      nullptr, nullptr, y7, psum0, psq0, 256, 256, 256, 0);
  bn1(psum0, psq0, Gf[7], Zf[7], ss + 7 * 768, 750, 256, 1.f / 96000.f);
  bn_relu_addx<<<dim3(12000), 256, 0, stream>>>(y7, ss + 7 * 768, X, (float*)d_out);
}

// Round 8
// 4363.297 us; speedup vs baseline: 1.4423x; 1.0062x over previous
//
#include <hip/hip_runtime.h>
#include <stdint.h>

typedef __bf16 bf16_t;
typedef bf16_t bf16x8 __attribute__((ext_vector_type(8)));
typedef float f32x4 __attribute__((ext_vector_type(4)));

__device__ __forceinline__ float bf2f(unsigned short u) {
  union { unsigned int i; float f; } x; x.i = ((unsigned int)u) << 16; return x.f;
}
__device__ __forceinline__ unsigned short f2bf(float f) {
  union { float f; unsigned int i; } x; x.f = f;
  unsigned int r = x.i + 0x7FFFu + ((x.i >> 16) & 1u);
  return (unsigned short)(r >> 16);
}
__device__ __forceinline__ unsigned pack2(float a, float b) {
  return (unsigned)f2bf(a) | ((unsigned)f2bf(b) << 16);
}

// bijective XCD-chunk swizzle (m204): block o (runs on XCD o%8) processes a
// work id from that XCD's contiguous chunk -> same-row column tiles run
// back-to-back on one XCD -> A row-panel L2 reuse.
__device__ __forceinline__ int xcd_map(int o, int n) {
  int q = n >> 3, r = n & 7;
  int x = o & 7, i = o >> 3;
  return (x < r ? x * (q + 1) : r * (q + 1) + (x - r) * q) + i;
}

// concat two 256-ch bias vectors
__global__ void cat2(const float* __restrict__ a, const float* __restrict__ b,
                     float* __restrict__ dst) {
  int i = threadIdx.x;
  dst[i] = a[i]; dst[256 + i] = b[i];
}

// pre-split fp32 weights into hi/lo bf16 planes
__global__ __launch_bounds__(256) void wsplit(
    const float* __restrict__ in, unsigned short* __restrict__ hi,
    unsigned short* __restrict__ lo, int n) {
  int i = (blockIdx.x * 256 + threadIdx.x) * 8;
  if (i >= n) return;
  float4 a = *(const float4*)(in + i);
  float4 b = *(const float4*)(in + i + 4);
  float f[8] = {a.x, a.y, a.z, a.w, b.x, b.y, b.z, b.w};
  unsigned short sh[8], sl[8];
#pragma unroll
  for (int j = 0; j < 8; ++j) {
    sh[j] = f2bf(f[j]);
    sl[j] = f2bf(f[j] - bf2f(sh[j]));
  }
  *(uint4*)(hi + i) = *(uint4*)sh;
  *(uint4*)(lo + i) = *(uint4*)sl;
}

struct f8 { float4 a, b; };

__device__ __forceinline__ f8 ld_c8(const float* __restrict__ X,
                                    const float* __restrict__ TE,
                                    const float* __restrict__ SE,
                                    size_t row, int cc) {
  const float* src = (cc < 256) ? X : ((cc < 512) ? TE : SE);
  const float* p = src + row * 256 + (cc & 255);
  f8 r; r.a = *(const float4*)p; r.b = *(const float4*)(p + 4);
  return r;
}
__device__ __forceinline__ uint4 pack_hi(const float4 a, const float4 b) {
  return make_uint4(pack2(a.x, a.y), pack2(a.z, a.w), pack2(b.x, b.y), pack2(b.z, b.w));
}

// ---------- GEMM: C[M,Cout] = A[M,K]*W[Cout,K]^T + bias ----------
// 1D grid, column-fastest + XCD swizzle; nx = number of 128-col tiles.
// AMODE 0: A fp32. 1: A concat(X,TE,SE) fp32. 2: A bf16 raw.
// PREC 1: ah*bh (stats). 2: ah*(bh+bl).
// SMODE 0: none, 1: raw bf16, 2: relu(BN) bf16, 4: raw fp32,
//         5: dual raw bf16 (cols<256 -> Cb, >=256 -> Cb2; both stride 256).
// PART: per-block column partials (width Cout); cstr = C row stride.
template<int AMODE, int SMODE, int PART, int PREC>
__global__ __launch_bounds__(256) void gemm2(
    const void* __restrict__ Ap, const float* __restrict__ AX,
    const float* __restrict__ ATE, const float* __restrict__ ASE,
    const unsigned short* __restrict__ Wh, const unsigned short* __restrict__ Wl,
    const float* __restrict__ bias, const float2* __restrict__ ssO,
    unsigned short* __restrict__ Cb, unsigned short* __restrict__ Cb2,
    float* __restrict__ Cf, float* __restrict__ psum, float* __restrict__ psq,
    int K, int Cout, int cstr, int pOff, int nx) {
  constexpr int PLANES = (PREC == 2) ? 3 : 2;
  __shared__ unsigned short lds[PLANES * 8192];
  unsigned short* lAh = lds;
  unsigned short* lBh = lds + 8192;
  unsigned short* lBl = lds + (PREC == 2 ? 16384 : 0);
  __shared__ float red[4][64][2];

  const int tid = threadIdx.x;
  const int lane = tid & 63, wid = tid >> 6;
  const int wr = wid >> 1, wc = wid & 1;
  const int l15 = lane & 15, l4 = lane >> 4;
  const int workid = xcd_map(blockIdx.x, gridDim.x);
  const int cy = workid / nx, cx = workid - cy * nx;
  const int brow = cy * 128, bcol = cx * 128;

  f32x4 acc[4][4] = {};

  const int sr = tid >> 3;
  const int sc = (tid & 7) * 8;
  const int sdst = sc ^ ((sr & 7) << 3);

  f8 vaf[4]; uint4 vah[4]; uint4 vbh[4], vbl[4];
  auto loadA = [&](int ci, int cc) {
    size_t ar = (size_t)(brow + ci * 32 + sr);
    if constexpr (AMODE == 2) {
      vah[ci] = *(const uint4*)((const unsigned short*)Ap + ar * K + cc);
    } else if constexpr (AMODE == 0) {
      const float* p = (const float*)Ap + ar * K + cc;
      vaf[ci].a = *(const float4*)p; vaf[ci].b = *(const float4*)(p + 4);
    } else {
      vaf[ci] = ld_c8(AX, ATE, ASE, ar, cc);
    }
  };
  auto loadB = [&](int ci, int cc) {
    size_t wrw = (size_t)(bcol + ci * 32 + sr);
    vbh[ci] = *(const uint4*)(Wh + wrw * K + cc);
    if constexpr (PREC == 2) vbl[ci] = *(const uint4*)(Wl + wrw * K + cc);
  };
#pragma unroll
  for (int ci = 0; ci < 4; ++ci) { loadA(ci, sc); loadB(ci, sc); }

  const int axor = (l15 & 7) << 3;

  for (int kt = 0; kt < K; kt += 64) {
    __syncthreads();
#pragma unroll
    for (int ci = 0; ci < 4; ++ci) {
      int dst = ((ci * 32 + sr) << 6) + sdst;
      if constexpr (AMODE == 2) *(uint4*)(lAh + dst) = vah[ci];
      else                      *(uint4*)(lAh + dst) = pack_hi(vaf[ci].a, vaf[ci].b);
      *(uint4*)(lBh + dst) = vbh[ci];
      if constexpr (PREC == 2) *(uint4*)(lBl + dst) = vbl[ci];
    }
    if (kt + 64 < K) {
      int cc = kt + 64 + sc;
#pragma unroll
      for (int ci = 0; ci < 4; ++ci) { loadA(ci, cc); loadB(ci, cc); }
    }
    __syncthreads();
#pragma unroll
    for (int ks = 0; ks < 2; ++ks) {
      const int cofs = (ks * 32 + l4 * 8) ^ axor;
      bf16x8 afh[4], bfh[4], bfl[4];
#pragma unroll
      for (int m = 0; m < 4; ++m) {
        int o = ((wr * 64 + m * 16 + l15) << 6) + cofs;
        afh[m] = *(const bf16x8*)(lAh + o);
      }
#pragma unroll
      for (int nn = 0; nn < 4; ++nn) {
        int o = ((wc * 64 + nn * 16 + l15) << 6) + cofs;
        bfh[nn] = *(const bf16x8*)(lBh + o);
        if constexpr (PREC == 2) bfl[nn] = *(const bf16x8*)(lBl + o);
      }
#pragma unroll
      for (int m = 0; m < 4; ++m)
#pragma unroll
        for (int nn = 0; nn < 4; ++nn) {
          acc[m][nn] = __builtin_amdgcn_mfma_f32_16x16x32_bf16(afh[m], bfh[nn], acc[m][nn], 0, 0, 0);
          if constexpr (PREC == 2)
            acc[m][nn] = __builtin_amdgcn_mfma_f32_16x16x32_bf16(afh[m], bfl[nn], acc[m][nn], 0, 0, 0);
        }
    }
  }

  float cs[4] = {0.f, 0.f, 0.f, 0.f}, cq[4] = {0.f, 0.f, 0.f, 0.f};
#pragma unroll
  for (int nn = 0; nn < 4; ++nn) {
    int col = bcol + wc * 64 + nn * 16 + l15;
    float bv = bias[col];
    float2 s2 = make_float2(1.f, 0.f);
    if constexpr (SMODE == 2) s2 = ssO[col];
#pragma unroll
    for (int m = 0; m < 4; ++m) {
      int row0 = brow + wr * 64 + m * 16 + l4 * 4;
#pragma unroll
      for (int r = 0; r < 4; ++r) {
        float v = acc[m][nn][r] + bv;
        if constexpr (SMODE == 1) Cb[(size_t)(row0 + r) * cstr + col] = f2bf(v);
        if constexpr (SMODE == 2) Cb[(size_t)(row0 + r) * cstr + col] = f2bf(fmaxf(v * s2.x + s2.y, 0.f));
        if constexpr (SMODE == 4) Cf[(size_t)(row0 + r) * cstr + col] = v;
        if constexpr (SMODE == 5) {
          unsigned short* dst = (col < 256) ? Cb : Cb2;
          dst[(size_t)(row0 + r) * 256 + (col & 255)] = f2bf(v);
        }
        if constexpr (PART) { cs[nn] += v; cq[nn] += v * v; }
      }
    }
  }
  if constexpr (PART) {
#pragma unroll
    for (int nn = 0; nn < 4; ++nn) {
      cs[nn] += __shfl_xor(cs[nn], 16); cs[nn] += __shfl_xor(cs[nn], 32);
      cq[nn] += __shfl_xor(cq[nn], 16); cq[nn] += __shfl_xor(cq[nn], 32);
    }
    __syncthreads();
    if (lane < 16) {
#pragma unroll
      for (int nn = 0; nn < 4; ++nn) {
        red[wid][nn * 16 + lane][0] = cs[nn];
        red[wid][nn * 16 + lane][1] = cq[nn];
      }
    }
    __syncthreads();
    if (tid < 128) {
      int w0 = tid >> 6, cl = tid & 63;
      float s = red[w0][cl][0] + red[w0 + 2][cl][0];
      float q = red[w0][cl][1] + red[w0 + 2][cl][1];
      psum[(size_t)(pOff + cy) * Cout + bcol + tid] = s;
      psq[(size_t)(pOff + cy) * Cout + bcol + tid] = q;
    }
  }
}

// ---------- column stats of a bf16 [rows][256] tensor; 2048 rows/block ----------
__global__ __launch_bounds__(256) void colstats(
    const unsigned short* __restrict__ A, float* __restrict__ psum,
    float* __restrict__ psq) {
  const int tid = threadIdx.x;
  const int r8 = tid >> 5, co = tid & 31;
  float s[8] = {0,0,0,0,0,0,0,0}, q[8] = {0,0,0,0,0,0,0,0};
  size_t base = (size_t)blockIdx.x * 2048;
  for (int it = 0; it < 256; ++it) {
    size_t row = base + it * 8 + r8;
    uint4 v = *(const uint4*)(A + row * 256 + co * 8);
    const unsigned short* pv = (const unsigned short*)&v;
#pragma unroll
    for (int j = 0; j < 8; ++j) {
      float f = bf2f(pv[j]);
      s[j] += f; q[j] += f * f;
    }
  }
  __shared__ float ls[8][32][8], lq[8][32][8];
#pragma unroll
  for (int j = 0; j < 8; ++j) { ls[r8][co][j] = s[j]; lq[r8][co][j] = q[j]; }
  __syncthreads();
  int co2 = tid >> 3, j2 = tid & 7;
  float S = 0.f, Q = 0.f;
#pragma unroll
  for (int r = 0; r < 8; ++r) { S += ls[r][co2][j2]; Q += lq[r][co2][j2]; }
  psum[(size_t)blockIdx.x * 256 + co2 * 8 + j2] = S;
  psq [(size_t)blockIdx.x * 256 + co2 * 8 + j2] = Q;
}

// ---------- BN stats: row-parallel partial + finalize ----------
__global__ __launch_bounds__(512) void bn_part(
    const float* __restrict__ psum, const float* __restrict__ psq,
    float* __restrict__ pp, int gridM, int Cout) {
  const int lane = threadIdx.x & 63, wv = threadIdx.x >> 6;
  const int c = blockIdx.y * 64 + lane;
  float s = 0.f, q = 0.f;
  for (int r = blockIdx.x + 64 * wv; r < gridM; r += 512) {
    s += psum[(size_t)r * Cout + c];
    q += psq[(size_t)r * Cout + c];
  }
  __shared__ float rs[8][64], rq[8][64];
  rs[wv][lane] = s; rq[wv][lane] = q;
  __syncthreads();
  if (threadIdx.x < 64) {
    float S = 0.f, Q = 0.f;
#pragma unroll
    for (int w2 = 0; w2 < 8; ++w2) { S += rs[w2][threadIdx.x]; Q += rq[w2][threadIdx.x]; }
    pp[(size_t)blockIdx.x * Cout + blockIdx.y * 64 + threadIdx.x] = S;
    pp[(size_t)(64 + blockIdx.x) * Cout + blockIdx.y * 64 + threadIdx.x] = Q;
  }
}
__global__ __launch_bounds__(64) void bn_fin(
    const float* __restrict__ pp, const float* __restrict__ g,
    const float* __restrict__ be, float2* __restrict__ ss, int Cout, float invR) {
  int c = blockIdx.x * 64 + threadIdx.x;
  float S = 0.f, Q = 0.f;
  for (int r = 0; r < 64; ++r) {
    S += pp[(size_t)r * Cout + c];
    Q += pp[(size_t)(64 + r) * Cout + c];
  }
  float mu = S * invR, var = Q * invR - mu * mu;
  float sc = g[c] * rsqrtf(var + 1e-5f);
  ss[c] = make_float2(sc, be[c] - mu * sc);
}
__global__ __launch_bounds__(64) void bn_fin2(
    const float* __restrict__ pp, const float* __restrict__ gA,
    const float* __restrict__ zA, const float* __restrict__ gB,
    const float* __restrict__ zB, float2* __restrict__ ssC, float invR) {
  int c = blockIdx.x * 64 + threadIdx.x;  // Cout = 512
  float S = 0.f, Q = 0.f;
  for (int r = 0; r < 64; ++r) {
    S += pp[(size_t)r * 512 + c];
    Q += pp[(size_t)(64 + r) * 512 + c];
  }
  float mu = S * invR, var = Q * invR - mu * mu;
  const float* g = (c < 256) ? gA : gB;
  const float* z = (c < 256) ? zA : zB;
  int ci = c & 255;
  float sc = g[ci] * rsqrtf(var + 1e-5f);
  ssC[c] = make_float2(sc, z[ci] - mu * sc);
}

// ---------- attention: q bf16 (+BN), k/v bf16 (+BN), bf16 out ----------
template<int NK, int NQ>
__global__ void attn_sm(const unsigned short* __restrict__ qy,
                        const unsigned short* __restrict__ ky,
                        const unsigned short* __restrict__ vy,
                        const float2* __restrict__ ssq, const float2* __restrict__ ssk,
                        const float2* __restrict__ ssv, unsigned short* __restrict__ out,
                        size_t qStride, size_t kvStride, size_t oStride, int RS) {
  __shared__ float kl[NK][16][17];
  __shared__ float vl[NK][16][17];
  const int n = blockIdx.x, b = blockIdx.y;
  const int tid = threadIdx.x;
  const unsigned short* kyb = ky + (size_t)b * kvStride;
  const unsigned short* vyb = vy + (size_t)b * kvStride;
  for (int ch = tid; ch < NK * 32; ch += NQ * 16) {
    int t = ch >> 5, c8 = (ch & 31) * 8;
    size_t src = ((size_t)t * 500 + n) * RS + c8;
    uint4 kv = *(const uint4*)(kyb + src);
    uint4 vv = *(const uint4*)(vyb + src);
    const unsigned short* kp = (const unsigned short*)&kv;
    const unsigned short* vp = (const unsigned short*)&vv;
#pragma unroll
    for (int j = 0; j < 8; ++j) {
      int c = c8 + j;
      float2 sk = ssk[c], sv = ssv[c];
      kl[t][c >> 4][c & 15] = fmaxf(bf2f(kp[j]) * sk.x + sk.y, 0.f);
      vl[t][c >> 4][c & 15] = fmaxf(bf2f(vp[j]) * sv.x + sv.y, 0.f);
    }
  }
  __syncthreads();
  const int s = tid >> 4, h = tid & 15;
  unsigned short qraw[16];
  size_t qb = (size_t)b * qStride + ((size_t)s * 500 + n) * 256 + h * 16;
  *(uint4*)qraw = *(const uint4*)(qy + qb);
  *(uint4*)(qraw + 8) = *(const uint4*)(qy + qb + 8);
  float qv[16];
#pragma unroll
  for (int c = 0; c < 16; ++c) {
    float2 sq = ssq[h * 16 + c];
    qv[c] = fmaxf(bf2f(qraw[c]) * sq.x + sq.y, 0.f);
  }
  float lg[NK], mx = -1e30f;
#pragma unroll
  for (int t = 0; t < NK; ++t) {
    float d = 0.f;
#pragma unroll
    for (int c = 0; c < 16; ++c) d += qv[c] * kl[t][h][c];
    lg[t] = d * 0.25f;
    mx = fmaxf(mx, lg[t]);
  }
  float sum = 0.f;
#pragma unroll
  for (int t = 0; t < NK; ++t) { lg[t] = __expf(lg[t] - mx); sum += lg[t]; }
  float inv = 1.f / sum;
  float o[16];
#pragma unroll
  for (int c = 0; c < 16; ++c) o[c] = 0.f;
#pragma unroll
  for (int t = 0; t < NK; ++t) {
    float p = lg[t] * inv;
#pragma unroll
    for (int c = 0; c < 16; ++c) o[c] += p * vl[t][h][c];
  }
  size_t ob = (size_t)b * oStride + ((size_t)s * 500 + n) * 256 + h * 16;
  uint4 w0;
  w0.x = pack2(o[0], o[1]); w0.y = pack2(o[2], o[3]);
  w0.z = pack2(o[4], o[5]); w0.w = pack2(o[6], o[7]);
  *(uint4*)(out + ob) = w0;
  w0.x = pack2(o[8], o[9]); w0.y = pack2(o[10], o[11]);
  w0.z = pack2(o[12], o[13]); w0.w = pack2(o[14], o[15]);
  *(uint4*)(out + ob + 8) = w0;
}

// ---------- final: out = X + relu(BN(y)), y fp32 ----------
__global__ __launch_bounds__(256) void bn_relu_addx(
    const float* __restrict__ y, const float2* __restrict__ ss,
    const float* __restrict__ X, float* __restrict__ out) {
  int r = blockIdx.x * 8 + (threadIdx.x >> 5);
  int c8 = (threadIdx.x & 31) * 8;
  size_t idx = (size_t)r * 256 + c8;
  float4 y0 = *(const float4*)(y + idx);
  float4 y1 = *(const float4*)(y + idx + 4);
  float4 x0 = *(const float4*)(X + idx);
  float4 x1 = *(const float4*)(X + idx + 4);
  float yv[8] = {y0.x, y0.y, y0.z, y0.w, y1.x, y1.y, y1.z, y1.w};
  float ov[8];
#pragma unroll
  for (int j = 0; j < 8; ++j) {
    float2 sc = ss[c8 + j];
    ov[j] = fmaxf(yv[j] * sc.x + sc.y, 0.f);
  }
  *(float4*)(out + idx)     = make_float4(x0.x + ov[0], x0.y + ov[1], x0.z + ov[2], x0.w + ov[3]);
  *(float4*)(out + idx + 4) = make_float4(x1.x + ov[4], x1.y + ov[5], x1.z + ov[6], x1.w + ov[7]);
}

// ---------- launcher ----------
extern "C" void kernel_launch(void* const* d_in, const int* in_sizes, int n_in,
                              void* d_out, int out_size, void* d_ws, size_t ws_size,
                              hipStream_t stream) {
  (void)in_sizes; (void)n_in; (void)out_size; (void)ws_size;
  const float* X  = (const float*)d_in[0];
  const float* TE = (const float*)d_in[1];
  const float* SE = (const float*)d_in[2];
  const float* I  = (const float*)d_in[3];
  const float *Wf[8], *Bf[8], *Gf[8], *Zf[8];
  for (int l = 0; l < 8; ++l) {
    Wf[l] = (const float*)d_in[4 + l * 4 + 0];
    Bf[l] = (const float*)d_in[4 + l * 4 + 1];
    Gf[l] = (const float*)d_in[4 + l * 4 + 2];
    Zf[l] = (const float*)d_in[4 + l * 4 + 3];
  }

  char* w = (char*)d_ws;
  size_t off = 0;
  auto alloc = [&](size_t bytes) -> void* {
    void* p = w + off;
    off += (bytes + 255) & ~(size_t)255;
    return p;
  };

  // ---- workspace (total ~330 MB; ws >= 345 MB proven in round 6) ----
  float* psum0 = (float*)alloc((size_t)2000 * 768 * 4);
  float* psq0  = (float*)alloc((size_t)2000 * 768 * 4);
  float* psumK = (float*)alloc((size_t)125 * 256 * 4);
  float* psqK  = (float*)alloc((size_t)125 * 256 * 4);
  float* pp    = (float*)alloc((size_t)128 * 768 * 4);
  float2* ss   = (float2*)alloc((size_t)(8 * 768 + 512) * sizeof(float2));
  float2* ssC  = ss + 8 * 768;   // fused k0|v0 BN (512)
  unsigned short *W0h, *W0l, *W3h, *W3l, *W4h, *W4l, *W7h, *W7l;
  unsigned short *KV0h, *KV0l, *KV1h, *KV1l;
  W0h = (unsigned short*)alloc(196608 * 2); W0l = (unsigned short*)alloc(196608 * 2);
  W3h = (unsigned short*)alloc(196608 * 2); W3l = (unsigned short*)alloc(196608 * 2);
  W4h = (unsigned short*)alloc(196608 * 2); W4l = (unsigned short*)alloc(196608 * 2);
  W7h = (unsigned short*)alloc(65536 * 2);  W7l = (unsigned short*)alloc(65536 * 2);
  KV0h = (unsigned short*)alloc(393216 * 2); KV0l = (unsigned short*)alloc(393216 * 2);
  KV1h = (unsigned short*)alloc(393216 * 2); KV1l = (unsigned short*)alloc(393216 * 2);
  float* b12 = (float*)alloc(512 * 4);
  float* b56 = (float*)alloc(512 * 4);
  // region R: q0 | kv0 | pad  == exactly k1 [256000][256] bf16 later
  char* R = (char*)alloc(131072000);
  unsigned short* q0  = (unsigned short*)R;                    // 16000*256
  unsigned short* kv0 = (unsigned short*)(R + 8192000);        // 96000*512
  unsigned short* k1  = (unsigned short*)R;                    // 256000*256
  unsigned short* o0b = (unsigned short*)alloc(131072000);     // 256000*256 -> v1 -> y7
  unsigned short* v1  = o0b;
  float* y7 = (float*)o0b;
  unsigned short* Hc  = (unsigned short*)alloc((size_t)32000 * 768 * 2);  // CB=2 chunk

  unsigned short* q1 = (unsigned short*)d_out;                 // 96000*256 bf16 (lower half)
  unsigned short* o1 = (unsigned short*)d_out + 24576000;      // 96000*256 bf16 (upper half)

  // ---- prep ----
  cat2<<<dim3(1), 256, 0, stream>>>(Bf[1], Bf[2], b12);
  cat2<<<dim3(1), 256, 0, stream>>>(Bf[5], Bf[6], b56);
  wsplit<<<dim3(96), 256, 0, stream>>>(Wf[0], W0h, W0l, 196608);
  wsplit<<<dim3(96), 256, 0, stream>>>(Wf[3], W3h, W3l, 196608);
  wsplit<<<dim3(96), 256, 0, stream>>>(Wf[4], W4h, W4l, 196608);
  wsplit<<<dim3(32), 256, 0, stream>>>(Wf[7], W7h, W7l, 65536);
  wsplit<<<dim3(96), 256, 0, stream>>>(Wf[1], KV0h, KV0l, 196608);
  wsplit<<<dim3(96), 256, 0, stream>>>(Wf[2], KV0h + 196608, KV0l + 196608, 196608);
  wsplit<<<dim3(96), 256, 0, stream>>>(Wf[5], KV1h, KV1l, 196608);
  wsplit<<<dim3(96), 256, 0, stream>>>(Wf[6], KV1h + 196608, KV1l + 196608, 196608);

  auto bn1 = [&](float* ps, float* pq, const float* g, const float* z, float2* dst,
                 int gridM, int Cout, float invR) {
    bn_part<<<dim3(64, Cout / 64), 512, 0, stream>>>(ps, pq, pp, gridM, Cout);
    bn_fin<<<dim3(Cout / 64), 64, 0, stream>>>(pp, g, z, dst, Cout, invR);
  };

  // ---- stage 1: q0, fused k0|v0, q1 ----
  gemm2<0, 1, 1, 2><<<dim3(250), 256, 0, stream>>>(
      I, nullptr, nullptr, nullptr, W0h, W0l, Bf[0], nullptr,
      q0, nullptr, nullptr, psum0, psq0, 768, 256, 256, 0, 2);
  bn1(psum0, psq0, Gf[0], Zf[0], ss + 0 * 768, 125, 256, 1.f / 16000.f);
  gemm2<1, 1, 1, 2><<<dim3(3000), 256, 0, stream>>>(
      nullptr, X, TE, SE, KV0h, KV0l, b12, nullptr,
      kv0, nullptr, nullptr, psum0, psq0, 768, 512, 512, 0, 4);
  bn_part<<<dim3(64, 8), 512, 0, stream>>>(psum0, psq0, pp, 750, 512);
  bn_fin2<<<dim3(8), 64, 0, stream>>>(pp, Gf[1], Zf[1], Gf[2], Zf[2], ssC, 1.f / 96000.f);
  gemm2<1, 1, 1, 2><<<dim3(1500), 256, 0, stream>>>(
      nullptr, X, TE, SE, W4h, W4l, Bf[4], nullptr,
      q1, nullptr, nullptr, psum0, psq0, 768, 256, 256, 0, 2);
  bn1(psum0, psq0, Gf[4], Zf[4], ss + 4 * 768, 750, 256, 1.f / 96000.f);

  // ---- attn0 (single launch) -> o0b bf16 ----
  attn_sm<12, 32><<<dim3(500, 16), 512, 0, stream>>>(
      q0, kv0, kv0 + 256, ss + 0 * 768, ssC, ssC + 256, o0b,
      0, (size_t)6000 * 512, (size_t)16000 * 256, 512);

  // ---- m0o stats (one pass, PREC1) ----
  gemm2<2, 0, 1, 1><<<dim3(12000), 256, 0, stream>>>(
      o0b, nullptr, nullptr, nullptr, W3h, W3l, Bf[3], nullptr,
      nullptr, nullptr, nullptr, psum0, psq0, 256, 768, 768, 0, 6);
  bn1(psum0, psq0, Gf[3], Zf[3], ss + 3 * 768, 2000, 768, 1.f / 256000.f);

  // ---- pass B: per 2-batch chunk: H -> fused k1|v1 raw bf16 ----
  for (int cb = 0; cb < 8; ++cb) {
    const size_t oCh = (size_t)cb * 32000 * 256;
    gemm2<2, 2, 0, 2><<<dim3(1500), 256, 0, stream>>>(
        o0b + oCh, nullptr, nullptr, nullptr, W3h, W3l, Bf[3], ss + 3 * 768,
        Hc, nullptr, nullptr, nullptr, nullptr, 256, 768, 768, 0, 6);
    gemm2<2, 5, 0, 2><<<dim3(1000), 256, 0, stream>>>(
        Hc, nullptr, nullptr, nullptr, KV1h, KV1l, b56, nullptr,
        k1 + oCh, v1 + oCh, nullptr, nullptr, nullptr, 768, 512, 256, 0, 4);
  }

  // ---- m1k / m1v stats from stored raw k1 / v1 ----
  colstats<<<dim3(125), 256, 0, stream>>>(k1, psumK, psqK);
  bn1(psumK, psqK, Gf[5], Zf[5], ss + 5 * 768, 125, 256, 1.f / 256000.f);
  colstats<<<dim3(125), 256, 0, stream>>>(v1, psumK, psqK);
  bn1(psumK, psqK, Gf[6], Zf[6], ss + 6 * 768, 125, 256, 1.f / 256000.f);

  // ---- attn1 (single launch) -> o1 bf16 in d_out upper half ----
  attn_sm<32, 12><<<dim3(500, 16), 192, 0, stream>>>(
      q1, k1, v1, ss + 4 * 768, ss + 5 * 768, ss + 6 * 768, o1,
      (size_t)6000 * 256, (size_t)16000 * 256, (size_t)6000 * 256, 256);

  // ---- m1o -> y7 fp32 (over o0b region) ----
  gemm2<2, 4, 1, 2><<<dim3(1500), 256, 0, stream>>>(
      o1, nullptr, nullptr, nullptr, W7h, W7l, Bf[7], nullptr,
      nullptr, nullptr, y7, psum0, psq0, 256, 256, 256, 0, 2);
  bn1(psum0, psq0, Gf[7], Zf[7], ss + 7 * 768, 750, 256, 1.f / 96000.f);
  bn_relu_addx<<<dim3(12000), 256, 0, stream>>>(y7, ss + 7 * 768, X, (float*)d_out);
}

// Round 9
// 4266.297 us; speedup vs baseline: 1.4751x; 1.0227x over previous
//
#include <hip/hip_runtime.h>
#include <stdint.h>

typedef __bf16 bf16_t;
typedef bf16_t bf16x8 __attribute__((ext_vector_type(8)));
typedef float f32x4 __attribute__((ext_vector_type(4)));

__device__ __forceinline__ float bf2f(unsigned short u) {
  union { unsigned int i; float f; } x; x.i = ((unsigned int)u) << 16; return x.f;
}
__device__ __forceinline__ unsigned short f2bf(float f) {
  union { float f; unsigned int i; } x; x.f = f;
  unsigned int r = x.i + 0x7FFFu + ((x.i >> 16) & 1u);
  return (unsigned short)(r >> 16);
}
__device__ __forceinline__ unsigned pack2(float a, float b) {
  return (unsigned)f2bf(a) | ((unsigned)f2bf(b) << 16);
}

// bijective XCD-chunk swizzle (m204)
__device__ __forceinline__ int xcd_map(int o, int n) {
  int q = n >> 3, r = n & 7;
  int x = o & 7, i = o >> 3;
  return (x < r ? x * (q + 1) : r * (q + 1) + (x - r) * q) + i;
}

__global__ void cat2(const float* __restrict__ a, const float* __restrict__ b,
                     float* __restrict__ dst) {
  int i = threadIdx.x;
  dst[i] = a[i]; dst[256 + i] = b[i];
}

__global__ __launch_bounds__(256) void wsplit(
    const float* __restrict__ in, unsigned short* __restrict__ hi,
    unsigned short* __restrict__ lo, int n) {
  int i = (blockIdx.x * 256 + threadIdx.x) * 8;
  if (i >= n) return;
  float4 a = *(const float4*)(in + i);
  float4 b = *(const float4*)(in + i + 4);
  float f[8] = {a.x, a.y, a.z, a.w, b.x, b.y, b.z, b.w};
  unsigned short sh[8], sl[8];
#pragma unroll
  for (int j = 0; j < 8; ++j) {
    sh[j] = f2bf(f[j]);
    sl[j] = f2bf(f[j] - bf2f(sh[j]));
  }
  *(uint4*)(hi + i) = *(uint4*)sh;
  *(uint4*)(lo + i) = *(uint4*)sl;
}

struct f8 { float4 a, b; };

__device__ __forceinline__ f8 ld_c8(const float* __restrict__ X,
                                    const float* __restrict__ TE,
                                    const float* __restrict__ SE,
                                    size_t row, int cc) {
  const float* src = (cc < 256) ? X : ((cc < 512) ? TE : SE);
  const float* p = src + row * 256 + (cc & 255);
  f8 r; r.a = *(const float4*)p; r.b = *(const float4*)(p + 4);
  return r;
}
__device__ __forceinline__ uint4 pack_hi(const float4 a, const float4 b) {
  return make_uint4(pack2(a.x, a.y), pack2(a.z, a.w), pack2(b.x, b.y), pack2(b.z, b.w));
}

// ---------- GEMM: C[M,Cout] = A[M,K]*W[Cout,K]^T + bias ----------
// 1D grid, column-fastest + XCD swizzle; nx = number of 128-col tiles.
// AMODE 0: A fp32. 1: A concat(X,TE,SE) fp32. 2: A bf16 raw.
// PREC 1: ah*bh (stats). 2: ah*(bh+bl).
// SMODE 0: none, 1: raw bf16, 2: relu(BN) bf16,
//         5: dual raw bf16 (bcol<256 -> Cb else Cb2; both row stride 256).
// All stores LDS-staged -> 16B-coalesced (256 B/row bursts).
// PART: per-block column partials (width Cout); cstr = C row stride.
template<int AMODE, int SMODE, int PART, int PREC>
__global__ __launch_bounds__(256) void gemm2(
    const void* __restrict__ Ap, const float* __restrict__ AX,
    const float* __restrict__ ATE, const float* __restrict__ ASE,
    const unsigned short* __restrict__ Wh, const unsigned short* __restrict__ Wl,
    const float* __restrict__ bias, const float2* __restrict__ ssO,
    unsigned short* __restrict__ Cb, unsigned short* __restrict__ Cb2,
    float* __restrict__ psum, float* __restrict__ psq,
    int K, int Cout, int cstr, int pOff, int nx) {
  constexpr int PLANES = (PREC == 2) ? 3 : 2;
  constexpr int LDSN = (SMODE != 0 && PLANES * 8192 < 17408) ? 17408 : PLANES * 8192;
  __shared__ unsigned short lds[LDSN];
  unsigned short* lAh = lds;
  unsigned short* lBh = lds + 8192;
  unsigned short* lBl = lds + (PREC == 2 ? 16384 : 0);
  __shared__ float red[4][64][2];

  const int tid = threadIdx.x;
  const int lane = tid & 63, wid = tid >> 6;
  const int wr = wid >> 1, wc = wid & 1;
  const int l15 = lane & 15, l4 = lane >> 4;
  const int workid = xcd_map(blockIdx.x, gridDim.x);
  const int cy = workid / nx, cx = workid - cy * nx;
  const int brow = cy * 128, bcol = cx * 128;

  f32x4 acc[4][4] = {};

  const int sr = tid >> 3;
  const int sc = (tid & 7) * 8;
  const int sdst = sc ^ ((sr & 7) << 3);

  f8 vaf[4]; uint4 vah[4]; uint4 vbh[4], vbl[4];
  auto loadA = [&](int ci, int cc) {
    size_t ar = (size_t)(brow + ci * 32 + sr);
    if constexpr (AMODE == 2) {
      vah[ci] = *(const uint4*)((const unsigned short*)Ap + ar * K + cc);
    } else if constexpr (AMODE == 0) {
      const float* p = (const float*)Ap + ar * K + cc;
      vaf[ci].a = *(const float4*)p; vaf[ci].b = *(const float4*)(p + 4);
    } else {
      vaf[ci] = ld_c8(AX, ATE, ASE, ar, cc);
    }
  };
  auto loadB = [&](int ci, int cc) {
    size_t wrw = (size_t)(bcol + ci * 32 + sr);
    vbh[ci] = *(const uint4*)(Wh + wrw * K + cc);
    if constexpr (PREC == 2) vbl[ci] = *(const uint4*)(Wl + wrw * K + cc);
  };
#pragma unroll
  for (int ci = 0; ci < 4; ++ci) { loadA(ci, sc); loadB(ci, sc); }

  const int axor = (l15 & 7) << 3;

  for (int kt = 0; kt < K; kt += 64) {
    __syncthreads();
#pragma unroll
    for (int ci = 0; ci < 4; ++ci) {
      int dst = ((ci * 32 + sr) << 6) + sdst;
      if constexpr (AMODE == 2) *(uint4*)(lAh + dst) = vah[ci];
      else                      *(uint4*)(lAh + dst) = pack_hi(vaf[ci].a, vaf[ci].b);
      *(uint4*)(lBh + dst) = vbh[ci];
      if constexpr (PREC == 2) *(uint4*)(lBl + dst) = vbl[ci];
    }
    if (kt + 64 < K) {
      int cc = kt + 64 + sc;
#pragma unroll
      for (int ci = 0; ci < 4; ++ci) { loadA(ci, cc); loadB(ci, cc); }
    }
    __syncthreads();
#pragma unroll
    for (int ks = 0; ks < 2; ++ks) {
      const int cofs = (ks * 32 + l4 * 8) ^ axor;
      bf16x8 afh[4], bfh[4], bfl[4];
#pragma unroll
      for (int m = 0; m < 4; ++m) {
        int o = ((wr * 64 + m * 16 + l15) << 6) + cofs;
        afh[m] = *(const bf16x8*)(lAh + o);
      }
#pragma unroll
      for (int nn = 0; nn < 4; ++nn) {
        int o = ((wc * 64 + nn * 16 + l15) << 6) + cofs;
        bfh[nn] = *(const bf16x8*)(lBh + o);
        if constexpr (PREC == 2) bfl[nn] = *(const bf16x8*)(lBl + o);
      }
#pragma unroll
      for (int m = 0; m < 4; ++m)
#pragma unroll
        for (int nn = 0; nn < 4; ++nn) {
          acc[m][nn] = __builtin_amdgcn_mfma_f32_16x16x32_bf16(afh[m], bfh[nn], acc[m][nn], 0, 0, 0);
          if constexpr (PREC == 2)
            acc[m][nn] = __builtin_amdgcn_mfma_f32_16x16x32_bf16(afh[m], bfl[nn], acc[m][nn], 0, 0, 0);
        }
    }
  }

  // ---- epilogue: fragments -> LDS tile -> coalesced 16B stores ----
  if constexpr (SMODE != 0) __syncthreads();   // staging LDS is now free
  float cs[4] = {0.f, 0.f, 0.f, 0.f}, cq[4] = {0.f, 0.f, 0.f, 0.f};
#pragma unroll
  for (int nn = 0; nn < 4; ++nn) {
    int colL = wc * 64 + nn * 16 + l15;
    int col = bcol + colL;
    float bv = bias[col];
    float2 s2 = make_float2(1.f, 0.f);
    if constexpr (SMODE == 2) s2 = ssO[col];
#pragma unroll
    for (int m = 0; m < 4; ++m) {
      int rowL0 = wr * 64 + m * 16 + l4 * 4;
#pragma unroll
      for (int r = 0; r < 4; ++r) {
        float v = acc[m][nn][r] + bv;
        if constexpr (PART) { cs[nn] += v; cq[nn] += v * v; }
        if constexpr (SMODE == 2) v = fmaxf(v * s2.x + s2.y, 0.f);
        if constexpr (SMODE != 0) lds[(rowL0 + r) * 136 + colL] = f2bf(v);
      }
    }
  }
  if constexpr (SMODE != 0) {
    __syncthreads();
    const int rw = tid >> 4, ln8 = (tid & 15) * 8;
#pragma unroll
    for (int it = 0; it < 8; ++it) {
      int rr = it * 16 + rw;
      uint4 val = *(const uint4*)(lds + rr * 136 + ln8);
      if constexpr (SMODE == 5) {
        unsigned short* dst = (bcol < 256) ? Cb : Cb2;
        *(uint4*)(dst + (size_t)(brow + rr) * 256 + (bcol & 255) + ln8) = val;
      } else {
        *(uint4*)(Cb + (size_t)(brow + rr) * cstr + bcol + ln8) = val;
      }
    }
  }
  if constexpr (PART) {
#pragma unroll
    for (int nn = 0; nn < 4; ++nn) {
      cs[nn] += __shfl_xor(cs[nn], 16); cs[nn] += __shfl_xor(cs[nn], 32);
      cq[nn] += __shfl_xor(cq[nn], 16); cq[nn] += __shfl_xor(cq[nn], 32);
    }
    __syncthreads();
    if (lane < 16) {
#pragma unroll
      for (int nn = 0; nn < 4; ++nn) {
        red[wid][nn * 16 + lane][0] = cs[nn];
        red[wid][nn * 16 + lane][1] = cq[nn];
      }
    }
    __syncthreads();
    if (tid < 128) {
      int w0 = tid >> 6, cl = tid & 63;
      float s = red[w0][cl][0] + red[w0 + 2][cl][0];
      float q = red[w0][cl][1] + red[w0 + 2][cl][1];
      psum[(size_t)(pOff + cy) * Cout + bcol + tid] = s;
      psq[(size_t)(pOff + cy) * Cout + bcol + tid] = q;
    }
  }
}

// ---------- column stats of a bf16 [rows][256] tensor; 2048 rows/block ----------
__global__ __launch_bounds__(256) void colstats(
    const unsigned short* __restrict__ A, float* __restrict__ psum,
    float* __restrict__ psq) {
  const int tid = threadIdx.x;
  const int r8 = tid >> 5, co = tid & 31;
  float s[8] = {0,0,0,0,0,0,0,0}, q[8] = {0,0,0,0,0,0,0,0};
  size_t base = (size_t)blockIdx.x * 2048;
  for (int it = 0; it < 256; ++it) {
    size_t row = base + it * 8 + r8;
    uint4 v = *(const uint4*)(A + row * 256 + co * 8);
    const unsigned short* pv = (const unsigned short*)&v;
#pragma unroll
    for (int j = 0; j < 8; ++j) {
      float f = bf2f(pv[j]);
      s[j] += f; q[j] += f * f;
    }
  }
  __shared__ float ls[8][32][8], lq[8][32][8];
#pragma unroll
  for (int j = 0; j < 8; ++j) { ls[r8][co][j] = s[j]; lq[r8][co][j] = q[j]; }
  __syncthreads();
  int co2 = tid >> 3, j2 = tid & 7;
  float S = 0.f, Q = 0.f;
#pragma unroll
  for (int r = 0; r < 8; ++r) { S += ls[r][co2][j2]; Q += lq[r][co2][j2]; }
  psum[(size_t)blockIdx.x * 256 + co2 * 8 + j2] = S;
  psq [(size_t)blockIdx.x * 256 + co2 * 8 + j2] = Q;
}

// ---------- BN stats: row-parallel partial + finalize ----------
__global__ __launch_bounds__(512) void bn_part(
    const float* __restrict__ psum, const float* __restrict__ psq,
    float* __restrict__ pp, int gridM, int Cout) {
  const int lane = threadIdx.x & 63, wv = threadIdx.x >> 6;
  const int c = blockIdx.y * 64 + lane;
  float s = 0.f, q = 0.f;
  for (int r = blockIdx.x + 64 * wv; r < gridM; r += 512) {
    s += psum[(size_t)r * Cout + c];
    q += psq[(size_t)r * Cout + c];
  }
  __shared__ float rs[8][64], rq[8][64];
  rs[wv][lane] = s; rq[wv][lane] = q;
  __syncthreads();
  if (threadIdx.x < 64) {
    float S = 0.f, Q = 0.f;
#pragma unroll
    for (int w2 = 0; w2 < 8; ++w2) { S += rs[w2][threadIdx.x]; Q += rq[w2][threadIdx.x]; }
    pp[(size_t)blockIdx.x * Cout + blockIdx.y * 64 + threadIdx.x] = S;
    pp[(size_t)(64 + blockIdx.x) * Cout + blockIdx.y * 64 + threadIdx.x] = Q;
  }
}
__global__ __launch_bounds__(64) void bn_fin(
    const float* __restrict__ pp, const float* __restrict__ g,
    const float* __restrict__ be, float2* __restrict__ ss, int Cout, float invR) {
  int c = blockIdx.x * 64 + threadIdx.x;
  float S = 0.f, Q = 0.f;
  for (int r = 0; r < 64; ++r) {
    S += pp[(size_t)r * Cout + c];
    Q += pp[(size_t)(64 + r) * Cout + c];
  }
  float mu = S * invR, var = Q * invR - mu * mu;
  float sc = g[c] * rsqrtf(var + 1e-5f);
  ss[c] = make_float2(sc, be[c] - mu * sc);
}
__global__ __launch_bounds__(64) void bn_fin2(
    const float* __restrict__ pp, const float* __restrict__ gA,
    const float* __restrict__ zA, const float* __restrict__ gB,
    const float* __restrict__ zB, float2* __restrict__ ssC, float invR) {
  int c = blockIdx.x * 64 + threadIdx.x;  // Cout = 512
  float S = 0.f, Q = 0.f;
  for (int r = 0; r < 64; ++r) {
    S += pp[(size_t)r * 512 + c];
    Q += pp[(size_t)(64 + r) * 512 + c];
  }
  float mu = S * invR, var = Q * invR - mu * mu;
  const float* g = (c < 256) ? gA : gB;
  const float* z = (c < 256) ? zA : zB;
  int ci = c & 255;
  float sc = g[ci] * rsqrtf(var + 1e-5f);
  ssC[c] = make_float2(sc, z[ci] - mu * sc);
}

// ---------- attention: q bf16 (+BN), k/v bf16 (+BN), bf16 out ----------
template<int NK, int NQ>
__global__ void attn_sm(const unsigned short* __restrict__ qy,
                        const unsigned short* __restrict__ ky,
                        const unsigned short* __restrict__ vy,
                        const float2* __restrict__ ssq, const float2* __restrict__ ssk,
                        const float2* __restrict__ ssv, unsigned short* __restrict__ out,
                        size_t qStride, size_t kvStride, size_t oStride, int RS) {
  __shared__ float kl[NK][16][17];
  __shared__ float vl[NK][16][17];
  const int n = blockIdx.x, b = blockIdx.y;
  const int tid = threadIdx.x;
  const unsigned short* kyb = ky + (size_t)b * kvStride;
  const unsigned short* vyb = vy + (size_t)b * kvStride;
  for (int ch = tid; ch < NK * 32; ch += NQ * 16) {
    int t = ch >> 5, c8 = (ch & 31) * 8;
    size_t src = ((size_t)t * 500 + n) * RS + c8;
    uint4 kv = *(const uint4*)(kyb + src);
    uint4 vv = *(const uint4*)(vyb + src);
    const unsigned short* kp = (const unsigned short*)&kv;
    const unsigned short* vp = (const unsigned short*)&vv;
#pragma unroll
    for (int j = 0; j < 8; ++j) {
      int c = c8 + j;
      float2 sk = ssk[c], sv = ssv[c];
      kl[t][c >> 4][c & 15] = fmaxf(bf2f(kp[j]) * sk.x + sk.y, 0.f);
      vl[t][c >> 4][c & 15] = fmaxf(bf2f(vp[j]) * sv.x + sv.y, 0.f);
    }
  }
  __syncthreads();
  const int s = tid >> 4, h = tid & 15;
  unsigned short qraw[16];
  size_t qb = (size_t)b * qStride + ((size_t)s * 500 + n) * 256 + h * 16;
  *(uint4*)qraw = *(const uint4*)(qy + qb);
  *(uint4*)(qraw + 8) = *(const uint4*)(qy + qb + 8);
  float qv[16];
#pragma unroll
  for (int c = 0; c < 16; ++c) {
    float2 sq = ssq[h * 16 + c];
    qv[c] = fmaxf(bf2f(qraw[c]) * sq.x + sq.y, 0.f);
  }
  float lg[NK], mx = -1e30f;
#pragma unroll
  for (int t = 0; t < NK; ++t) {
    float d = 0.f;
#pragma unroll
    for (int c = 0; c < 16; ++c) d += qv[c] * kl[t][h][c];
    lg[t] = d * 0.25f;
    mx = fmaxf(mx, lg[t]);
  }
  float sum = 0.f;
#pragma unroll
  for (int t = 0; t < NK; ++t) { lg[t] = __expf(lg[t] - mx); sum += lg[t]; }
  float inv = 1.f / sum;
  float o[16];
#pragma unroll
  for (int c = 0; c < 16; ++c) o[c] = 0.f;
#pragma unroll
  for (int t = 0; t < NK; ++t) {
    float p = lg[t] * inv;
#pragma unroll
    for (int c = 0; c < 16; ++c) o[c] += p * vl[t][h][c];
  }
  size_t ob = (size_t)b * oStride + ((size_t)s * 500 + n) * 256 + h * 16;
  uint4 w0;
  w0.x = pack2(o[0], o[1]); w0.y = pack2(o[2], o[3]);
  w0.z = pack2(o[4], o[5]); w0.w = pack2(o[6], o[7]);
  *(uint4*)(out + ob) = w0;
  w0.x = pack2(o[8], o[9]); w0.y = pack2(o[10], o[11]);
  w0.z = pack2(o[12], o[13]); w0.w = pack2(o[14], o[15]);
  *(uint4*)(out + ob + 8) = w0;
}

// ---------- final: out = X + relu(BN(y)), y bf16 ----------
__global__ __launch_bounds__(256) void bn_relu_addx(
    const unsigned short* __restrict__ y, const float2* __restrict__ ss,
    const float* __restrict__ X, float* __restrict__ out) {
  int r = blockIdx.x * 8 + (threadIdx.x >> 5);
  int c8 = (threadIdx.x & 31) * 8;
  size_t idx = (size_t)r * 256 + c8;
  uint4 yv4 = *(const uint4*)(y + idx);
  const unsigned short* yv = (const unsigned short*)&yv4;
  float4 x0 = *(const float4*)(X + idx);
  float4 x1 = *(const float4*)(X + idx + 4);
  float ov[8];
#pragma unroll
  for (int j = 0; j < 8; ++j) {
    float2 sc = ss[c8 + j];
    ov[j] = fmaxf(bf2f(yv[j]) * sc.x + sc.y, 0.f);
  }
  *(float4*)(out + idx)     = make_float4(x0.x + ov[0], x0.y + ov[1], x0.z + ov[2], x0.w + ov[3]);
  *(float4*)(out + idx + 4) = make_float4(x1.x + ov[4], x1.y + ov[5], x1.z + ov[6], x1.w + ov[7]);
}

// ---------- launcher ----------
extern "C" void kernel_launch(void* const* d_in, const int* in_sizes, int n_in,
                              void* d_out, int out_size, void* d_ws, size_t ws_size,
                              hipStream_t stream) {
  (void)in_sizes; (void)n_in; (void)out_size; (void)ws_size;
  const float* X  = (const float*)d_in[0];
  const float* TE = (const float*)d_in[1];
  const float* SE = (const float*)d_in[2];
  const float* I  = (const float*)d_in[3];
  const float *Wf[8], *Bf[8], *Gf[8], *Zf[8];
  for (int l = 0; l < 8; ++l) {
    Wf[l] = (const float*)d_in[4 + l * 4 + 0];
    Bf[l] = (const float*)d_in[4 + l * 4 + 1];
    Gf[l] = (const float*)d_in[4 + l * 4 + 2];
    Zf[l] = (const float*)d_in[4 + l * 4 + 3];
  }

  char* w = (char*)d_ws;
  size_t off = 0;
  auto alloc = [&](size_t bytes) -> void* {
    void* p = w + off;
    off += (bytes + 255) & ~(size_t)255;
    return p;
  };

  // ---- workspace (~330 MB; ws >= 345 MB proven) ----
  float* psum0 = (float*)alloc((size_t)2000 * 768 * 4);
  float* psq0  = (float*)alloc((size_t)2000 * 768 * 4);
  float* psumK = (float*)alloc((size_t)125 * 256 * 4);
  float* psqK  = (float*)alloc((size_t)125 * 256 * 4);
  float* pp    = (float*)alloc((size_t)128 * 768 * 4);
  float2* ss   = (float2*)alloc((size_t)(8 * 768 + 512) * sizeof(float2));
  float2* ssC  = ss + 8 * 768;
  unsigned short *W0h, *W0l, *W3h, *W3l, *W4h, *W4l, *W7h, *W7l;
  unsigned short *KV0h, *KV0l, *KV1h, *KV1l;
  W0h = (unsigned short*)alloc(196608 * 2); W0l = (unsigned short*)alloc(196608 * 2);
  W3h = (unsigned short*)alloc(196608 * 2); W3l = (unsigned short*)alloc(196608 * 2);
  W4h = (unsigned short*)alloc(196608 * 2); W4l = (unsigned short*)alloc(196608 * 2);
  W7h = (unsigned short*)alloc(65536 * 2);  W7l = (unsigned short*)alloc(65536 * 2);
  KV0h = (unsigned short*)alloc(393216 * 2); KV0l = (unsigned short*)alloc(393216 * 2);
  KV1h = (unsigned short*)alloc(393216 * 2); KV1l = (unsigned short*)alloc(393216 * 2);
  float* b12 = (float*)alloc(512 * 4);
  float* b56 = (float*)alloc(512 * 4);
  // region R: q0 | kv0 | pad  == exactly k1 [256000][256] bf16 later
  char* R = (char*)alloc(131072000);
  unsigned short* q0  = (unsigned short*)R;                    // 16000*256
  unsigned short* kv0 = (unsigned short*)(R + 8192000);        // 96000*512
  unsigned short* k1  = (unsigned short*)R;                    // 256000*256
  unsigned short* o0b = (unsigned short*)alloc(131072000);     // 256000*256 -> v1 -> y7
  unsigned short* v1  = o0b;
  unsigned short* y7  = o0b;
  unsigned short* Hc  = (unsigned short*)alloc((size_t)32000 * 768 * 2);  // CB=2 chunk

  unsigned short* q1 = (unsigned short*)d_out;                 // bf16 (lower half)
  unsigned short* o1 = (unsigned short*)d_out + 24576000;      // bf16 (upper half)

  // ---- prep ----
  cat2<<<dim3(1), 256, 0, stream>>>(Bf[1], Bf[2], b12);
  cat2<<<dim3(1), 256, 0, stream>>>(Bf[5], Bf[6], b56);
  wsplit<<<dim3(96), 256, 0, stream>>>(Wf[0], W0h, W0l, 196608);
  wsplit<<<dim3(96), 256, 0, stream>>>(Wf[3], W3h, W3l, 196608);
  wsplit<<<dim3(96), 256, 0, stream>>>(Wf[4], W4h, W4l, 196608);
  wsplit<<<dim3(32), 256, 0, stream>>>(Wf[7], W7h, W7l, 65536);
  wsplit<<<dim3(96), 256, 0, stream>>>(Wf[1], KV0h, KV0l, 196608);
  wsplit<<<dim3(96), 256, 0, stream>>>(Wf[2], KV0h + 196608, KV0l + 196608, 196608);
  wsplit<<<dim3(96), 256, 0, stream>>>(Wf[5], KV1h, KV1l, 196608);
  wsplit<<<dim3(96), 256, 0, stream>>>(Wf[6], KV1h + 196608, KV1l + 196608, 196608);

  auto bn1 = [&](float* ps, float* pq, const float* g, const float* z, float2* dst,
                 int gridM, int Cout, float invR) {
    bn_part<<<dim3(64, Cout / 64), 512, 0, stream>>>(ps, pq, pp, gridM, Cout);
    bn_fin<<<dim3(Cout / 64), 64, 0, stream>>>(pp, g, z, dst, Cout, invR);
  };

  // ---- stage 1: q0, fused k0|v0, q1 ----
  gemm2<0, 1, 1, 2><<<dim3(250), 256, 0, stream>>>(
      I, nullptr, nullptr, nullptr, W0h, W0l, Bf[0], nullptr,
      q0, nullptr, psum0, psq0, 768, 256, 256, 0, 2);
  bn1(psum0, psq0, Gf[0], Zf[0], ss + 0 * 768, 125, 256, 1.f / 16000.f);
  gemm2<1, 1, 1, 2><<<dim3(3000), 256, 0, stream>>>(
      nullptr, X, TE, SE, KV0h, KV0l, b12, nullptr,
      kv0, nullptr, psum0, psq0, 768, 512, 512, 0, 4);
  bn_part<<<dim3(64, 8), 512, 0, stream>>>(psum0, psq0, pp, 750, 512);
  bn_fin2<<<dim3(8), 64, 0, stream>>>(pp, Gf[1], Zf[1], Gf[2], Zf[2], ssC, 1.f / 96000.f);
  gemm2<1, 1, 1, 2><<<dim3(1500), 256, 0, stream>>>(
      nullptr, X, TE, SE, W4h, W4l, Bf[4], nullptr,
      q1, nullptr, psum0, psq0, 768, 256, 256, 0, 2);
  bn1(psum0, psq0, Gf[4], Zf[4], ss + 4 * 768, 750, 256, 1.f / 96000.f);

  // ---- attn0 (single launch) -> o0b bf16 ----
  attn_sm<12, 32><<<dim3(500, 16), 512, 0, stream>>>(
      q0, kv0, kv0 + 256, ss + 0 * 768, ssC, ssC + 256, o0b,
      0, (size_t)6000 * 512, (size_t)16000 * 256, 512);

  // ---- m0o stats (one pass, PREC1) ----
  gemm2<2, 0, 1, 1><<<dim3(12000), 256, 0, stream>>>(
      o0b, nullptr, nullptr, nullptr, W3h, W3l, Bf[3], nullptr,
      nullptr, nullptr, psum0, psq0, 256, 768, 768, 0, 6);
  bn1(psum0, psq0, Gf[3], Zf[3], ss + 3 * 768, 2000, 768, 1.f / 256000.f);

  // ---- pass B: per 2-batch chunk: H -> fused k1|v1 raw bf16 ----
  for (int cb = 0; cb < 8; ++cb) {
    const size_t oCh = (size_t)cb * 32000 * 256;
    gemm2<2, 2, 0, 2><<<dim3(1500), 256, 0, stream>>>(
        o0b + oCh, nullptr, nullptr, nullptr, W3h, W3l, Bf[3], ss + 3 * 768,
        Hc, nullptr, nullptr, nullptr, 256, 768, 768, 0, 6);
    gemm2<2, 5, 0, 2><<<dim3(1000), 256, 0, stream>>>(
        Hc, nullptr, nullptr, nullptr, KV1h, KV1l, b56, nullptr,
        k1 + oCh, v1 + oCh, nullptr, nullptr, 768, 512, 256, 0, 4);
  }

  // ---- m1k / m1v stats from stored raw k1 / v1 ----
  colstats<<<dim3(125), 256, 0, stream>>>(k1, psumK, psqK);
  bn1(psumK, psqK, Gf[5], Zf[5], ss + 5 * 768, 125, 256, 1.f / 256000.f);
  colstats<<<dim3(125), 256, 0, stream>>>(v1, psumK, psqK);
  bn1(psumK, psqK, Gf[6], Zf[6], ss + 6 * 768, 125, 256, 1.f / 256000.f);

  // ---- attn1 (single launch) -> o1 bf16 in d_out upper half ----
  attn_sm<32, 12><<<dim3(500, 16), 192, 0, stream>>>(
      q1, k1, v1, ss + 4 * 768, ss + 5 * 768, ss + 6 * 768, o1,
      (size_t)6000 * 256, (size_t)16000 * 256, (size_t)6000 * 256, 256);

  // ---- m1o -> y7 bf16 (over o0b region) ----
  gemm2<2, 1, 1, 2><<<dim3(1500), 256, 0, stream>>>(
      o1, nullptr, nullptr, nullptr, W7h, W7l, Bf[7], nullptr,
      y7, nullptr, psum0, psq0, 256, 256, 256, 0, 2);
  bn1(psum0, psq0, Gf[7], Zf[7], ss + 7 * 768, 750, 256, 1.f / 96000.f);
  bn_relu_addx<<<dim3(12000), 256, 0, stream>>>(y7, ss + 7 * 768, X, (float*)d_out);
}

// Round 10
// 3862.753 us; speedup vs baseline: 1.6292x; 1.1045x over previous
//
#include <hip/hip_runtime.h>
#include <stdint.h>

typedef __bf16 bf16_t;
typedef bf16_t bf16x8 __attribute__((ext_vector_type(8)));
typedef float f32x4 __attribute__((ext_vector_type(4)));

__device__ __forceinline__ float bf2f(unsigned short u) {
  union { unsigned int i; float f; } x; x.i = ((unsigned int)u) << 16; return x.f;
}
__device__ __forceinline__ unsigned short f2bf(float f) {
  union { float f; unsigned int i; } x; x.f = f;
  unsigned int r = x.i + 0x7FFFu + ((x.i >> 16) & 1u);
  return (unsigned short)(r >> 16);
}
__device__ __forceinline__ unsigned pack2(float a, float b) {
  return (unsigned)f2bf(a) | ((unsigned)f2bf(b) << 16);
}

__global__ void cat2(const float* __restrict__ a, const float* __restrict__ b,
                     float* __restrict__ dst) {
  int i = threadIdx.x;
  dst[i] = a[i]; dst[256 + i] = b[i];
}

__global__ __launch_bounds__(256) void wsplit(
    const float* __restrict__ in, unsigned short* __restrict__ hi,
    unsigned short* __restrict__ lo, int n) {
  int i = (blockIdx.x * 256 + threadIdx.x) * 8;
  if (i >= n) return;
  float4 a = *(const float4*)(in + i);
  float4 b = *(const float4*)(in + i + 4);
  float f[8] = {a.x, a.y, a.z, a.w, b.x, b.y, b.z, b.w};
  unsigned short sh[8], sl[8];
#pragma unroll
  for (int j = 0; j < 8; ++j) {
    sh[j] = f2bf(f[j]);
    sl[j] = f2bf(f[j] - bf2f(sh[j]));
  }
  *(uint4*)(hi + i) = *(uint4*)sh;
  *(uint4*)(lo + i) = *(uint4*)sl;
}

struct f8 { float4 a, b; };

__device__ __forceinline__ f8 ld_c8(const float* __restrict__ X,
                                    const float* __restrict__ TE,
                                    const float* __restrict__ SE,
                                    size_t row, int cc) {
  const float* src = (cc < 256) ? X : ((cc < 512) ? TE : SE);
  const float* p = src + row * 256 + (cc & 255);
  f8 r; r.a = *(const float4*)p; r.b = *(const float4*)(p + 4);
  return r;
}
__device__ __forceinline__ uint4 pack_hi(const float4 a, const float4 b) {
  return make_uint4(pack2(a.x, a.y), pack2(a.z, a.w), pack2(b.x, b.y), pack2(b.z, b.w));
}

// ---------- A-panel-resident GEMM: C[M,Cout] = A[M,K]*W[Cout,K]^T + bias ----
// Block owns 64 rows; A panel staged to LDS ONCE (bf16 hi); loops nx col
// tiles internally. A HBM traffic = exact; B comes from L2 (shared by all).
// AMODE 0: A fp32. 1: A concat(X,TE,SE) fp32. 2: A bf16 raw.
// PREC 1: ah*bh (stats). 2: ah*(bh+bl).
// SMODE 0: none, 1: raw bf16, 2: relu(BN) bf16,
//         5: dual raw bf16 (bcol<256 -> Cb else Cb2; both row stride 256).
// PART: per-block column partials (width Cout); cstr = C row stride.
template<int AMODE, int SMODE, int PART, int PREC, int K>
__global__ __launch_bounds__(256) void gemm3(
    const void* __restrict__ Ap, const float* __restrict__ AX,
    const float* __restrict__ ATE, const float* __restrict__ ASE,
    const unsigned short* __restrict__ Wh, const unsigned short* __restrict__ Wl,
    const float* __restrict__ bias, const float2* __restrict__ ssO,
    unsigned short* __restrict__ Cb, unsigned short* __restrict__ Cb2,
    float* __restrict__ psum, float* __restrict__ psq,
    int Cout, int cstr, int pOff, int nx) {
  constexpr int BM = 64;
  constexpr int ASH = BM * K;                          // A panel (shorts)
  constexpr int BSH = 128 * 64 * (PREC == 2 ? 2 : 1);  // B tile hi(+lo)
  __shared__ unsigned short lds[ASH + BSH];
  unsigned short* lA  = lds;
  unsigned short* lBh = lds + ASH;
  unsigned short* lBl = lds + ASH + 8192;              // PREC2 only

  const int tid = threadIdx.x;
  const int lane = tid & 63, wid = tid >> 6;
  const int l15 = lane & 15, l4 = lane >> 4;
  const int brow = blockIdx.x * BM;

  // ---- stage A panel once ----
  constexpr int CPR = K / 8;
#pragma unroll
  for (int i = 0; i < (BM * CPR) / 256; ++i) {
    int ch = i * 256 + tid;
    int row = ch / CPR, c8 = (ch % CPR) * 8;
    uint4 hv;
    if constexpr (AMODE == 2) {
      hv = *(const uint4*)((const unsigned short*)Ap + (size_t)(brow + row) * K + c8);
    } else if constexpr (AMODE == 0) {
      const float* p = (const float*)Ap + (size_t)(brow + row) * K + c8;
      hv = pack_hi(*(const float4*)p, *(const float4*)(p + 4));
    } else {
      f8 v = ld_c8(AX, ATE, ASE, (size_t)(brow + row), c8);
      hv = pack_hi(v.a, v.b);
    }
    int dst = row * K + (c8 & ~63) + ((c8 & 63) ^ ((row & 7) << 3));
    *(uint4*)(lA + dst) = hv;
  }

  const int sr = tid >> 3;            // 0..31
  const int sc = (tid & 7) * 8;       // 0..56
  const int sdst = sc ^ ((sr & 7) << 3);
  const int axor = (l15 & 7) << 3;

  uint4 vbh[4], vbl[4];
  auto loadB = [&](int bcol, int kt) {
#pragma unroll
    for (int ci = 0; ci < 4; ++ci) {
      size_t wrw = (size_t)(bcol + ci * 32 + sr);
      vbh[ci] = *(const uint4*)(Wh + wrw * K + kt * 64 + sc);
      if constexpr (PREC == 2) vbl[ci] = *(const uint4*)(Wl + wrw * K + kt * 64 + sc);
    }
  };

  for (int cx = 0; cx < nx; ++cx) {
    const int bcol = cx * 128;
    f32x4 acc[4][2] = {};
    loadB(bcol, 0);
    for (int kt = 0; kt < K / 64; ++kt) {
      __syncthreads();
#pragma unroll
      for (int ci = 0; ci < 4; ++ci) {
        int dst = ((ci * 32 + sr) << 6) + sdst;
        *(uint4*)(lBh + dst) = vbh[ci];
        if constexpr (PREC == 2) *(uint4*)(lBl + dst) = vbl[ci];
      }
      if (kt + 1 < K / 64) loadB(bcol, kt + 1);
      __syncthreads();
#pragma unroll
      for (int ks = 0; ks < 2; ++ks) {
        const int cofs = (ks * 32 + l4 * 8) ^ axor;
        bf16x8 af[4], bfh[2], bfl[2];
#pragma unroll
        for (int m = 0; m < 4; ++m)
          af[m] = *(const bf16x8*)(lA + (m * 16 + l15) * K + kt * 64 + cofs);
#pragma unroll
        for (int nn = 0; nn < 2; ++nn) {
          int o = ((wid * 32 + nn * 16 + l15) << 6) + cofs;
          bfh[nn] = *(const bf16x8*)(lBh + o);
          if constexpr (PREC == 2) bfl[nn] = *(const bf16x8*)(lBl + o);
        }
#pragma unroll
        for (int m = 0; m < 4; ++m)
#pragma unroll
          for (int nn = 0; nn < 2; ++nn) {
            acc[m][nn] = __builtin_amdgcn_mfma_f32_16x16x32_bf16(af[m], bfh[nn], acc[m][nn], 0, 0, 0);
            if constexpr (PREC == 2)
              acc[m][nn] = __builtin_amdgcn_mfma_f32_16x16x32_bf16(af[m], bfl[nn], acc[m][nn], 0, 0, 0);
          }
      }
    }

    // ---- epilogue for this col tile ----
    float cs[2] = {0.f, 0.f}, cq[2] = {0.f, 0.f};
    if constexpr (SMODE != 0) __syncthreads();   // B LDS reads done; reuse as C tile
#pragma unroll
    for (int nn = 0; nn < 2; ++nn) {
      int colL = wid * 32 + nn * 16 + l15;
      int col = bcol + colL;
      float bv = bias[col];
      float2 s2 = make_float2(1.f, 0.f);
      if constexpr (SMODE == 2) s2 = ssO[col];
#pragma unroll
      for (int m = 0; m < 4; ++m) {
        int rowL0 = m * 16 + l4 * 4;
#pragma unroll
        for (int r = 0; r < 4; ++r) {
          float v = acc[m][nn][r] + bv;
          if constexpr (PART) { cs[nn] += v; cq[nn] += v * v; }
          if constexpr (SMODE == 2) v = fmaxf(v * s2.x + s2.y, 0.f);
          if constexpr (SMODE != 0) lBh[(rowL0 + r) * 136 + colL] = f2bf(v);
        }
      }
    }
    if constexpr (SMODE != 0) {
      __syncthreads();
      const int rw = tid >> 4, ln8 = (tid & 15) * 8;
#pragma unroll
      for (int it = 0; it < 4; ++it) {
        int rr = it * 16 + rw;
        uint4 val = *(const uint4*)(lBh + rr * 136 + ln8);
        if constexpr (SMODE == 5) {
          unsigned short* dst = (bcol < 256) ? Cb : Cb2;
          *(uint4*)(dst + (size_t)(brow + rr) * 256 + (bcol & 255) + ln8) = val;
        } else {
          *(uint4*)(Cb + (size_t)(brow + rr) * cstr + bcol + ln8) = val;
        }
      }
    }
    if constexpr (PART) {
#pragma unroll
      for (int nn = 0; nn < 2; ++nn) {
        cs[nn] += __shfl_xor(cs[nn], 16); cs[nn] += __shfl_xor(cs[nn], 32);
        cq[nn] += __shfl_xor(cq[nn], 16); cq[nn] += __shfl_xor(cq[nn], 32);
      }
      if (l4 == 0) {
#pragma unroll
        for (int nn = 0; nn < 2; ++nn) {
          size_t pidx = (size_t)(pOff + blockIdx.x) * Cout + bcol + wid * 32 + nn * 16 + l15;
          psum[pidx] = cs[nn];
          psq[pidx]  = cq[nn];
        }
      }
    }
  }
}

// ---------- column stats of a bf16 [rows][256] tensor; 2048 rows/block ----------
__global__ __launch_bounds__(256) void colstats(
    const unsigned short* __restrict__ A, float* __restrict__ psum,
    float* __restrict__ psq) {
  const int tid = threadIdx.x;
  const int r8 = tid >> 5, co = tid & 31;
  float s[8] = {0,0,0,0,0,0,0,0}, q[8] = {0,0,0,0,0,0,0,0};
  size_t base = (size_t)blockIdx.x * 2048;
  for (int it = 0; it < 256; ++it) {
    size_t row = base + it * 8 + r8;
    uint4 v = *(const uint4*)(A + row * 256 + co * 8);
    const unsigned short* pv = (const unsigned short*)&v;
#pragma unroll
    for (int j = 0; j < 8; ++j) {
      float f = bf2f(pv[j]);
      s[j] += f; q[j] += f * f;
    }
  }
  __shared__ float ls[8][32][8], lq[8][32][8];
#pragma unroll
  for (int j = 0; j < 8; ++j) { ls[r8][co][j] = s[j]; lq[r8][co][j] = q[j]; }
  __syncthreads();
  int co2 = tid >> 3, j2 = tid & 7;
  float S = 0.f, Q = 0.f;
#pragma unroll
  for (int r = 0; r < 8; ++r) { S += ls[r][co2][j2]; Q += lq[r][co2][j2]; }
  psum[(size_t)blockIdx.x * 256 + co2 * 8 + j2] = S;
  psq [(size_t)blockIdx.x * 256 + co2 * 8 + j2] = Q;
}

// ---------- BN stats: row-parallel partial + finalize ----------
__global__ __launch_bounds__(512) void bn_part(
    const float* __restrict__ psum, const float* __restrict__ psq,
    float* __restrict__ pp, int gridM, int Cout) {
  const int lane = threadIdx.x & 63, wv = threadIdx.x >> 6;
  const int c = blockIdx.y * 64 + lane;
  float s = 0.f, q = 0.f;
  for (int r = blockIdx.x + 64 * wv; r < gridM; r += 512) {
    s += psum[(size_t)r * Cout + c];
    q += psq[(size_t)r * Cout + c];
  }
  __shared__ float rs[8][64], rq[8][64];
  rs[wv][lane] = s; rq[wv][lane] = q;
  __syncthreads();
  if (threadIdx.x < 64) {
    float S = 0.f, Q = 0.f;
#pragma unroll
    for (int w2 = 0; w2 < 8; ++w2) { S += rs[w2][threadIdx.x]; Q += rq[w2][threadIdx.x]; }
    pp[(size_t)blockIdx.x * Cout + blockIdx.y * 64 + threadIdx.x] = S;
    pp[(size_t)(64 + blockIdx.x) * Cout + blockIdx.y * 64 + threadIdx.x] = Q;
  }
}
__global__ __launch_bounds__(64) void bn_fin(
    const float* __restrict__ pp, const float* __restrict__ g,
    const float* __restrict__ be, float2* __restrict__ ss, int Cout, float invR) {
  int c = blockIdx.x * 64 + threadIdx.x;
  float S = 0.f, Q = 0.f;
  for (int r = 0; r < 64; ++r) {
    S += pp[(size_t)r * Cout + c];
    Q += pp[(size_t)(64 + r) * Cout + c];
  }
  float mu = S * invR, var = Q * invR - mu * mu;
  float sc = g[c] * rsqrtf(var + 1e-5f);
  ss[c] = make_float2(sc, be[c] - mu * sc);
}
__global__ __launch_bounds__(64) void bn_fin2(
    const float* __restrict__ pp, const float* __restrict__ gA,
    const float* __restrict__ zA, const float* __restrict__ gB,
    const float* __restrict__ zB, float2* __restrict__ ssC, float invR) {
  int c = blockIdx.x * 64 + threadIdx.x;  // Cout = 512
  float S = 0.f, Q = 0.f;
  for (int r = 0; r < 64; ++r) {
    S += pp[(size_t)r * 512 + c];
    Q += pp[(size_t)(64 + r) * 512 + c];
  }
  float mu = S * invR, var = Q * invR - mu * mu;
  const float* g = (c < 256) ? gA : gB;
  const float* z = (c < 256) ? zA : zB;
  int ci = c & 255;
  float sc = g[ci] * rsqrtf(var + 1e-5f);
  ssC[c] = make_float2(sc, z[ci] - mu * sc);
}

// ---------- attention: q bf16 (+BN), k/v bf16 (+BN), bf16 out ----------
template<int NK, int NQ>
__global__ void attn_sm(const unsigned short* __restrict__ qy,
                        const unsigned short* __restrict__ ky,
                        const unsigned short* __restrict__ vy,
                        const float2* __restrict__ ssq, const float2* __restrict__ ssk,
                        const float2* __restrict__ ssv, unsigned short* __restrict__ out,
                        size_t qStride, size_t kvStride, size_t oStride, int RS) {
  __shared__ float kl[NK][16][17];
  __shared__ float vl[NK][16][17];
  const int n = blockIdx.x, b = blockIdx.y;
  const int tid = threadIdx.x;
  const unsigned short* kyb = ky + (size_t)b * kvStride;
  const unsigned short* vyb = vy + (size_t)b * kvStride;
  for (int ch = tid; ch < NK * 32; ch += NQ * 16) {
    int t = ch >> 5, c8 = (ch & 31) * 8;
    size_t src = ((size_t)t * 500 + n) * RS + c8;
    uint4 kv = *(const uint4*)(kyb + src);
    uint4 vv = *(const uint4*)(vyb + src);
    const unsigned short* kp = (const unsigned short*)&kv;
    const unsigned short* vp = (const unsigned short*)&vv;
#pragma unroll
    for (int j = 0; j < 8; ++j) {
      int c = c8 + j;
      float2 sk = ssk[c], sv = ssv[c];
      kl[t][c >> 4][c & 15] = fmaxf(bf2f(kp[j]) * sk.x + sk.y, 0.f);
      vl[t][c >> 4][c & 15] = fmaxf(bf2f(vp[j]) * sv.x + sv.y, 0.f);
    }
  }
  __syncthreads();
  const int s = tid >> 4, h = tid & 15;
  unsigned short qraw[16];
  size_t qb = (size_t)b * qStride + ((size_t)s * 500 + n) * 256 + h * 16;
  *(uint4*)qraw = *(const uint4*)(qy + qb);
  *(uint4*)(qraw + 8) = *(const uint4*)(qy + qb + 8);
  float qv[16];
#pragma unroll
  for (int c = 0; c < 16; ++c) {
    float2 sq = ssq[h * 16 + c];
    qv[c] = fmaxf(bf2f(qraw[c]) * sq.x + sq.y, 0.f);
  }
  float lg[NK], mx = -1e30f;
#pragma unroll
  for (int t = 0; t < NK; ++t) {
    float d = 0.f;
#pragma unroll
    for (int c = 0; c < 16; ++c) d += qv[c] * kl[t][h][c];
    lg[t] = d * 0.25f;
    mx = fmaxf(mx, lg[t]);
  }
  float sum = 0.f;
#pragma unroll
  for (int t = 0; t < NK; ++t) { lg[t] = __expf(lg[t] - mx); sum += lg[t]; }
  float inv = 1.f / sum;
  float o[16];
#pragma unroll
  for (int c = 0; c < 16; ++c) o[c] = 0.f;
#pragma unroll
  for (int t = 0; t < NK; ++t) {
    float p = lg[t] * inv;
#pragma unroll
    for (int c = 0; c < 16; ++c) o[c] += p * vl[t][h][c];
  }
  size_t ob = (size_t)b * oStride + ((size_t)s * 500 + n) * 256 + h * 16;
  uint4 w0;
  w0.x = pack2(o[0], o[1]); w0.y = pack2(o[2], o[3]);
  w0.z = pack2(o[4], o[5]); w0.w = pack2(o[6], o[7]);
  *(uint4*)(out + ob) = w0;
  w0.x = pack2(o[8], o[9]); w0.y = pack2(o[10], o[11]);
  w0.z = pack2(o[12], o[13]); w0.w = pack2(o[14], o[15]);
  *(uint4*)(out + ob + 8) = w0;
}

// ---------- final: out = X + relu(BN(y)), y bf16 ----------
__global__ __launch_bounds__(256) void bn_relu_addx(
    const unsigned short* __restrict__ y, const float2* __restrict__ ss,
    const float* __restrict__ X, float* __restrict__ out) {
  int r = blockIdx.x * 8 + (threadIdx.x >> 5);
  int c8 = (threadIdx.x & 31) * 8;
  size_t idx = (size_t)r * 256 + c8;
  uint4 yv4 = *(const uint4*)(y + idx);
  const unsigned short* yv = (const unsigned short*)&yv4;
  float4 x0 = *(const float4*)(X + idx);
  float4 x1 = *(const float4*)(X + idx + 4);
  float ov[8];
#pragma unroll
  for (int j = 0; j < 8; ++j) {
    float2 sc = ss[c8 + j];
    ov[j] = fmaxf(bf2f(yv[j]) * sc.x + sc.y, 0.f);
  }
  *(float4*)(out + idx)     = make_float4(x0.x + ov[0], x0.y + ov[1], x0.z + ov[2], x0.w + ov[3]);
  *(float4*)(out + idx + 4) = make_float4(x1.x + ov[4], x1.y + ov[5], x1.z + ov[6], x1.w + ov[7]);
}

// ---------- launcher ----------
extern "C" void kernel_launch(void* const* d_in, const int* in_sizes, int n_in,
                              void* d_out, int out_size, void* d_ws, size_t ws_size,
                              hipStream_t stream) {
  (void)in_sizes; (void)n_in; (void)out_size; (void)ws_size;
  const float* X  = (const float*)d_in[0];
  const float* TE = (const float*)d_in[1];
  const float* SE = (const float*)d_in[2];
  const float* I  = (const float*)d_in[3];
  const float *Wf[8], *Bf[8], *Gf[8], *Zf[8];
  for (int l = 0; l < 8; ++l) {
    Wf[l] = (const float*)d_in[4 + l * 4 + 0];
    Bf[l] = (const float*)d_in[4 + l * 4 + 1];
    Gf[l] = (const float*)d_in[4 + l * 4 + 2];
    Zf[l] = (const float*)d_in[4 + l * 4 + 3];
  }

  char* w = (char*)d_ws;
  size_t off = 0;
  auto alloc = [&](size_t bytes) -> void* {
    void* p = w + off;
    off += (bytes + 255) & ~(size_t)255;
    return p;
  };

  // ---- workspace (~342 MB; ws >= 345 MB proven) ----
  float* psum0 = (float*)alloc((size_t)4000 * 768 * 4);
  float* psq0  = (float*)alloc((size_t)4000 * 768 * 4);
  float* psumK = (float*)alloc((size_t)125 * 256 * 4);
  float* psqK  = (float*)alloc((size_t)125 * 256 * 4);
  float* pp    = (float*)alloc((size_t)128 * 768 * 4);
  float2* ss   = (float2*)alloc((size_t)(8 * 768 + 512) * sizeof(float2));
  float2* ssC  = ss + 8 * 768;
  unsigned short *W0h, *W0l, *W3h, *W3l, *W4h, *W4l, *W7h, *W7l;
  unsigned short *KV0h, *KV0l, *KV1h, *KV1l;
  W0h = (unsigned short*)alloc(196608 * 2); W0l = (unsigned short*)alloc(196608 * 2);
  W3h = (unsigned short*)alloc(196608 * 2); W3l = (unsigned short*)alloc(196608 * 2);
  W4h = (unsigned short*)alloc(196608 * 2); W4l = (unsigned short*)alloc(196608 * 2);
  W7h = (unsigned short*)alloc(65536 * 2);  W7l = (unsigned short*)alloc(65536 * 2);
  KV0h = (unsigned short*)alloc(393216 * 2); KV0l = (unsigned short*)alloc(393216 * 2);
  KV1h = (unsigned short*)alloc(393216 * 2); KV1l = (unsigned short*)alloc(393216 * 2);
  float* b12 = (float*)alloc(512 * 4);
  float* b56 = (float*)alloc(512 * 4);
  // region R: q0 | kv0 | pad  == exactly k1 [256000][256] bf16 later
  char* R = (char*)alloc(131072000);
  unsigned short* q0  = (unsigned short*)R;                    // 16000*256
  unsigned short* kv0 = (unsigned short*)(R + 8192000);        // 96000*512
  unsigned short* k1  = (unsigned short*)R;                    // 256000*256
  unsigned short* o0b = (unsigned short*)alloc(131072000);     // 256000*256 -> v1 -> y7
  unsigned short* v1  = o0b;
  unsigned short* y7  = o0b;
  unsigned short* Hc  = (unsigned short*)alloc((size_t)32000 * 768 * 2);  // 2-batch chunk

  unsigned short* q1 = (unsigned short*)d_out;                 // bf16 (lower half)
  unsigned short* o1 = (unsigned short*)d_out + 24576000;      // bf16 (upper half)

  // ---- prep ----
  cat2<<<dim3(1), 256, 0, stream>>>(Bf[1], Bf[2], b12);
  cat2<<<dim3(1), 256, 0, stream>>>(Bf[5], Bf[6], b56);
  wsplit<<<dim3(96), 256, 0, stream>>>(Wf[0], W0h, W0l, 196608);
  wsplit<<<dim3(96), 256, 0, stream>>>(Wf[3], W3h, W3l, 196608);
  wsplit<<<dim3(96), 256, 0, stream>>>(Wf[4], W4h, W4l, 196608);
  wsplit<<<dim3(32), 256, 0, stream>>>(Wf[7], W7h, W7l, 65536);
  wsplit<<<dim3(96), 256, 0, stream>>>(Wf[1], KV0h, KV0l, 196608);
  wsplit<<<dim3(96), 256, 0, stream>>>(Wf[2], KV0h + 196608, KV0l + 196608, 196608);
  wsplit<<<dim3(96), 256, 0, stream>>>(Wf[5], KV1h, KV1l, 196608);
  wsplit<<<dim3(96), 256, 0, stream>>>(Wf[6], KV1h + 196608, KV1l + 196608, 196608);

  auto bn1 = [&](float* ps, float* pq, const float* g, const float* z, float2* dst,
                 int gridM, int Cout, float invR) {
    bn_part<<<dim3(64, Cout / 64), 512, 0, stream>>>(ps, pq, pp, gridM, Cout);
    bn_fin<<<dim3(Cout / 64), 64, 0, stream>>>(pp, g, z, dst, Cout, invR);
  };

  // ---- stage 1: q0, fused k0|v0, q1 ----
  gemm3<0, 1, 1, 2, 768><<<dim3(250), 256, 0, stream>>>(
      I, nullptr, nullptr, nullptr, W0h, W0l, Bf[0], nullptr,
      q0, nullptr, psum0, psq0, 256, 256, 0, 2);
  bn1(psum0, psq0, Gf[0], Zf[0], ss + 0 * 768, 250, 256, 1.f / 16000.f);
  gemm3<1, 1, 1, 2, 768><<<dim3(1500), 256, 0, stream>>>(
      nullptr, X, TE, SE, KV0h, KV0l, b12, nullptr,
      kv0, nullptr, psum0, psq0, 512, 512, 0, 4);
  bn_part<<<dim3(64, 8), 512, 0, stream>>>(psum0, psq0, pp, 1500, 512);
  bn_fin2<<<dim3(8), 64, 0, stream>>>(pp, Gf[1], Zf[1], Gf[2], Zf[2], ssC, 1.f / 96000.f);
  gemm3<1, 1, 1, 2, 768><<<dim3(1500), 256, 0, stream>>>(
      nullptr, X, TE, SE, W4h, W4l, Bf[4], nullptr,
      q1, nullptr, psum0, psq0, 256, 256, 0, 2);
  bn1(psum0, psq0, Gf[4], Zf[4], ss + 4 * 768, 1500, 256, 1.f / 96000.f);

  // ---- attn0 (single launch) -> o0b bf16 ----
  attn_sm<12, 32><<<dim3(500, 16), 512, 0, stream>>>(
      q0, kv0, kv0 + 256, ss + 0 * 768, ssC, ssC + 256, o0b,
      0, (size_t)6000 * 512, (size_t)16000 * 256, 512);

  // ---- m0o stats (one pass, PREC1) ----
  gemm3<2, 0, 1, 1, 256><<<dim3(4000), 256, 0, stream>>>(
      o0b, nullptr, nullptr, nullptr, W3h, W3l, Bf[3], nullptr,
      nullptr, nullptr, psum0, psq0, 768, 768, 0, 6);
  bn1(psum0, psq0, Gf[3], Zf[3], ss + 3 * 768, 4000, 768, 1.f / 256000.f);

  // ---- pass B: per 2-batch chunk: H -> fused k1|v1 raw bf16 ----
  for (int cb = 0; cb < 8; ++cb) {
    const size_t oCh = (size_t)cb * 32000 * 256;
    gemm3<2, 2, 0, 2, 256><<<dim3(500), 256, 0, stream>>>(
        o0b + oCh, nullptr, nullptr, nullptr, W3h, W3l, Bf[3], ss + 3 * 768,
        Hc, nullptr, nullptr, nullptr, 768, 768, 0, 6);
    gemm3<2, 5, 0, 2, 768><<<dim3(500), 256, 0, stream>>>(
        Hc, nullptr, nullptr, nullptr, KV1h, KV1l, b56, nullptr,
        k1 + oCh, v1 + oCh, nullptr, nullptr, 512, 256, 0, 4);
  }

  // ---- m1k / m1v stats from stored raw k1 / v1 ----
  colstats<<<dim3(125), 256, 0, stream>>>(k1, psumK, psqK);
  bn1(psumK, psqK, Gf[5], Zf[5], ss + 5 * 768, 125, 256, 1.f / 256000.f);
  colstats<<<dim3(125), 256, 0, stream>>>(v1, psumK, psqK);
  bn1(psumK, psqK, Gf[6], Zf[6], ss + 6 * 768, 125, 256, 1.f / 256000.f);

  // ---- attn1 (single launch) -> o1 bf16 in d_out upper half ----
  attn_sm<32, 12><<<dim3(500, 16), 192, 0, stream>>>(
      q1, k1, v1, ss + 4 * 768, ss + 5 * 768, ss + 6 * 768, o1,
      (size_t)6000 * 256, (size_t)16000 * 256, (size_t)6000 * 256, 256);

  // ---- m1o -> y7 bf16 (over o0b region) ----
  gemm3<2, 1, 1, 2, 256><<<dim3(1500), 256, 0, stream>>>(
      o1, nullptr, nullptr, nullptr, W7h, W7l, Bf[7], nullptr,
      y7, nullptr, psum0, psq0, 256, 256, 0, 2);
  bn1(psum0, psq0, Gf[7], Zf[7], ss + 7 * 768, 1500, 256, 1.f / 96000.f);
  bn_relu_addx<<<dim3(12000), 256, 0, stream>>>(y7, ss + 7 * 768, X, (float*)d_out);
}

// Round 11
// 3336.247 us; speedup vs baseline: 1.8863x; 1.1578x over previous
//
#include <hip/hip_runtime.h>
#include <stdint.h>

typedef __bf16 bf16_t;
typedef bf16_t bf16x8 __attribute__((ext_vector_type(8)));
typedef float f32x4 __attribute__((ext_vector_type(4)));

__device__ __forceinline__ float bf2f(unsigned short u) {
  union { unsigned int i; float f; } x; x.i = ((unsigned int)u) << 16; return x.f;
}
__device__ __forceinline__ unsigned short f2bf(float f) {
  union { float f; unsigned int i; } x; x.f = f;
  unsigned int r = x.i + 0x7FFFu + ((x.i >> 16) & 1u);
  return (unsigned short)(r >> 16);
}
__device__ __forceinline__ unsigned pack2(float a, float b) {
  return (unsigned)f2bf(a) | ((unsigned)f2bf(b) << 16);
}

__global__ void cat2(const float* __restrict__ a, const float* __restrict__ b,
                     float* __restrict__ dst) {
  int i = threadIdx.x;
  dst[i] = a[i]; dst[256 + i] = b[i];
}

__global__ __launch_bounds__(256) void wsplit(
    const float* __restrict__ in, unsigned short* __restrict__ hi,
    unsigned short* __restrict__ lo, int n) {
  int i = (blockIdx.x * 256 + threadIdx.x) * 8;
  if (i >= n) return;
  float4 a = *(const float4*)(in + i);
  float4 b = *(const float4*)(in + i + 4);
  float f[8] = {a.x, a.y, a.z, a.w, b.x, b.y, b.z, b.w};
  unsigned short sh[8], sl[8];
#pragma unroll
  for (int j = 0; j < 8; ++j) {
    sh[j] = f2bf(f[j]);
    sl[j] = f2bf(f[j] - bf2f(sh[j]));
  }
  *(uint4*)(hi + i) = *(uint4*)sh;
  *(uint4*)(lo + i) = *(uint4*)sl;
}

struct f8 { float4 a, b; };

__device__ __forceinline__ f8 ld_c8(const float* __restrict__ X,
                                    const float* __restrict__ TE,
                                    const float* __restrict__ SE,
                                    size_t row, int cc) {
  const float* src = (cc < 256) ? X : ((cc < 512) ? TE : SE);
  const float* p = src + row * 256 + (cc & 255);
  f8 r; r.a = *(const float4*)p; r.b = *(const float4*)(p + 4);
  return r;
}
__device__ __forceinline__ uint4 pack_hi(const float4 a, const float4 b) {
  return make_uint4(pack2(a.x, a.y), pack2(a.z, a.w), pack2(b.x, b.y), pack2(b.z, b.w));
}

// ---------- A-panel-resident GEMM, 8 waves ----------
// Block owns 64 rows; A panel staged to LDS once (bf16 hi, XOR-swizzled);
// loops nx col tiles; wave w computes cols [w*16, w*16+16).
// AMODE 0: A fp32. 1: A concat(X,TE,SE) fp32. 2: A bf16 raw.
// PREC 1: ah*bh. 2: ah*(bh+bl). 3: lo-plane only for bcol>=256 (SMODE5 k|v).
// SMODE 0: none, 1: raw bf16, 2: relu(BN) bf16,
//         5: dual raw bf16 (bcol<256 -> Cb else Cb2; both row stride 256).
// PART: per-block column partials (width Cout); cstr = C row stride.
template<int AMODE, int SMODE, int PART, int PREC, int K>
__global__ __launch_bounds__(512) void gemm4(
    const void* __restrict__ Ap, const float* __restrict__ AX,
    const float* __restrict__ ATE, const float* __restrict__ ASE,
    const unsigned short* __restrict__ Wh, const unsigned short* __restrict__ Wl,
    const float* __restrict__ bias, const float2* __restrict__ ssO,
    unsigned short* __restrict__ Cb, unsigned short* __restrict__ Cb2,
    float* __restrict__ psum, float* __restrict__ psq,
    int Cout, int cstr, int pOff, int nx) {
  constexpr int ASH = 64 * K;
  constexpr int BSH = 128 * 64 * (PREC >= 2 ? 2 : 1);
  __shared__ unsigned short lds[ASH + BSH];
  unsigned short* lA  = lds;
  unsigned short* lBh = lds + ASH;
  unsigned short* lBl = lds + ASH + 8192;   // PREC>=2 only

  const int tid = threadIdx.x;
  const int lane = tid & 63, wid = tid >> 6;   // 8 waves
  const int l15 = lane & 15, l4 = lane >> 4;
  const int brow = blockIdx.x * 64;

  // ---- stage A panel once (swizzled within 64-elem K groups) ----
  constexpr int CPR = K / 8;
#pragma unroll
  for (int i = 0; i < (64 * CPR) / 512; ++i) {
    int ch = i * 512 + tid;
    int row = ch / CPR, c8 = (ch % CPR) * 8;
    uint4 hv;
    if constexpr (AMODE == 2) {
      hv = *(const uint4*)((const unsigned short*)Ap + (size_t)(brow + row) * K + c8);
    } else if constexpr (AMODE == 0) {
      const float* p = (const float*)Ap + (size_t)(brow + row) * K + c8;
      hv = pack_hi(*(const float4*)p, *(const float4*)(p + 4));
    } else {
      f8 v = ld_c8(AX, ATE, ASE, (size_t)(brow + row), c8);
      hv = pack_hi(v.a, v.b);
    }
    int dst = row * K + (c8 & ~63) + ((c8 & 63) ^ ((row & 7) << 3));
    *(uint4*)(lA + dst) = hv;
  }

  const int sr = tid >> 3;            // 0..63
  const int sc = (tid & 7) * 8;       // 0..56
  const int sdst = sc ^ ((sr & 7) << 3);
  const int axor = (l15 & 7) << 3;

  uint4 vbh[2], vbl[2];
  auto loadB = [&](int bcol, int kt) {
#pragma unroll
    for (int ci = 0; ci < 2; ++ci) {
      size_t wrw = (size_t)(bcol + ci * 64 + sr);
      vbh[ci] = *(const uint4*)(Wh + wrw * K + kt * 64 + sc);
      if constexpr (PREC >= 2) vbl[ci] = *(const uint4*)(Wl + wrw * K + kt * 64 + sc);
    }
  };

  for (int cx = 0; cx < nx; ++cx) {
    const int bcol = cx * 128;
    const bool useLo = (PREC == 2) || (PREC == 3 && bcol >= 256);
    f32x4 acc[4] = {};
    loadB(bcol, 0);
    for (int kt = 0; kt < K / 64; ++kt) {
      __syncthreads();
#pragma unroll
      for (int ci = 0; ci < 2; ++ci) {
        int dst = ((ci * 64 + sr) << 6) + sdst;
        *(uint4*)(lBh + dst) = vbh[ci];
        if constexpr (PREC >= 2) *(uint4*)(lBl + dst) = vbl[ci];
      }
      if (kt + 1 < K / 64) loadB(bcol, kt + 1);
      __syncthreads();
#pragma unroll
      for (int ks = 0; ks < 2; ++ks) {
        const int cofs = (ks * 32 + l4 * 8) ^ axor;
        bf16x8 af[4];
#pragma unroll
        for (int m = 0; m < 4; ++m)
          af[m] = *(const bf16x8*)(lA + (m * 16 + l15) * K + kt * 64 + cofs);
        const int o = ((wid * 16 + l15) << 6) + cofs;
        bf16x8 bh = *(const bf16x8*)(lBh + o);
#pragma unroll
        for (int m = 0; m < 4; ++m)
          acc[m] = __builtin_amdgcn_mfma_f32_16x16x32_bf16(af[m], bh, acc[m], 0, 0, 0);
        if constexpr (PREC >= 2) {
          if (useLo) {
            bf16x8 bl = *(const bf16x8*)(lBl + o);
#pragma unroll
            for (int m = 0; m < 4; ++m)
              acc[m] = __builtin_amdgcn_mfma_f32_16x16x32_bf16(af[m], bl, acc[m], 0, 0, 0);
          }
        }
      }
    }

    // ---- epilogue for this col tile ----
    float cs = 0.f, cq = 0.f;
    const int colL = wid * 16 + l15;
    const int col = bcol + colL;
    float bv = bias[col];
    float2 s2 = make_float2(1.f, 0.f);
    if constexpr (SMODE == 2) s2 = ssO[col];
    if constexpr (SMODE != 0) __syncthreads();   // all B reads done; reuse lBh as C tile
#pragma unroll
    for (int m = 0; m < 4; ++m) {
#pragma unroll
      for (int r = 0; r < 4; ++r) {
        float v = acc[m][r] + bv;
        if constexpr (PART) { cs += v; cq += v * v; }
        if constexpr (SMODE == 2) v = fmaxf(v * s2.x + s2.y, 0.f);
        if constexpr (SMODE != 0) lBh[(m * 16 + l4 * 4 + r) * 136 + colL] = f2bf(v);
      }
    }
    if constexpr (SMODE != 0) {
      __syncthreads();
      const int rw = tid >> 4, c16 = (tid & 15) * 8;
#pragma unroll
      for (int it = 0; it < 2; ++it) {
        int rr = it * 32 + rw;
        uint4 val = *(const uint4*)(lBh + rr * 136 + c16);
        if constexpr (SMODE == 5) {
          unsigned short* dst = (bcol < 256) ? Cb : Cb2;
          *(uint4*)(dst + (size_t)(brow + rr) * 256 + (bcol & 255) + c16) = val;
        } else {
          *(uint4*)(Cb + (size_t)(brow + rr) * cstr + bcol + c16) = val;
        }
      }
    }
    if constexpr (PART) {
      cs += __shfl_xor(cs, 16); cs += __shfl_xor(cs, 32);
      cq += __shfl_xor(cq, 16); cq += __shfl_xor(cq, 32);
      if (l4 == 0) {
        size_t pidx = (size_t)(pOff + blockIdx.x) * Cout + col;
        psum[pidx] = cs;
        psq[pidx]  = cq;
      }
    }
  }
}

// ---------- column stats of a bf16 [rows][256] tensor; 2048 rows/block ----------
__global__ __launch_bounds__(256) void colstats(
    const unsigned short* __restrict__ A, float* __restrict__ psum,
    float* __restrict__ psq) {
  const int tid = threadIdx.x;
  const int r8 = tid >> 5, co = tid & 31;
  float s[8] = {0,0,0,0,0,0,0,0}, q[8] = {0,0,0,0,0,0,0,0};
  size_t base = (size_t)blockIdx.x * 2048;
  for (int it = 0; it < 256; ++it) {
    size_t row = base + it * 8 + r8;
    uint4 v = *(const uint4*)(A + row * 256 + co * 8);
    const unsigned short* pv = (const unsigned short*)&v;
#pragma unroll
    for (int j = 0; j < 8; ++j) {
      float f = bf2f(pv[j]);
      s[j] += f; q[j] += f * f;
    }
  }
  __shared__ float ls[8][32][8], lq[8][32][8];
#pragma unroll
  for (int j = 0; j < 8; ++j) { ls[r8][co][j] = s[j]; lq[r8][co][j] = q[j]; }
  __syncthreads();
  int co2 = tid >> 3, j2 = tid & 7;
  float S = 0.f, Q = 0.f;
#pragma unroll
  for (int r = 0; r < 8; ++r) { S += ls[r][co2][j2]; Q += lq[r][co2][j2]; }
  psum[(size_t)blockIdx.x * 256 + co2 * 8 + j2] = S;
  psq [(size_t)blockIdx.x * 256 + co2 * 8 + j2] = Q;
}

// ---------- BN stats: row-parallel partial + finalize ----------
__global__ __launch_bounds__(512) void bn_part(
    const float* __restrict__ psum, const float* __restrict__ psq,
    float* __restrict__ pp, int gridM, int Cout) {
  const int lane = threadIdx.x & 63, wv = threadIdx.x >> 6;
  const int c = blockIdx.y * 64 + lane;
  float s = 0.f, q = 0.f;
  for (int r = blockIdx.x + 64 * wv; r < gridM; r += 512) {
    s += psum[(size_t)r * Cout + c];
    q += psq[(size_t)r * Cout + c];
  }
  __shared__ float rs[8][64], rq[8][64];
  rs[wv][lane] = s; rq[wv][lane] = q;
  __syncthreads();
  if (threadIdx.x < 64) {
    float S = 0.f, Q = 0.f;
#pragma unroll
    for (int w2 = 0; w2 < 8; ++w2) { S += rs[w2][threadIdx.x]; Q += rq[w2][threadIdx.x]; }
    pp[(size_t)blockIdx.x * Cout + blockIdx.y * 64 + threadIdx.x] = S;
    pp[(size_t)(64 + blockIdx.x) * Cout + blockIdx.y * 64 + threadIdx.x] = Q;
  }
}
__global__ __launch_bounds__(64) void bn_fin(
    const float* __restrict__ pp, const float* __restrict__ g,
    const float* __restrict__ be, float2* __restrict__ ss, int Cout, float invR) {
  int c = blockIdx.x * 64 + threadIdx.x;
  float S = 0.f, Q = 0.f;
  for (int r = 0; r < 64; ++r) {
    S += pp[(size_t)r * Cout + c];
    Q += pp[(size_t)(64 + r) * Cout + c];
  }
  float mu = S * invR, var = Q * invR - mu * mu;
  float sc = g[c] * rsqrtf(var + 1e-5f);
  ss[c] = make_float2(sc, be[c] - mu * sc);
}
__global__ __launch_bounds__(64) void bn_fin2(
    const float* __restrict__ pp, const float* __restrict__ gA,
    const float* __restrict__ zA, const float* __restrict__ gB,
    const float* __restrict__ zB, float2* __restrict__ ssC, float invR) {
  int c = blockIdx.x * 64 + threadIdx.x;  // Cout = 512
  float S = 0.f, Q = 0.f;
  for (int r = 0; r < 64; ++r) {
    S += pp[(size_t)r * 512 + c];
    Q += pp[(size_t)(64 + r) * 512 + c];
  }
  float mu = S * invR, var = Q * invR - mu * mu;
  const float* g = (c < 256) ? gA : gB;
  const float* z = (c < 256) ? zA : zB;
  int ci = c & 255;
  float sc = g[ci] * rsqrtf(var + 1e-5f);
  ssC[c] = make_float2(sc, z[ci] - mu * sc);
}

// ---------- attention: q bf16 (+BN), k/v bf16 (+BN), bf16 out ----------
template<int NK, int NQ>
__global__ void attn_sm(const unsigned short* __restrict__ qy,
                        const unsigned short* __restrict__ ky,
                        const unsigned short* __restrict__ vy,
                        const float2* __restrict__ ssq, const float2* __restrict__ ssk,
                        const float2* __restrict__ ssv, unsigned short* __restrict__ out,
                        size_t qStride, size_t kvStride, size_t oStride, int RS) {
  __shared__ float kl[NK][16][17];
  __shared__ float vl[NK][16][17];
  const int n = blockIdx.x, b = blockIdx.y;
  const int tid = threadIdx.x;
  const unsigned short* kyb = ky + (size_t)b * kvStride;
  const unsigned short* vyb = vy + (size_t)b * kvStride;
  for (int ch = tid; ch < NK * 32; ch += NQ * 16) {
    int t = ch >> 5, c8 = (ch & 31) * 8;
    size_t src = ((size_t)t * 500 + n) * RS + c8;
    uint4 kv = *(const uint4*)(kyb + src);
    uint4 vv = *(const uint4*)(vyb + src);
    const unsigned short* kp = (const unsigned short*)&kv;
    const unsigned short* vp = (const unsigned short*)&vv;
#pragma unroll
    for (int j = 0; j < 8; ++j) {
      int c = c8 + j;
      float2 sk = ssk[c], sv = ssv[c];
      kl[t][c >> 4][c & 15] = fmaxf(bf2f(kp[j]) * sk.x + sk.y, 0.f);
      vl[t][c >> 4][c & 15] = fmaxf(bf2f(vp[j]) * sv.x + sv.y, 0.f);
    }
  }
  __syncthreads();
  const int s = tid >> 4, h = tid & 15;
  unsigned short qraw[16];
  size_t qb = (size_t)b * qStride + ((size_t)s * 500 + n) * 256 + h * 16;
  *(uint4*)qraw = *(const uint4*)(qy + qb);
  *(uint4*)(qraw + 8) = *(const uint4*)(qy + qb + 8);
  float qv[16];
#pragma unroll
  for (int c = 0; c < 16; ++c) {
    float2 sq = ssq[h * 16 + c];
    qv[c] = fmaxf(bf2f(qraw[c]) * sq.x + sq.y, 0.f);
  }
  float lg[NK], mx = -1e30f;
#pragma unroll
  for (int t = 0; t < NK; ++t) {
    float d = 0.f;
#pragma unroll
    for (int c = 0; c < 16; ++c) d += qv[c] * kl[t][h][c];
    lg[t] = d * 0.25f;
    mx = fmaxf(mx, lg[t]);
  }
  float sum = 0.f;
#pragma unroll
  for (int t = 0; t < NK; ++t) { lg[t] = __expf(lg[t] - mx); sum += lg[t]; }
  float inv = 1.f / sum;
  float o[16];
#pragma unroll
  for (int c = 0; c < 16; ++c) o[c] = 0.f;
#pragma unroll
  for (int t = 0; t < NK; ++t) {
    float p = lg[t] * inv;
#pragma unroll
    for (int c = 0; c < 16; ++c) o[c] += p * vl[t][h][c];
  }
  size_t ob = (size_t)b * oStride + ((size_t)s * 500 + n) * 256 + h * 16;
  uint4 w0;
  w0.x = pack2(o[0], o[1]); w0.y = pack2(o[2], o[3]);
  w0.z = pack2(o[4], o[5]); w0.w = pack2(o[6], o[7]);
  *(uint4*)(out + ob) = w0;
  w0.x = pack2(o[8], o[9]); w0.y = pack2(o[10], o[11]);
  w0.z = pack2(o[12], o[13]); w0.w = pack2(o[14], o[15]);
  *(uint4*)(out + ob + 8) = w0;
}

// ---------- final: out = X + relu(BN(y)), y bf16 ----------
__global__ __launch_bounds__(256) void bn_relu_addx(
    const unsigned short* __restrict__ y, const float2* __restrict__ ss,
    const float* __restrict__ X, float* __restrict__ out) {
  int r = blockIdx.x * 8 + (threadIdx.x >> 5);
  int c8 = (threadIdx.x & 31) * 8;
  size_t idx = (size_t)r * 256 + c8;
  uint4 yv4 = *(const uint4*)(y + idx);
  const unsigned short* yv = (const unsigned short*)&yv4;
  float4 x0 = *(const float4*)(X + idx);
  float4 x1 = *(const float4*)(X + idx + 4);
  float ov[8];
#pragma unroll
  for (int j = 0; j < 8; ++j) {
    float2 sc = ss[c8 + j];
    ov[j] = fmaxf(bf2f(yv[j]) * sc.x + sc.y, 0.f);
  }
  *(float4*)(out + idx)     = make_float4(x0.x + ov[0], x0.y + ov[1], x0.z + ov[2], x0.w + ov[3]);
  *(float4*)(out + idx + 4) = make_float4(x1.x + ov[4], x1.y + ov[5], x1.z + ov[6], x1.w + ov[7]);
}

// ---------- launcher ----------
extern "C" void kernel_launch(void* const* d_in, const int* in_sizes, int n_in,
                              void* d_out, int out_size, void* d_ws, size_t ws_size,
                              hipStream_t stream) {
  (void)in_sizes; (void)n_in; (void)out_size; (void)ws_size;
  const float* X  = (const float*)d_in[0];
  const float* TE = (const float*)d_in[1];
  const float* SE = (const float*)d_in[2];
  const float* I  = (const float*)d_in[3];
  const float *Wf[8], *Bf[8], *Gf[8], *Zf[8];
  for (int l = 0; l < 8; ++l) {
    Wf[l] = (const float*)d_in[4 + l * 4 + 0];
    Bf[l] = (const float*)d_in[4 + l * 4 + 1];
    Gf[l] = (const float*)d_in[4 + l * 4 + 2];
    Zf[l] = (const float*)d_in[4 + l * 4 + 3];
  }

  char* w = (char*)d_ws;
  size_t off = 0;
  auto alloc = [&](size_t bytes) -> void* {
    void* p = w + off;
    off += (bytes + 255) & ~(size_t)255;
    return p;
  };

  // ---- workspace (~342 MB; ws >= 345 MB proven) ----
  float* psum0 = (float*)alloc((size_t)4000 * 768 * 4);
  float* psq0  = (float*)alloc((size_t)4000 * 768 * 4);
  float* psumK = (float*)alloc((size_t)125 * 256 * 4);
  float* psqK  = (float*)alloc((size_t)125 * 256 * 4);
  float* pp    = (float*)alloc((size_t)128 * 768 * 4);
  float2* ss   = (float2*)alloc((size_t)(8 * 768 + 512) * sizeof(float2));
  float2* ssC  = ss + 8 * 768;
  unsigned short *W0h, *W0l, *W3h, *W3l, *W4h, *W4l, *W7h, *W7l;
  unsigned short *KV0h, *KV0l, *KV1h, *KV1l;
  W0h = (unsigned short*)alloc(196608 * 2); W0l = (unsigned short*)alloc(196608 * 2);
  W3h = (unsigned short*)alloc(196608 * 2); W3l = (unsigned short*)alloc(196608 * 2);
  W4h = (unsigned short*)alloc(196608 * 2); W4l = (unsigned short*)alloc(196608 * 2);
  W7h = (unsigned short*)alloc(65536 * 2);  W7l = (unsigned short*)alloc(65536 * 2);
  KV0h = (unsigned short*)alloc(393216 * 2); KV0l = (unsigned short*)alloc(393216 * 2);
  KV1h = (unsigned short*)alloc(393216 * 2); KV1l = (unsigned short*)alloc(393216 * 2);
  float* b12 = (float*)alloc(512 * 4);
  float* b56 = (float*)alloc(512 * 4);
  // region R: q0 | kv0 | pad  == exactly k1 [256000][256] bf16 later
  char* R = (char*)alloc(131072000);
  unsigned short* q0  = (unsigned short*)R;                    // 16000*256
  unsigned short* kv0 = (unsigned short*)(R + 8192000);        // 96000*512
  unsigned short* k1  = (unsigned short*)R;                    // 256000*256
  unsigned short* o0b = (unsigned short*)alloc(131072000);     // 256000*256 -> v1 -> y7
  unsigned short* v1  = o0b;
  unsigned short* y7  = o0b;
  unsigned short* Hc  = (unsigned short*)alloc((size_t)32000 * 768 * 2);  // 2-batch chunk

  unsigned short* q1 = (unsigned short*)d_out;                 // bf16 (lower half)
  unsigned short* o1 = (unsigned short*)d_out + 24576000;      // bf16 (upper half)

  // ---- prep ----
  cat2<<<dim3(1), 256, 0, stream>>>(Bf[1], Bf[2], b12);
  cat2<<<dim3(1), 256, 0, stream>>>(Bf[5], Bf[6], b56);
  wsplit<<<dim3(96), 256, 0, stream>>>(Wf[0], W0h, W0l, 196608);
  wsplit<<<dim3(96), 256, 0, stream>>>(Wf[3], W3h, W3l, 196608);
  wsplit<<<dim3(96), 256, 0, stream>>>(Wf[4], W4h, W4l, 196608);
  wsplit<<<dim3(32), 256, 0, stream>>>(Wf[7], W7h, W7l, 65536);
  wsplit<<<dim3(96), 256, 0, stream>>>(Wf[1], KV0h, KV0l, 196608);
  wsplit<<<dim3(96), 256, 0, stream>>>(Wf[2], KV0h + 196608, KV0l + 196608, 196608);
  wsplit<<<dim3(96), 256, 0, stream>>>(Wf[5], KV1h, KV1l, 196608);
  wsplit<<<dim3(96), 256, 0, stream>>>(Wf[6], KV1h + 196608, KV1l + 196608, 196608);

  auto bn1 = [&](float* ps, float* pq, const float* g, const float* z, float2* dst,
                 int gridM, int Cout, float invR) {
    bn_part<<<dim3(64, Cout / 64), 512, 0, stream>>>(ps, pq, pp, gridM, Cout);
    bn_fin<<<dim3(Cout / 64), 64, 0, stream>>>(pp, g, z, dst, Cout, invR);
  };

  // ---- stage 1: q0, fused k0|v0, q1 ----
  gemm4<0, 1, 1, 2, 768><<<dim3(250), 512, 0, stream>>>(
      I, nullptr, nullptr, nullptr, W0h, W0l, Bf[0], nullptr,
      q0, nullptr, psum0, psq0, 256, 256, 0, 2);
  bn1(psum0, psq0, Gf[0], Zf[0], ss + 0 * 768, 250, 256, 1.f / 16000.f);
  gemm4<1, 1, 1, 2, 768><<<dim3(1500), 512, 0, stream>>>(
      nullptr, X, TE, SE, KV0h, KV0l, b12, nullptr,
      kv0, nullptr, psum0, psq0, 512, 512, 0, 4);
  bn_part<<<dim3(64, 8), 512, 0, stream>>>(psum0, psq0, pp, 1500, 512);
  bn_fin2<<<dim3(8), 64, 0, stream>>>(pp, Gf[1], Zf[1], Gf[2], Zf[2], ssC, 1.f / 96000.f);
  gemm4<1, 1, 1, 2, 768><<<dim3(1500), 512, 0, stream>>>(
      nullptr, X, TE, SE, W4h, W4l, Bf[4], nullptr,
      q1, nullptr, psum0, psq0, 256, 256, 0, 2);
  bn1(psum0, psq0, Gf[4], Zf[4], ss + 4 * 768, 1500, 256, 1.f / 96000.f);

  // ---- attn0 (single launch) -> o0b bf16 ----
  attn_sm<12, 32><<<dim3(500, 16), 512, 0, stream>>>(
      q0, kv0, kv0 + 256, ss + 0 * 768, ssC, ssC + 256, o0b,
      0, (size_t)6000 * 512, (size_t)16000 * 256, 512);

  // ---- m0o stats (one pass, PREC1) ----
  gemm4<2, 0, 1, 1, 256><<<dim3(4000), 512, 0, stream>>>(
      o0b, nullptr, nullptr, nullptr, W3h, W3l, Bf[3], nullptr,
      nullptr, nullptr, psum0, psq0, 768, 768, 0, 6);
  bn1(psum0, psq0, Gf[3], Zf[3], ss + 3 * 768, 4000, 768, 1.f / 256000.f);

  // ---- pass B: per 2-batch chunk: H -> fused k1|v1 raw bf16 ----
  for (int cb = 0; cb < 8; ++cb) {
    const size_t oCh = (size_t)cb * 32000 * 256;
    gemm4<2, 2, 0, 2, 256><<<dim3(500), 512, 0, stream>>>(
        o0b + oCh, nullptr, nullptr, nullptr, W3h, W3l, Bf[3], ss + 3 * 768,
        Hc, nullptr, nullptr, nullptr, 768, 768, 0, 6);
    gemm4<2, 5, 0, 3, 768><<<dim3(500), 512, 0, stream>>>(
        Hc, nullptr, nullptr, nullptr, KV1h, KV1l, b56, nullptr,
        k1 + oCh, v1 + oCh, nullptr, nullptr, 512, 256, 0, 4);
  }

  // ---- m1k / m1v stats from stored raw k1 / v1 ----
  colstats<<<dim3(125), 256, 0, stream>>>(k1, psumK, psqK);
  bn1(psumK, psqK, Gf[5], Zf[5], ss + 5 * 768, 125, 256, 1.f / 256000.f);
  colstats<<<dim3(125), 256, 0, stream>>>(v1, psumK, psqK);
  bn1(psumK, psqK, Gf[6], Zf[6], ss + 6 * 768, 125, 256, 1.f / 256000.f);

  // ---- attn1 (single launch) -> o1 bf16 in d_out upper half ----
  attn_sm<32, 12><<<dim3(500, 16), 192, 0, stream>>>(
      q1, k1, v1, ss + 4 * 768, ss + 5 * 768, ss + 6 * 768, o1,
      (size_t)6000 * 256, (size_t)16000 * 256, (size_t)6000 * 256, 256);

  // ---- m1o -> y7 bf16 (over o0b region) ----
  gemm4<2, 1, 1, 2, 256><<<dim3(1500), 512, 0, stream>>>(
      o1, nullptr, nullptr, nullptr, W7h, W7l, Bf[7], nullptr,
      y7, nullptr, psum0, psq0, 256, 256, 0, 2);
  bn1(psum0, psq0, Gf[7], Zf[7], ss + 7 * 768, 1500, 256, 1.f / 96000.f);
  bn_relu_addx<<<dim3(12000), 256, 0, stream>>>(y7, ss + 7 * 768, X, (float*)d_out);
}

// Round 12
// 2559.934 us; speedup vs baseline: 2.4584x; 1.3033x over previous
//
#include <hip/hip_runtime.h>
#include <stdint.h>

typedef __bf16 bf16_t;
typedef bf16_t bf16x8 __attribute__((ext_vector_type(8)));
typedef float f32x4 __attribute__((ext_vector_type(4)));

__device__ __forceinline__ float bf2f(unsigned short u) {
  union { unsigned int i; float f; } x; x.i = ((unsigned int)u) << 16; return x.f;
}
__device__ __forceinline__ unsigned short f2bf(float f) {
  union { float f; unsigned int i; } x; x.f = f;
  unsigned int r = x.i + 0x7FFFu + ((x.i >> 16) & 1u);
  return (unsigned short)(r >> 16);
}
__device__ __forceinline__ unsigned pack2(float a, float b) {
  return (unsigned)f2bf(a) | ((unsigned)f2bf(b) << 16);
}

__global__ void cat2(const float* __restrict__ a, const float* __restrict__ b,
                     float* __restrict__ dst) {
  int i = threadIdx.x;
  dst[i] = a[i]; dst[256 + i] = b[i];
}

__global__ __launch_bounds__(256) void wsplit(
    const float* __restrict__ in, unsigned short* __restrict__ hi,
    unsigned short* __restrict__ lo, int n) {
  int i = (blockIdx.x * 256 + threadIdx.x) * 8;
  if (i >= n) return;
  float4 a = *(const float4*)(in + i);
  float4 b = *(const float4*)(in + i + 4);
  float f[8] = {a.x, a.y, a.z, a.w, b.x, b.y, b.z, b.w};
  unsigned short sh[8], sl[8];
#pragma unroll
  for (int j = 0; j < 8; ++j) {
    sh[j] = f2bf(f[j]);
    sl[j] = f2bf(f[j] - bf2f(sh[j]));
  }
  *(uint4*)(hi + i) = *(uint4*)sh;
  *(uint4*)(lo + i) = *(uint4*)sl;
}

struct f8 { float4 a, b; };

__device__ __forceinline__ f8 ld_c8(const float* __restrict__ X,
                                    const float* __restrict__ TE,
                                    const float* __restrict__ SE,
                                    size_t row, int cc) {
  const float* src = (cc < 256) ? X : ((cc < 512) ? TE : SE);
  const float* p = src + row * 256 + (cc & 255);
  f8 r; r.a = *(const float4*)p; r.b = *(const float4*)(p + 4);
  return r;
}
__device__ __forceinline__ uint4 pack_hi(const float4 a, const float4 b) {
  return make_uint4(pack2(a.x, a.y), pack2(a.z, a.w), pack2(b.x, b.y), pack2(b.z, b.w));
}

// ---------- A-panel-resident, barrier-free GEMM, 8 waves ----------
// Block owns 64 rows; A panel staged to LDS once (bf16 hi, XOR-swizzled).
// B fragments live in REGISTERS, loaded directly from global (L2-resident W)
// in 256-K chunks -> no B staging, no inner-loop barriers. C stores are
// LDS-staged for coalescing (2 barriers per col tile); stats kernels
// (SMODE 0) have zero barriers after A staging.
// AMODE 0: A fp32. 1: A concat(X,TE,SE) fp32. 2: A bf16 raw.
// PREC 1: ah*bh. 2: ah*(bh+bl). 3: lo-plane only for bcol>=256 (SMODE5 k|v).
// SMODE 0: none, 1: raw bf16, 2: relu(BN) bf16,
//         5: dual raw bf16 (bcol<256 -> Cb else Cb2; both row stride 256).
// PART: per-block column partials (width Cout); cstr = C row stride.
template<int AMODE, int SMODE, int PART, int PREC, int K>
__global__ __launch_bounds__(512) void gemm5(
    const void* __restrict__ Ap, const float* __restrict__ AX,
    const float* __restrict__ ATE, const float* __restrict__ ASE,
    const unsigned short* __restrict__ Wh, const unsigned short* __restrict__ Wl,
    const float* __restrict__ bias, const float2* __restrict__ ssO,
    unsigned short* __restrict__ Cb, unsigned short* __restrict__ Cb2,
    float* __restrict__ psum, float* __restrict__ psq,
    int Cout, int cstr, int pOff, int nx) {
  constexpr int ASH = 64 * K;
  constexpr int TOT = ASH + (SMODE != 0 ? 64 * 136 : 8);
  __shared__ unsigned short lds[TOT];
  unsigned short* lA = lds;
  unsigned short* lC = lds + ASH;

  const int tid = threadIdx.x;
  const int lane = tid & 63, wid = tid >> 6;   // 8 waves
  const int l15 = lane & 15, l4 = lane >> 4;
  const int brow = blockIdx.x * 64;

  // ---- stage A panel once (XOR-swizzled within 64-elem K groups) ----
  constexpr int CPR = K / 8;
#pragma unroll
  for (int i = 0; i < (64 * CPR) / 512; ++i) {
    int ch = i * 512 + tid;
    int row = ch / CPR, c8 = (ch % CPR) * 8;
    uint4 hv;
    if constexpr (AMODE == 2) {
      hv = *(const uint4*)((const unsigned short*)Ap + (size_t)(brow + row) * K + c8);
    } else if constexpr (AMODE == 0) {
      const float* p = (const float*)Ap + (size_t)(brow + row) * K + c8;
      hv = pack_hi(*(const float4*)p, *(const float4*)(p + 4));
    } else {
      f8 v = ld_c8(AX, ATE, ASE, (size_t)(brow + row), c8);
      hv = pack_hi(v.a, v.b);
    }
    int dst = row * K + (c8 & ~63) + ((c8 & 63) ^ ((row & 7) << 3));
    *(uint4*)(lA + dst) = hv;
  }
  __syncthreads();

  const int axor = (l15 & 7) << 3;

  for (int cx = 0; cx < nx; ++cx) {
    const int bcol = cx * 128;
    const int colL = wid * 16 + l15;
    const int col = bcol + colL;
    const bool useLo = (PREC == 2) || (PREC == 3 && bcol >= 256);
    f32x4 acc[4] = {};

    for (int kc = 0; kc < K; kc += 256) {
      // B fragments for this 256-K chunk -> registers (global/L2 reads)
      uint4 bh[8], bl[8];
      const unsigned short* wp = Wh + (size_t)col * K + kc + l4 * 8;
#pragma unroll
      for (int ks = 0; ks < 8; ++ks) bh[ks] = *(const uint4*)(wp + ks * 32);
      if (useLo) {
        const unsigned short* wq = Wl + (size_t)col * K + kc + l4 * 8;
#pragma unroll
        for (int ks = 0; ks < 8; ++ks) bl[ks] = *(const uint4*)(wq + ks * 32);
      }
#pragma unroll
      for (int kk = 0; kk < 8; ++kk) {
        const int kabs = kc + kk * 32;
        const int kt64 = kabs & ~63;
        const int cofs = ((kabs & 32) + l4 * 8) ^ axor;
        bf16x8 af[4];
#pragma unroll
        for (int m = 0; m < 4; ++m)
          af[m] = *(const bf16x8*)(lA + (m * 16 + l15) * K + kt64 + cofs);
        bf16x8 bhf = *(const bf16x8*)&bh[kk];
#pragma unroll
        for (int m = 0; m < 4; ++m)
          acc[m] = __builtin_amdgcn_mfma_f32_16x16x32_bf16(af[m], bhf, acc[m], 0, 0, 0);
        if (useLo) {
          bf16x8 blf = *(const bf16x8*)&bl[kk];
#pragma unroll
          for (int m = 0; m < 4; ++m)
            acc[m] = __builtin_amdgcn_mfma_f32_16x16x32_bf16(af[m], blf, acc[m], 0, 0, 0);
        }
      }
    }

    // ---- epilogue for this col tile ----
    float cs = 0.f, cq = 0.f;
    float bv = bias[col];
    float2 s2 = make_float2(1.f, 0.f);
    if constexpr (SMODE == 2) s2 = ssO[col];
    if constexpr (SMODE != 0) __syncthreads();   // prev cx's lC reads done
#pragma unroll
    for (int m = 0; m < 4; ++m) {
#pragma unroll
      for (int r = 0; r < 4; ++r) {
        float v = acc[m][r] + bv;
        if constexpr (PART) { cs += v; cq += v * v; }
        if constexpr (SMODE == 2) v = fmaxf(v * s2.x + s2.y, 0.f);
        if constexpr (SMODE != 0) lC[(m * 16 + l4 * 4 + r) * 136 + colL] = f2bf(v);
      }
    }
    if constexpr (SMODE != 0) {
      __syncthreads();
      const int rw = tid >> 4, c16 = (tid & 15) * 8;
#pragma unroll
      for (int it = 0; it < 2; ++it) {
        int rr = it * 32 + rw;
        uint4 val = *(const uint4*)(lC + rr * 136 + c16);
        if constexpr (SMODE == 5) {
          unsigned short* dst = (bcol < 256) ? Cb : Cb2;
          *(uint4*)(dst + (size_t)(brow + rr) * 256 + (bcol & 255) + c16) = val;
        } else {
          *(uint4*)(Cb + (size_t)(brow + rr) * cstr + bcol + c16) = val;
        }
      }
    }
    if constexpr (PART) {
      cs += __shfl_xor(cs, 16); cs += __shfl_xor(cs, 32);
      cq += __shfl_xor(cq, 16); cq += __shfl_xor(cq, 32);
      if (l4 == 0) {
        size_t pidx = (size_t)(pOff + blockIdx.x) * Cout + col;
        psum[pidx] = cs;
        psq[pidx]  = cq;
      }
    }
  }
}

// ---------- column stats of a bf16 [rows][256] tensor; 2048 rows/block ----------
__global__ __launch_bounds__(256) void colstats(
    const unsigned short* __restrict__ A, float* __restrict__ psum,
    float* __restrict__ psq) {
  const int tid = threadIdx.x;
  const int r8 = tid >> 5, co = tid & 31;
  float s[8] = {0,0,0,0,0,0,0,0}, q[8] = {0,0,0,0,0,0,0,0};
  size_t base = (size_t)blockIdx.x * 2048;
  for (int it = 0; it < 256; ++it) {
    size_t row = base + it * 8 + r8;
    uint4 v = *(const uint4*)(A + row * 256 + co * 8);
    const unsigned short* pv = (const unsigned short*)&v;
#pragma unroll
    for (int j = 0; j < 8; ++j) {
      float f = bf2f(pv[j]);
      s[j] += f; q[j] += f * f;
    }
  }
  __shared__ float ls[8][32][8], lq[8][32][8];
#pragma unroll
  for (int j = 0; j < 8; ++j) { ls[r8][co][j] = s[j]; lq[r8][co][j] = q[j]; }
  __syncthreads();
  int co2 = tid >> 3, j2 = tid & 7;
  float S = 0.f, Q = 0.f;
#pragma unroll
  for (int r = 0; r < 8; ++r) { S += ls[r][co2][j2]; Q += lq[r][co2][j2]; }
  psum[(size_t)blockIdx.x * 256 + co2 * 8 + j2] = S;
  psq [(size_t)blockIdx.x * 256 + co2 * 8 + j2] = Q;
}

// ---------- BN stats: row-parallel partial + finalize ----------
__global__ __launch_bounds__(512) void bn_part(
    const float* __restrict__ psum, const float* __restrict__ psq,
    float* __restrict__ pp, int gridM, int Cout) {
  const int lane = threadIdx.x & 63, wv = threadIdx.x >> 6;
  const int c = blockIdx.y * 64 + lane;
  float s = 0.f, q = 0.f;
  for (int r = blockIdx.x + 64 * wv; r < gridM; r += 512) {
    s += psum[(size_t)r * Cout + c];
    q += psq[(size_t)r * Cout + c];
  }
  __shared__ float rs[8][64], rq[8][64];
  rs[wv][lane] = s; rq[wv][lane] = q;
  __syncthreads();
  if (threadIdx.x < 64) {
    float S = 0.f, Q = 0.f;
#pragma unroll
    for (int w2 = 0; w2 < 8; ++w2) { S += rs[w2][threadIdx.x]; Q += rq[w2][threadIdx.x]; }
    pp[(size_t)blockIdx.x * Cout + blockIdx.y * 64 + threadIdx.x] = S;
    pp[(size_t)(64 + blockIdx.x) * Cout + blockIdx.y * 64 + threadIdx.x] = Q;
  }
}
__global__ __launch_bounds__(64) void bn_fin(
    const float* __restrict__ pp, const float* __restrict__ g,
    const float* __restrict__ be, float2* __restrict__ ss, int Cout, float invR) {
  int c = blockIdx.x * 64 + threadIdx.x;
  float S = 0.f, Q = 0.f;
  for (int r = 0; r < 64; ++r) {
    S += pp[(size_t)r * Cout + c];
    Q += pp[(size_t)(64 + r) * Cout + c];
  }
  float mu = S * invR, var = Q * invR - mu * mu;
  float sc = g[c] * rsqrtf(var + 1e-5f);
  ss[c] = make_float2(sc, be[c] - mu * sc);
}
__global__ __launch_bounds__(64) void bn_fin2(
    const float* __restrict__ pp, const float* __restrict__ gA,
    const float* __restrict__ zA, const float* __restrict__ gB,
    const float* __restrict__ zB, float2* __restrict__ ssC, float invR) {
  int c = blockIdx.x * 64 + threadIdx.x;  // Cout = 512
  float S = 0.f, Q = 0.f;
  for (int r = 0; r < 64; ++r) {
    S += pp[(size_t)r * 512 + c];
    Q += pp[(size_t)(64 + r) * 512 + c];
  }
  float mu = S * invR, var = Q * invR - mu * mu;
  const float* g = (c < 256) ? gA : gB;
  const float* z = (c < 256) ? zA : zB;
  int ci = c & 255;
  float sc = g[ci] * rsqrtf(var + 1e-5f);
  ssC[c] = make_float2(sc, z[ci] - mu * sc);
}

// ---------- attention: q bf16 (+BN), k/v bf16 (+BN), bf16 out ----------
template<int NK, int NQ>
__global__ void attn_sm(const unsigned short* __restrict__ qy,
                        const unsigned short* __restrict__ ky,
                        const unsigned short* __restrict__ vy,
                        const float2* __restrict__ ssq, const float2* __restrict__ ssk,
                        const float2* __restrict__ ssv, unsigned short* __restrict__ out,
                        size_t qStride, size_t kvStride, size_t oStride, int RS) {
  __shared__ float kl[NK][16][17];
  __shared__ float vl[NK][16][17];
  const int n = blockIdx.x, b = blockIdx.y;
  const int tid = threadIdx.x;
  const unsigned short* kyb = ky + (size_t)b * kvStride;
  const unsigned short* vyb = vy + (size_t)b * kvStride;
  for (int ch = tid; ch < NK * 32; ch += NQ * 16) {
    int t = ch >> 5, c8 = (ch & 31) * 8;
    size_t src = ((size_t)t * 500 + n) * RS + c8;
    uint4 kv = *(const uint4*)(kyb + src);
    uint4 vv = *(const uint4*)(vyb + src);
    const unsigned short* kp = (const unsigned short*)&kv;
    const unsigned short* vp = (const unsigned short*)&vv;
#pragma unroll
    for (int j = 0; j < 8; ++j) {
      int c = c8 + j;
      float2 sk = ssk[c], sv = ssv[c];
      kl[t][c >> 4][c & 15] = fmaxf(bf2f(kp[j]) * sk.x + sk.y, 0.f);
      vl[t][c >> 4][c & 15] = fmaxf(bf2f(vp[j]) * sv.x + sv.y, 0.f);
    }
  }
  __syncthreads();
  const int s = tid >> 4, h = tid & 15;
  unsigned short qraw[16];
  size_t qb = (size_t)b * qStride + ((size_t)s * 500 + n) * 256 + h * 16;
  *(uint4*)qraw = *(const uint4*)(qy + qb);
  *(uint4*)(qraw + 8) = *(const uint4*)(qy + qb + 8);
  float qv[16];
#pragma unroll
  for (int c = 0; c < 16; ++c) {
    float2 sq = ssq[h * 16 + c];
    qv[c] = fmaxf(bf2f(qraw[c]) * sq.x + sq.y, 0.f);
  }
  float lg[NK], mx = -1e30f;
#pragma unroll
  for (int t = 0; t < NK; ++t) {
    float d = 0.f;
#pragma unroll
    for (int c = 0; c < 16; ++c) d += qv[c] * kl[t][h][c];
    lg[t] = d * 0.25f;
    mx = fmaxf(mx, lg[t]);
  }
  float sum = 0.f;
#pragma unroll
  for (int t = 0; t < NK; ++t) { lg[t] = __expf(lg[t] - mx); sum += lg[t]; }
  float inv = 1.f / sum;
  float o[16];
#pragma unroll
  for (int c = 0; c < 16; ++c) o[c] = 0.f;
#pragma unroll
  for (int t = 0; t < NK; ++t) {
    float p = lg[t] * inv;
#pragma unroll
    for (int c = 0; c < 16; ++c) o[c] += p * vl[t][h][c];
  }
  size_t ob = (size_t)b * oStride + ((size_t)s * 500 + n) * 256 + h * 16;
  uint4 w0;
  w0.x = pack2(o[0], o[1]); w0.y = pack2(o[2], o[3]);
  w0.z = pack2(o[4], o[5]); w0.w = pack2(o[6], o[7]);
  *(uint4*)(out + ob) = w0;
  w0.x = pack2(o[8], o[9]); w0.y = pack2(o[10], o[11]);
  w0.z = pack2(o[12], o[13]); w0.w = pack2(o[14], o[15]);
  *(uint4*)(out + ob + 8) = w0;
}

// ---------- final: out = X + relu(BN(y)), y bf16 ----------
__global__ __launch_bounds__(256) void bn_relu_addx(
    const unsigned short* __restrict__ y, const float2* __restrict__ ss,
    const float* __restrict__ X, float* __restrict__ out) {
  int r = blockIdx.x * 8 + (threadIdx.x >> 5);
  int c8 = (threadIdx.x & 31) * 8;
  size_t idx = (size_t)r * 256 + c8;
  uint4 yv4 = *(const uint4*)(y + idx);
  const unsigned short* yv = (const unsigned short*)&yv4;
  float4 x0 = *(const float4*)(X + idx);
  float4 x1 = *(const float4*)(X + idx + 4);
  float ov[8];
#pragma unroll
  for (int j = 0; j < 8; ++j) {
    float2 sc = ss[c8 + j];
    ov[j] = fmaxf(bf2f(yv[j]) * sc.x + sc.y, 0.f);
  }
  *(float4*)(out + idx)     = make_float4(x0.x + ov[0], x0.y + ov[1], x0.z + ov[2], x0.w + ov[3]);
  *(float4*)(out + idx + 4) = make_float4(x1.x + ov[4], x1.y + ov[5], x1.z + ov[6], x1.w + ov[7]);
}

// ---------- launcher ----------
extern "C" void kernel_launch(void* const* d_in, const int* in_sizes, int n_in,
                              void* d_out, int out_size, void* d_ws, size_t ws_size,
                              hipStream_t stream) {
  (void)in_sizes; (void)n_in; (void)out_size; (void)ws_size;
  const float* X  = (const float*)d_in[0];
  const float* TE = (const float*)d_in[1];
  const float* SE = (const float*)d_in[2];
  const float* I  = (const float*)d_in[3];
  const float *Wf[8], *Bf[8], *Gf[8], *Zf[8];
  for (int l = 0; l < 8; ++l) {
    Wf[l] = (const float*)d_in[4 + l * 4 + 0];
    Bf[l] = (const float*)d_in[4 + l * 4 + 1];
    Gf[l] = (const float*)d_in[4 + l * 4 + 2];
    Zf[l] = (const float*)d_in[4 + l * 4 + 3];
  }

  char* w = (char*)d_ws;
  size_t off = 0;
  auto alloc = [&](size_t bytes) -> void* {
    void* p = w + off;
    off += (bytes + 255) & ~(size_t)255;
    return p;
  };

  // ---- workspace (~342 MB; ws >= 345 MB proven) ----
  float* psum0 = (float*)alloc((size_t)4000 * 768 * 4);
  float* psq0  = (float*)alloc((size_t)4000 * 768 * 4);
  float* psumK = (float*)alloc((size_t)125 * 256 * 4);
  float* psqK  = (float*)alloc((size_t)125 * 256 * 4);
  float* pp    = (float*)alloc((size_t)128 * 768 * 4);
  float2* ss   = (float2*)alloc((size_t)(8 * 768 + 512) * sizeof(float2));
  float2* ssC  = ss + 8 * 768;
  unsigned short *W0h, *W0l, *W3h, *W3l, *W4h, *W4l, *W7h, *W7l;
  unsigned short *KV0h, *KV0l, *KV1h, *KV1l;
  W0h = (unsigned short*)alloc(196608 * 2); W0l = (unsigned short*)alloc(196608 * 2);
  W3h = (unsigned short*)alloc(196608 * 2); W3l = (unsigned short*)alloc(196608 * 2);
  W4h = (unsigned short*)alloc(196608 * 2); W4l = (unsigned short*)alloc(196608 * 2);
  W7h = (unsigned short*)alloc(65536 * 2);  W7l = (unsigned short*)alloc(65536 * 2);
  KV0h = (unsigned short*)alloc(393216 * 2); KV0l = (unsigned short*)alloc(393216 * 2);
  KV1h = (unsigned short*)alloc(393216 * 2); KV1l = (unsigned short*)alloc(393216 * 2);
  float* b12 = (float*)alloc(512 * 4);
  float* b56 = (float*)alloc(512 * 4);
  // region R: q0 | kv0 | pad  == exactly k1 [256000][256] bf16 later
  char* R = (char*)alloc(131072000);
  unsigned short* q0  = (unsigned short*)R;                    // 16000*256
  unsigned short* kv0 = (unsigned short*)(R + 8192000);        // 96000*512
  unsigned short* k1  = (unsigned short*)R;                    // 256000*256
  unsigned short* o0b = (unsigned short*)alloc(131072000);     // 256000*256 -> v1 -> y7
  unsigned short* v1  = o0b;
  unsigned short* y7  = o0b;
  unsigned short* Hc  = (unsigned short*)alloc((size_t)32000 * 768 * 2);  // 2-batch chunk

  unsigned short* q1 = (unsigned short*)d_out;                 // bf16 (lower half)
  unsigned short* o1 = (unsigned short*)d_out + 24576000;      // bf16 (upper half)

  // ---- prep ----
  cat2<<<dim3(1), 256, 0, stream>>>(Bf[1], Bf[2], b12);
  cat2<<<dim3(1), 256, 0, stream>>>(Bf[5], Bf[6], b56);
  wsplit<<<dim3(96), 256, 0, stream>>>(Wf[0], W0h, W0l, 196608);
  wsplit<<<dim3(96), 256, 0, stream>>>(Wf[3], W3h, W3l, 196608);
  wsplit<<<dim3(96), 256, 0, stream>>>(Wf[4], W4h, W4l, 196608);
  wsplit<<<dim3(32), 256, 0, stream>>>(Wf[7], W7h, W7l, 65536);
  wsplit<<<dim3(96), 256, 0, stream>>>(Wf[1], KV0h, KV0l, 196608);
  wsplit<<<dim3(96), 256, 0, stream>>>(Wf[2], KV0h + 196608, KV0l + 196608, 196608);
  wsplit<<<dim3(96), 256, 0, stream>>>(Wf[5], KV1h, KV1l, 196608);
  wsplit<<<dim3(96), 256, 0, stream>>>(Wf[6], KV1h + 196608, KV1l + 196608, 196608);

  auto bn1 = [&](float* ps, float* pq, const float* g, const float* z, float2* dst,
                 int gridM, int Cout, float invR) {
    bn_part<<<dim3(64, Cout / 64), 512, 0, stream>>>(ps, pq, pp, gridM, Cout);
    bn_fin<<<dim3(Cout / 64), 64, 0, stream>>>(pp, g, z, dst, Cout, invR);
  };

  // ---- stage 1: q0, fused k0|v0, q1 ----
  gemm5<0, 1, 1, 2, 768><<<dim3(250), 512, 0, stream>>>(
      I, nullptr, nullptr, nullptr, W0h, W0l, Bf[0], nullptr,
      q0, nullptr, psum0, psq0, 256, 256, 0, 2);
  bn1(psum0, psq0, Gf[0], Zf[0], ss + 0 * 768, 250, 256, 1.f / 16000.f);
  gemm5<1, 1, 1, 2, 768><<<dim3(1500), 512, 0, stream>>>(
      nullptr, X, TE, SE, KV0h, KV0l, b12, nullptr,
      kv0, nullptr, psum0, psq0, 512, 512, 0, 4);
  bn_part<<<dim3(64, 8), 512, 0, stream>>>(psum0, psq0, pp, 1500, 512);
  bn_fin2<<<dim3(8), 64, 0, stream>>>(pp, Gf[1], Zf[1], Gf[2], Zf[2], ssC, 1.f / 96000.f);
  gemm5<1, 1, 1, 2, 768><<<dim3(1500), 512, 0, stream>>>(
      nullptr, X, TE, SE, W4h, W4l, Bf[4], nullptr,
      q1, nullptr, psum0, psq0, 256, 256, 0, 2);
  bn1(psum0, psq0, Gf[4], Zf[4], ss + 4 * 768, 1500, 256, 1.f / 96000.f);

  // ---- attn0 (single launch) -> o0b bf16 ----
  attn_sm<12, 32><<<dim3(500, 16), 512, 0, stream>>>(
      q0, kv0, kv0 + 256, ss + 0 * 768, ssC, ssC + 256, o0b,
      0, (size_t)6000 * 512, (size_t)16000 * 256, 512);

  // ---- m0o stats (one pass, PREC1, barrier-free) ----
  gemm5<2, 0, 1, 1, 256><<<dim3(4000), 512, 0, stream>>>(
      o0b, nullptr, nullptr, nullptr, W3h, W3l, Bf[3], nullptr,
      nullptr, nullptr, psum0, psq0, 768, 768, 0, 6);
  bn1(psum0, psq0, Gf[3], Zf[3], ss + 3 * 768, 4000, 768, 1.f / 256000.f);

  // ---- pass B: per 2-batch chunk: H -> fused k1|v1 raw bf16 ----
  for (int cb = 0; cb < 8; ++cb) {
    const size_t oCh = (size_t)cb * 32000 * 256;
    gemm5<2, 2, 0, 2, 256><<<dim3(500), 512, 0, stream>>>(
        o0b + oCh, nullptr, nullptr, nullptr, W3h, W3l, Bf[3], ss + 3 * 768,
        Hc, nullptr, nullptr, nullptr, 768, 768, 0, 6);
    gemm5<2, 5, 0, 3, 768><<<dim3(500), 512, 0, stream>>>(
        Hc, nullptr, nullptr, nullptr, KV1h, KV1l, b56, nullptr,
        k1 + oCh, v1 + oCh, nullptr, nullptr, 512, 256, 0, 4);
  }

  // ---- m1k / m1v stats from stored raw k1 / v1 ----
  colstats<<<dim3(125), 256, 0, stream>>>(k1, psumK, psqK);
  bn1(psumK, psqK, Gf[5], Zf[5], ss + 5 * 768, 125, 256, 1.f / 256000.f);
  colstats<<<dim3(125), 256, 0, stream>>>(v1, psumK, psqK);
  bn1(psumK, psqK, Gf[6], Zf[6], ss + 6 * 768, 125, 256, 1.f / 256000.f);

  // ---- attn1 (single launch) -> o1 bf16 in d_out upper half ----
  attn_sm<32, 12><<<dim3(500, 16), 192, 0, stream>>>(
      q1, k1, v1, ss + 4 * 768, ss + 5 * 768, ss + 6 * 768, o1,
      (size_t)6000 * 256, (size_t)16000 * 256, (size_t)6000 * 256, 256);

  // ---- m1o -> y7 bf16 (over o0b region) ----
  gemm5<2, 1, 1, 2, 256><<<dim3(1500), 512, 0, stream>>>(
      o1, nullptr, nullptr, nullptr, W7h, W7l, Bf[7], nullptr,
      y7, nullptr, psum0, psq0, 256, 256, 0, 2);
  bn1(psum0, psq0, Gf[7], Zf[7], ss + 7 * 768, 1500, 256, 1.f / 96000.f);
  bn_relu_addx<<<dim3(12000), 256, 0, stream>>>(y7, ss + 7 * 768, X, (float*)d_out);
}